// Round 6
// baseline (2887.156 us; speedup 1.0000x reference)
//
#include <hip/hip_runtime.h>

// ---------------------------------------------------------------------------
// MoleRec pipeline on gfx950.
// R5: the GIN layer's random h-row gather is an MLP (memory-level-parallelism)
//     wall: R2/R3/R4 all plateau at ~650 GB/s effective with ~9 waves/CU
//     (51.2KB LDS caps occupancy; compiler refuses to hold >few loads in
//     flight — R4's 4-edge batching changed nothing, VGPR stayed 68).
//     Changes: h/z stored bf16 (halves gather bytes; 1 uint load = full row
//     share), and gin_fused split into gather_z (16.9KB LDS, 32-row tiles,
//     launch_bounds(256,4) => 2-2.5x waves/CU) + gin_mlp2 (sequential z
//     reads + verified MFMA phases B/C). Split also isolates counters.
// ---------------------------------------------------------------------------

typedef short short8 __attribute__((ext_vector_type(8)));
typedef float f32x4 __attribute__((ext_vector_type(4)));
typedef unsigned short us4 __attribute__((ext_vector_type(4)));

#define BN_RSQ 0.9999950000374997f   // 1/sqrt(1+1e-5)  (BatchNorm eval, var=1)
#define LN_EPS 1e-5f
#define NEGBIG -4294967296.0f        // -(1<<32), matches reference mask fill

__device__ __forceinline__ unsigned short f2bf(float x) {
  union { float f; unsigned int u; } v; v.f = x;
  unsigned int r = v.u + 0x7fffu + ((v.u >> 16) & 1u);   // RNE
  return (unsigned short)(r >> 16);
}
__device__ __forceinline__ float bf2f(unsigned short x) {
  union { unsigned int u; float f; } v; v.u = ((unsigned int)x) << 16;
  return v.f;
}

// ---------------- weight prep: fp32 [K][N] -> bf16 [N][K] ------------------
__global__ void prep_weights(const float* __restrict__ w1, const float* __restrict__ w2,
                             unsigned short* __restrict__ w1t, unsigned short* __restrict__ w2t) {
  int i = blockIdx.x * 256 + threadIdx.x;
  if (i >= 262144) return;
  int gl = i >> 15;
  int k1 = (i >> 8) & 127, c1 = i & 255;
  w1t[(gl << 15) + c1 * 128 + k1] = f2bf(w1[i]);
  int k2 = (i >> 7) & 255, c2 = i & 127;
  w2t[(gl << 15) + c2 * 256 + k2] = f2bf(w2[i]);
}

// ---------------- bond tables fp32 -> bf16 (same layout) --------------------
__global__ void prep_bond(const float* __restrict__ in, unsigned short* __restrict__ out, int n) {
  int i = blockIdx.x * 256 + threadIdx.x;
  if (i < n) out[i] = f2bf(in[i]);
}

// ---------------- mask layout detection ------------------------------------
__global__ void mask_detect(const unsigned char* __restrict__ m, int* __restrict__ flags, int nbytes) {
  int i = blockIdx.x * 256 + threadIdx.x;
  if (i < nbytes && m[i]) {
    if ((i & 3) == 0) atomicOr(flags, 1);
    else atomicOr(flags + 1, 1);
  }
}

// ---------------- CSR build: count ------------------------------------------
__global__ void build_count(const int* __restrict__ ei_m, int Em,
                            const int* __restrict__ ei_s, int Es,
                            const int* __restrict__ bm, int Nm,
                            const int* __restrict__ bs, int Ns,
                            int* __restrict__ deg_e, int* __restrict__ deg_n, int M) {
  int i = blockIdx.x * 256 + threadIdx.x;
  if (i < Em) { atomicAdd(&deg_e[ei_m[i]], 1); return; }
  i -= Em;
  if (i < Es) { atomicAdd(&deg_e[Nm + ei_s[i]], 1); return; }
  i -= Es;
  if (i < Nm) { atomicAdd(&deg_n[bm[i]], 1); return; }
  i -= Nm;
  if (i < Ns) { atomicAdd(&deg_n[M + bs[i]], 1); }
}

// ---------------- CSR build: block-level exclusive scan ---------------------
__global__ __launch_bounds__(256) void scan_block(const int* __restrict__ cnt, int n,
                                                  int* __restrict__ excl, int* __restrict__ bsum) {
  int gid = blockIdx.x * 256 + threadIdx.x;
  int lane = threadIdx.x & 63, w = threadIdx.x >> 6;
  int v = (gid < n) ? cnt[gid] : 0;
  int x = v;
#pragma unroll
  for (int off = 1; off < 64; off <<= 1) {
    int y = __shfl_up(x, off, 64);
    if (lane >= off) x += y;
  }
  __shared__ int wt[4];
  if (lane == 63) wt[w] = x;
  __syncthreads();
  int add = 0;
  for (int i = 0; i < w; i++) add += wt[i];
  x += add;
  if (gid < n) excl[gid] = x - v;
  if (threadIdx.x == 255) bsum[blockIdx.x] = x;
}

__global__ __launch_bounds__(1024) void scan_top(int* __restrict__ bsum, int n) {
  int t = threadIdx.x;
  int lane = t & 63, w = t >> 6;
  int v = (t < n) ? bsum[t] : 0;
  int x = v;
#pragma unroll
  for (int off = 1; off < 64; off <<= 1) {
    int y = __shfl_up(x, off, 64);
    if (lane >= off) x += y;
  }
  __shared__ int wt[16];
  if (lane == 63) wt[w] = x;
  __syncthreads();
  int add = 0;
  for (int i = 0; i < w; i++) add += wt[i];
  x += add;
  if (t < n) bsum[t] = x - v;
}

// ---------------- rowptr finalize: rowptr[i] = excl[i]+bsum[i>>8] -----------
__global__ void finalize_rowptr(const int* __restrict__ excl, const int* __restrict__ bsum,
                                int n, int total, int* __restrict__ rowptr) {
  int i = blockIdx.x * 256 + threadIdx.x;
  if (i < n) rowptr[i] = excl[i] + bsum[i >> 8];
  if (i == n) rowptr[n] = total;
}

// ---------------- CSR build: scatter ----------------------------------------
// epool rec: x=src*128, y=tgt_local, z=p0|(p1<<16), w=p2  (bond elem offsets)
__global__ void scatter_edges(const int* __restrict__ ei_m, const int* __restrict__ ea_m, int Em,
                              const int* __restrict__ ei_s, const int* __restrict__ ea_s, int Es, int Nm,
                              const int* __restrict__ rowptr_e,
                              int* __restrict__ cur_e, int4* __restrict__ epool) {
  int i = blockIdx.x * 256 + threadIdx.x;
  int g, tgt, src, a0, a1, a2;
  if (i < Em) {
    tgt = ei_m[i]; src = ei_m[Em + i]; g = tgt;
    a0 = ea_m[i * 3]; a1 = ea_m[i * 3 + 1]; a2 = ea_m[i * 3 + 2];
  } else {
    int j = i - Em; if (j >= Es) return;
    tgt = ei_s[j]; src = ei_s[Es + j]; g = Nm + tgt;
    a0 = ea_s[j * 3]; a1 = ea_s[j * 3 + 1]; a2 = ea_s[j * 3 + 2];
  }
  int slot = rowptr_e[g] + atomicAdd(&cur_e[g], 1);
  int p0 = a0 * 128, p1 = (64 + a1) * 128, p2 = (128 + a2) * 128;
  epool[slot] = make_int4(src * 128, tgt, p0 | (p1 << 16), p2);
}

__global__ void scatter_nodes(const int* __restrict__ bm, int Nm,
                              const int* __restrict__ bs, int Ns, int M,
                              const int* __restrict__ rowptr_n,
                              int* __restrict__ cur_n, int* __restrict__ npool) {
  int i = blockIdx.x * 256 + threadIdx.x;
  int g, node;
  if (i < Nm) { g = bm[i]; node = i; }
  else { int j = i - Nm; if (j >= Ns) return; g = M + bs[j]; node = j; }
  int slot = rowptr_n[g] + atomicAdd(&cur_n[g], 1);
  npool[slot] = node;
}

// ---------------- node embedding (bf16 out) ---------------------------------
__global__ void embed_nodes(const int* __restrict__ x, const float* __restrict__ table,
                            unsigned short* __restrict__ h, int N) {
  int i = blockIdx.x * 256 + threadIdx.x;
  if (i >= N * 128) return;
  int n = i >> 7, c = i & 127;
  float s = 0.f;
#pragma unroll
  for (int f = 0; f < 9; f++) {
    int v = x[n * 9 + f];
    s += table[(f * 64 + v) * 128 + c];
  }
  h[i] = f2bf(s);
}

// ---------------- edge gather: z = (1+eps)*h + sum relu(h[src]+bond) --------
// h, z bf16. 32-row tiles, LDS zacc only (16.9KB) -> high occupancy.
__global__ __launch_bounds__(256, 4) void gather_z(
    const unsigned short* __restrict__ hin, unsigned short* __restrict__ z,
    const float* __restrict__ eps_p, const unsigned short* __restrict__ bt,
    const int4* __restrict__ epool, const int* __restrict__ rowptr_e, int nodebase,
    int N) {
  __shared__ float zacc[32][132];
  int t = threadIdx.x;
  int r0 = blockIdx.x * 32;
  int lane = t & 63, wave = t >> 6;
  float eps1 = 1.0f + *eps_p;
  // init zacc with self-term
  for (int i = t; i < 2048; i += 256) {
    int r = i >> 6, c2 = (i & 63) << 1;
    int n = r0 + r;
    float v0 = 0.f, v1 = 0.f;
    if (n < N) {
      unsigned int u = *(const unsigned int*)(hin + (size_t)n * 128 + c2);
      union { unsigned int u; float f; } a, b;
      a.u = (u & 0xffffu) << 16; b.u = u & 0xffff0000u;
      v0 = eps1 * a.f; v1 = eps1 * b.f;
    }
    zacc[r][c2] = v0; zacc[r][c2 + 1] = v1;
  }
  int gN = (r0 + 32 < N) ? (r0 + 32) : N;
  int e0 = rowptr_e[nodebase + r0], e1 = rowptr_e[nodebase + gN];
  __syncthreads();
  // edge-parallel: 4 edges/wave/iter; 4 loads per edge (1 uint/lane = 2 ch)
  for (int base = e0 + wave * 4; base < e1; base += 16) {
    int4 rec[4];
#pragma unroll
    for (int j = 0; j < 4; j++) {
      int idx = base + j;
      rec[j] = epool[(idx < e1) ? idx : (e1 - 1)];
    }
    unsigned int hv[4], q0[4], q1[4], q2[4];
#pragma unroll
    for (int j = 0; j < 4; j++) {
      hv[j] = *(const unsigned int*)(hin + rec[j].x + lane * 2);
      q0[j] = *(const unsigned int*)(bt + (rec[j].z & 0xffff) + lane * 2);
      q1[j] = *(const unsigned int*)(bt + (((unsigned)rec[j].z) >> 16) + lane * 2);
      q2[j] = *(const unsigned int*)(bt + rec[j].w + lane * 2);
    }
#pragma unroll
    for (int j = 0; j < 4; j++) {
      bool valid = (base + j) < e1;
      union { unsigned int u; float f; } a0, a1, b0, b1, c0, c1, d0, d1;
      a0.u = (hv[j] & 0xffffu) << 16; a1.u = hv[j] & 0xffff0000u;
      b0.u = (q0[j] & 0xffffu) << 16; b1.u = q0[j] & 0xffff0000u;
      c0.u = (q1[j] & 0xffffu) << 16; c1.u = q1[j] & 0xffff0000u;
      d0.u = (q2[j] & 0xffffu) << 16; d1.u = q2[j] & 0xffff0000u;
      float v0 = fmaxf(a0.f + b0.f + c0.f + d0.f, 0.f);
      float v1 = fmaxf(a1.f + b1.f + c1.f + d1.f, 0.f);
      v0 = valid ? v0 : 0.f;
      v1 = valid ? v1 : 0.f;
      int row = rec[j].y - r0;       // in [0,32) for valid slots
      atomicAdd(&zacc[row][lane * 2], v0);
      atomicAdd(&zacc[row][lane * 2 + 1], v1);
    }
  }
  __syncthreads();
  // write z bf16
  for (int i = t; i < 2048; i += 256) {
    int r = i >> 6, c2 = (i & 63) << 1;
    int n = r0 + r;
    if (n < N) {
      unsigned int lo = (unsigned int)f2bf(zacc[r][c2]);
      unsigned int hi = ((unsigned int)f2bf(zacc[r][c2 + 1])) << 16;
      *(unsigned int*)(z + (size_t)n * 128 + c2) = lo | hi;
    }
  }
}

// ---------------- GIN MLP: h = bn2(relu(bn1(z@w1+b1))@w2+b2) (+relu) --------
// z bf16 sequential in, hout bf16. MFMA phases unchanged from verified R2.
__global__ __launch_bounds__(256) void gin_mlp2(
    const unsigned short* __restrict__ zin, unsigned short* __restrict__ hout,
    const unsigned short* __restrict__ w1t, const float* __restrict__ b1,
    const float* __restrict__ g1, const float* __restrict__ be1,
    const unsigned short* __restrict__ w2t, const float* __restrict__ b2,
    const float* __restrict__ g2, const float* __restrict__ be2,
    int N, int do_relu) {
  __shared__ unsigned short zs[64][136];    // 64x128 bf16, +8 pad
  __shared__ unsigned short z1s[64][264];   // 64x256 bf16, +8 pad
  int t = threadIdx.x;
  int r0 = blockIdx.x * 64;
  // Phase A: stage z tile (sequential us4 loads)
  for (int i = t; i < 2048; i += 256) {
    int r = i >> 5, c4 = (i & 31) << 2;
    int n = r0 + r;
    us4 v;
    if (n < N) v = *(const us4*)(zin + (size_t)n * 128 + c4);
    else { v.x = 0; v.y = 0; v.z = 0; v.w = 0; }
    *(us4*)&zs[r][c4] = v;
  }
  __syncthreads();
  int lane = t & 63, wave = t >> 6;
  int quad = lane >> 4, l16 = lane & 15;
  // Phase B: z1[64x256] = relu(bn1(z @ w1 + b1)); wave handles 64 cols
  {
    short8 bw[4][4];
    int cb = wave * 64;
#pragma unroll
    for (int nt = 0; nt < 4; nt++) {
      const unsigned short* p = w1t + (cb + nt * 16 + l16) * 128 + quad * 8;
#pragma unroll
      for (int kc = 0; kc < 4; kc++) bw[nt][kc] = *(const short8*)(p + kc * 32);
    }
#pragma unroll
    for (int mt = 0; mt < 4; mt++) {
      short8 af[4];
#pragma unroll
      for (int kc = 0; kc < 4; kc++)
        af[kc] = *(const short8*)&zs[mt * 16 + l16][kc * 32 + quad * 8];
#pragma unroll
      for (int nt = 0; nt < 4; nt++) {
        f32x4 acc = {0.f, 0.f, 0.f, 0.f};
#pragma unroll
        for (int kc = 0; kc < 4; kc++)
          acc = __builtin_amdgcn_mfma_f32_16x16x32_bf16(af[kc], bw[nt][kc], acc, 0, 0, 0);
        int c = cb + nt * 16 + l16;
        float sc = g1[c] * BN_RSQ, sh = be1[c], bb = b1[c];
#pragma unroll
        for (int reg = 0; reg < 4; reg++) {
          int r = mt * 16 + quad * 4 + reg;
          float y = (acc[reg] + bb) * sc + sh;
          z1s[r][c] = f2bf(fmaxf(y, 0.f));
        }
      }
    }
  }
  __syncthreads();
  // Phase C: h_out = bn2(z1 @ w2 + b2) (+relu); wave handles 32 cols
  {
    short8 bw[2][8];
    int cb = wave * 32;
#pragma unroll
    for (int nt = 0; nt < 2; nt++) {
      const unsigned short* p = w2t + (cb + nt * 16 + l16) * 256 + quad * 8;
#pragma unroll
      for (int kc = 0; kc < 8; kc++) bw[nt][kc] = *(const short8*)(p + kc * 32);
    }
#pragma unroll
    for (int mt = 0; mt < 4; mt++) {
      short8 af[8];
#pragma unroll
      for (int kc = 0; kc < 8; kc++)
        af[kc] = *(const short8*)&z1s[mt * 16 + l16][kc * 32 + quad * 8];
#pragma unroll
      for (int nt = 0; nt < 2; nt++) {
        f32x4 acc = {0.f, 0.f, 0.f, 0.f};
#pragma unroll
        for (int kc = 0; kc < 8; kc++)
          acc = __builtin_amdgcn_mfma_f32_16x16x32_bf16(af[kc], bw[nt][kc], acc, 0, 0, 0);
        int c = cb + nt * 16 + l16;
        float sc = g2[c] * BN_RSQ, sh = be2[c], bb = b2[c];
#pragma unroll
        for (int reg = 0; reg < 4; reg++) {
          int n = r0 + mt * 16 + quad * 4 + reg;
          if (n < N) {
            float y = (acc[reg] + bb) * sc + sh;
            if (do_relu) y = fmaxf(y, 0.f);
            hout[n * 128 + c] = f2bf(y);
          }
        }
      }
    }
  }
}

// ---------------- CSR mean pooling (bf16 h) ---------------------------------
__global__ __launch_bounds__(128) void pool_csr(const unsigned short* __restrict__ h,
                                                const int* __restrict__ npool,
                                                const int* __restrict__ rowptr_n,
                                                int segbase, float* __restrict__ pooled, int nseg) {
  int m = blockIdx.x;
  if (m >= nseg) return;
  int g = segbase + m;
  int st = rowptr_n[g];
  int e = rowptr_n[g + 1];
  int len = e - st;
  int c = threadIdx.x;
  float s = 0.f;
  int i = st;
  for (; i + 3 < e; i += 4) {
    int n0 = npool[i], n1 = npool[i + 1], n2 = npool[i + 2], n3 = npool[i + 3];
    float v0 = bf2f(h[(size_t)n0 * 128 + c]);
    float v1 = bf2f(h[(size_t)n1 * 128 + c]);
    float v2 = bf2f(h[(size_t)n2 * 128 + c]);
    float v3 = bf2f(h[(size_t)n3 * 128 + c]);
    s += (v0 + v1) + (v2 + v3);
  }
  for (; i < e; i++) s += bf2f(h[(size_t)npool[i] * 128 + c]);
  pooled[m * 128 + c] = s / ((float)len + 1e-9f);
}

// ---------------- small generic GEMM: C = A[MxK] @ W[KxN] + bias -----------
__global__ void gemm_small(const float* __restrict__ A, const float* __restrict__ W,
                           const float* __restrict__ bias, float* __restrict__ C,
                           int M, int N, int K) {
  int i = blockIdx.x * 256 + threadIdx.x;
  if (i >= M * N) return;
  int r = i / N, c = i - r * N;
  float acc = bias ? bias[c] : 0.f;
  const float* a = A + (size_t)r * K;
  for (int k = 0; k < K; k++) acc = fmaf(a[k], W[(size_t)k * N + c], acc);
  C[i] = acc;
}

// ---------------- SAB attention: O = Qs + softmax(QsKs^T/8) Vs -------------
__global__ __launch_bounds__(256) void sab_attn(const float* __restrict__ Q, const float* __restrict__ K,
                                                const float* __restrict__ V, float* __restrict__ O, int S) {
  int q = blockIdx.x, hd = blockIdx.y;
  int t = threadIdx.x;
  __shared__ float sc[512];
  __shared__ float red[8];
  __shared__ float pacc[4][64];
  const float* qrow = Q + q * 128 + hd * 64;
  for (int k = t; k < 512; k += 256) {
    float d = -1e30f;
    if (k < S) {
      const float* krow = K + k * 128 + hd * 64;
      d = 0.f;
#pragma unroll
      for (int j = 0; j < 64; j += 4) {
        float4 a = *(const float4*)(qrow + j);
        float4 b = *(const float4*)(krow + j);
        d += a.x * b.x + a.y * b.y + a.z * b.z + a.w * b.w;
      }
      d *= 0.125f;
    }
    sc[k] = d;
  }
  __syncthreads();
  float m = fmaxf(sc[t], sc[t + 256]);
  for (int off = 32; off; off >>= 1) m = fmaxf(m, __shfl_down(m, off));
  if ((t & 63) == 0) red[t >> 6] = m;
  __syncthreads();
  m = fmaxf(fmaxf(red[0], red[1]), fmaxf(red[2], red[3]));
  float p0 = __expf(sc[t] - m), p1 = __expf(sc[t + 256] - m);
  sc[t] = p0; sc[t + 256] = p1;
  float s = p0 + p1;
  for (int off = 32; off; off >>= 1) s += __shfl_down(s, off);
  if ((t & 63) == 0) red[4 + (t >> 6)] = s;
  __syncthreads();
  float inv = 1.f / (red[4] + red[5] + red[6] + red[7]);
  int d = t & 63, part = t >> 6;
  float acc = 0.f;
  for (int k = part; k < S; k += 4) acc += sc[k] * V[k * 128 + hd * 64 + d];
  pacc[part][d] = acc;
  __syncthreads();
  if (part == 0) {
    float o = (pacc[0][d] + pacc[1][d] + pacc[2][d] + pacc[3][d]) * inv;
    O[q * 128 + hd * 64 + d] = qrow[d] + o;
  }
}

// ---------------- row LayerNorm over 128 ------------------------------------
__global__ __launch_bounds__(128) void ln_rows(const float* __restrict__ in, float* __restrict__ out,
                                               const float* __restrict__ g, const float* __restrict__ b) {
  int r = blockIdx.x, t = threadIdx.x;
  __shared__ float red[4];
  float x = in[r * 128 + t];
  float s = x;
  for (int off = 32; off; off >>= 1) s += __shfl_down(s, off);
  if ((t & 63) == 0) red[t >> 6] = s;
  __syncthreads();
  float mu = (red[0] + red[1]) * (1.f / 128.f);
  float dd = x - mu;
  float v = dd * dd;
  for (int off = 32; off; off >>= 1) v += __shfl_down(v, off);
  if ((t & 63) == 0) red[2 + (t >> 6)] = v;
  __syncthreads();
  float var = (red[2] + red[3]) * (1.f / 128.f);
  out[r * 128 + t] = g[t] * dd * rsqrtf(var + LN_EPS) + b[t];
}

// ---------------- masked softmax attn: attn[d,s] ----------------------------
__global__ __launch_bounds__(256) void agg_attn(const float* __restrict__ Q, const float* __restrict__ Kt,
                                                const void* __restrict__ mask, const int* __restrict__ flags,
                                                float* __restrict__ attn, int D, int S) {
  int d = blockIdx.x, t = threadIdx.x;
  __shared__ float sc[512];
  __shared__ float red[8];
  int layout = (flags[1] == 0) ? 0 : (flags[0] ? 1 : 2);
  const float* qrow = Q + d * 128;
  for (int s = t; s < 512; s += 256) {
    float v = NEGBIG;
    if (s < S) {
      int mi = d * S + s;
      bool msk;
      if (layout == 0)      msk = ((const int*)mask)[mi] != 0;
      else if (layout == 1) msk = ((const unsigned char*)mask)[mi] != 0;
      else                  msk = ((const float*)mask)[mi] != 0.f;
      if (!msk) {
        float dd = 0.f;
        const float* krow = Kt + s * 128;
#pragma unroll
        for (int j = 0; j < 128; j += 4) {
          float4 a = *(const float4*)(qrow + j);
          float4 b = *(const float4*)(krow + j);
          dd += a.x * b.x + a.y * b.y + a.z * b.z + a.w * b.w;
        }
        v = dd * 0.08838834764831845f;
      }
    }
    sc[s] = v;
  }
  __syncthreads();
  float m = fmaxf(sc[t], sc[t + 256]);
  for (int off = 32; off; off >>= 1) m = fmaxf(m, __shfl_down(m, off));
  if ((t & 63) == 0) red[t >> 6] = m;
  __syncthreads();
  m = fmaxf(fmaxf(red[0], red[1]), fmaxf(red[2], red[3]));
  float p0 = __expf(sc[t] - m), p1 = __expf(sc[t + 256] - m);
  float s2 = p0 + p1;
  for (int off = 32; off; off >>= 1) s2 += __shfl_down(s2, off);
  if ((t & 63) == 0) red[4 + (t >> 6)] = s2;
  __syncthreads();
  float inv = 1.f / (red[4] + red[5] + red[6] + red[7]);
  attn[d * S + t] = p0 * inv;
  if (t + 256 < S) attn[d * S + t + 256] = p1 * inv;
}

// ---------------- subT prep: subf [S][128] f32 -> subT bf16 [128][512] ------
__global__ void prep_subT(const float* __restrict__ subf, unsigned short* __restrict__ subT, int S) {
  int i = blockIdx.x * 256 + threadIdx.x;
  if (i >= 128 * 512) return;
  int hh = i >> 9, k = i & 511;
  subT[i] = (k < S) ? f2bf(subf[k * 128 + hh]) : (unsigned short)0;
}

// ---------------- agg via MFMA: per d, (pat .* attn[d])[64x492] @ sub -------
__global__ __launch_bounds__(256) void agg_mfma(const float* __restrict__ attn, const float* __restrict__ pat,
                                                const unsigned short* __restrict__ subT,
                                                float* __restrict__ aggT, int D, int S) {
  int d = blockIdx.x, t = threadIdx.x;
  __shared__ unsigned short As[64][40];
  int lane = t & 63, wave = t >> 6;
  int quad = lane >> 4, l16 = lane & 15;
  f32x4 acc[8];
#pragma unroll
  for (int nt = 0; nt < 8; nt++) acc[nt] = (f32x4){0.f, 0.f, 0.f, 0.f};
  const float* arow = attn + d * S;
  int srow = t >> 2, skb = (t & 3) * 8;
  for (int c = 0; c < 16; c++) {
    int s0 = c * 32;
    __syncthreads();
    unsigned short v[8];
#pragma unroll
    for (int j = 0; j < 8; j++) {
      int s = s0 + skb + j;
      float x = (s < S) ? arow[s] * pat[srow * S + s] : 0.f;
      v[j] = f2bf(x);
    }
    *(us4*)&As[srow][skb]     = *(us4*)&v[0];
    *(us4*)&As[srow][skb + 4] = *(us4*)&v[4];
    __syncthreads();
    short8 af = *(const short8*)&As[16 * wave + l16][quad * 8];
#pragma unroll
    for (int nt = 0; nt < 8; nt++) {
      short8 bf = *(const short8*)(subT + (nt * 16 + l16) * 512 + s0 + quad * 8);
      acc[nt] = __builtin_amdgcn_mfma_f32_16x16x32_bf16(af, bf, acc[nt], 0, 0, 0);
    }
  }
#pragma unroll
  for (int nt = 0; nt < 8; nt++) {
    int hh = nt * 16 + l16;
#pragma unroll
    for (int reg = 0; reg < 4; reg++) {
      int b = 16 * wave + quad * 4 + reg;
      aggT[((size_t)(b * D + d)) * 128 + hh] = acc[nt][reg];
    }
  }
}

// ---------------- score head: sigmoid(relu(agg@w1+b1)@w2+b2) ---------------
__global__ __launch_bounds__(64) void score_head(const float* __restrict__ aggT,
                                                 const float* __restrict__ w1, const float* __restrict__ b1,
                                                 const float* __restrict__ w2, const float* __restrict__ b2,
                                                 float* __restrict__ out) {
  int i = blockIdx.x;
  int j = threadIdx.x;
  const float* av = aggT + (size_t)i * 128;
  float acc = b1[j];
#pragma unroll 8
  for (int k = 0; k < 128; k++) acc = fmaf(av[k], w1[k * 64 + j], acc);
  acc = fmaxf(acc, 0.f) * w2[j];
  for (int off = 32; off; off >>= 1) acc += __shfl_down(acc, off);
  if (j == 0) {
    float x = acc + b2[0];
    out[i] = 1.f / (1.f + __expf(-x));
  }
}

// ---------------------------------------------------------------------------
extern "C" void kernel_launch(void* const* d_in, const int* in_sizes, int n_in,
                              void* d_out, int out_size, void* d_ws, size_t ws_size,
                              hipStream_t stream) {
  const float* atom_emb = (const float*)d_in[0];
  const float* bond_emb = (const float*)d_in[1];
  const float* gin_eps  = (const float*)d_in[2];
  const float* gin_w1   = (const float*)d_in[3];
  const float* gin_b1   = (const float*)d_in[4];
  const float* bn1g     = (const float*)d_in[5];
  const float* bn1b     = (const float*)d_in[6];
  const float* gin_w2   = (const float*)d_in[7];
  const float* gin_b2   = (const float*)d_in[8];
  const float* bn2g     = (const float*)d_in[9];
  const float* bn2b     = (const float*)d_in[10];
  const float* sab_wq = (const float*)d_in[11];
  const float* sab_wk = (const float*)d_in[12];
  const float* sab_wv = (const float*)d_in[13];
  const float* sab_wo = (const float*)d_in[14];
  const float* sab_bq = (const float*)d_in[15];
  const float* sab_bk = (const float*)d_in[16];
  const float* sab_bv = (const float*)d_in[17];
  const float* sab_bo = (const float*)d_in[18];
  const float* ln1b = (const float*)d_in[19];
  const float* ln2b = (const float*)d_in[20];
  const float* ln1g = (const float*)d_in[21];
  const float* ln2g = (const float*)d_in[22];
  const float* agg_wq = (const float*)d_in[23];
  const float* agg_bq = (const float*)d_in[24];
  const float* agg_wk = (const float*)d_in[25];
  const float* agg_bk = (const float*)d_in[26];
  const float* score_w1 = (const float*)d_in[27];
  const float* score_b1 = (const float*)d_in[28];
  const float* score_w2 = (const float*)d_in[29];
  const float* score_b2 = (const float*)d_in[30];
  const float* patient  = (const float*)d_in[31];
  const float* avgproj  = (const float*)d_in[32];
  const int* sub_x     = (const int*)d_in[33];
  const int* sub_ea    = (const int*)d_in[34];
  const int* sub_ei    = (const int*)d_in[35];
  const int* sub_batch = (const int*)d_in[36];
  const int* mol_x     = (const int*)d_in[37];
  const int* mol_ea    = (const int*)d_in[38];
  const int* mol_ei    = (const int*)d_in[39];
  const int* mol_batch = (const int*)d_in[40];
  const void* mask     = d_in[41];

  const int Ns = in_sizes[33] / 9, Es = in_sizes[34] / 3;
  const int Nm = in_sizes[37] / 9, Em = in_sizes[38] / 3;
  const int S = 492, M = 600, D = 200, B = 64;
  const int NE = Nm + Ns;           // edge-CSR index space (mol first)
  const int NSEG = M + S;           // node-CSR index space (mol first)
  const int ETOT = Em + Es;
  const int BONDE = 2 * 4 * 3 * 64 * 128;   // bond table elements

  // ---- workspace carve-up ----
  char* Wp = (char*)d_ws;
  size_t off = 0;
  auto alloc = [&](size_t bytes) -> void* {
    void* p = Wp + off;
    off = (off + bytes + 255) & ~(size_t)255;
    return p;
  };
  int NR = ((Nm > Ns ? Nm : Ns) + 63) & ~63;
  unsigned short* h0 = (unsigned short*)alloc((size_t)NR * 128 * 2);
  unsigned short* h1 = (unsigned short*)alloc((size_t)NR * 128 * 2);
  unsigned short* zb = (unsigned short*)alloc((size_t)NR * 128 * 2);
  unsigned short* w1t = (unsigned short*)alloc(262144 * 2);
  unsigned short* w2t = (unsigned short*)alloc(262144 * 2);
  unsigned short* bt16 = (unsigned short*)alloc((size_t)BONDE * 2);
  int4* epool  = (int4*)alloc((size_t)ETOT * 16);
  int*  npool  = (int*)alloc((size_t)NE * 4);
  int*  excl_e = (int*)alloc((size_t)NE * 4);
  int*  bsum_e = (int*)alloc(1024 * 4);
  int*  excl_n = (int*)alloc((size_t)NSEG * 4);
  int*  bsum_n = (int*)alloc(1024 * 4);
  int*  rowptr_e = (int*)alloc((size_t)(NE + 1) * 4);
  int*  rowptr_n = (int*)alloc((size_t)(NSEG + 1) * 4);
  char* zstart = Wp + off;                       // region zeroed below
  int*  deg_e  = (int*)alloc((size_t)NE * 4);
  int*  deg_n  = (int*)alloc((size_t)NSEG * 4);
  int*  cur_e  = (int*)alloc((size_t)NE * 4);
  int*  cur_n  = (int*)alloc((size_t)NSEG * 4);
  int*  flags  = (int*)alloc(8);
  size_t zsize = (size_t)((Wp + off) - zstart);
  float* pooled_sub = (float*)alloc((size_t)S * 128 * 4);
  float* pooled_mol = (float*)alloc((size_t)M * 128 * 4);
  float* Qb   = (float*)alloc((size_t)S * 128 * 4);
  float* Kb   = (float*)alloc((size_t)S * 128 * 4);
  float* Vb   = (float*)alloc((size_t)S * 128 * 4);
  float* Ob   = (float*)alloc((size_t)S * 128 * 4);
  float* O2b  = (float*)alloc((size_t)S * 128 * 4);
  float* subf = (float*)alloc((size_t)S * 128 * 4);
  unsigned short* subT = (unsigned short*)alloc((size_t)128 * 512 * 2);
  float* mol_embb = (float*)alloc((size_t)D * 128 * 4);
  float* aggQb = (float*)alloc((size_t)D * 128 * 4);
  float* aggKb = (float*)alloc((size_t)S * 128 * 4);
  float* attnb = (float*)alloc((size_t)D * S * 4);
  float* aggTb = (float*)alloc((size_t)B * D * 128 * 4);
  (void)ws_size; (void)n_in; (void)out_size;

  hipMemsetAsync(zstart, 0, zsize, stream);
  prep_weights<<<1024, 256, 0, stream>>>(gin_w1, gin_w2, w1t, w2t);
  prep_bond<<<(BONDE + 255) / 256, 256, 0, stream>>>(bond_emb, bt16, BONDE);
  mask_detect<<<(D * S + 255) / 256, 256, 0, stream>>>((const unsigned char*)mask, flags, D * S);

  // ---- CSR build (edges by tgt; nodes by batch) ----
  int total_cnt = Em + Es + Nm + Ns;
  build_count<<<(total_cnt + 255) / 256, 256, 0, stream>>>(
      mol_ei, Em, sub_ei, Es, mol_batch, Nm, sub_batch, Ns, deg_e, deg_n, M);
  int nb_e = (NE + 255) / 256;        // <= 1024
  int nb_n = (NSEG + 255) / 256;
  scan_block<<<nb_e, 256, 0, stream>>>(deg_e, NE, excl_e, bsum_e);
  scan_top<<<1, 1024, 0, stream>>>(bsum_e, nb_e);
  scan_block<<<nb_n, 256, 0, stream>>>(deg_n, NSEG, excl_n, bsum_n);
  scan_top<<<1, 1024, 0, stream>>>(bsum_n, nb_n);
  finalize_rowptr<<<(NE + 256) / 256 + 1, 256, 0, stream>>>(excl_e, bsum_e, NE, ETOT, rowptr_e);
  finalize_rowptr<<<(NSEG + 256) / 256 + 1, 256, 0, stream>>>(excl_n, bsum_n, NSEG, NE, rowptr_n);
  scatter_edges<<<(ETOT + 255) / 256, 256, 0, stream>>>(
      mol_ei, mol_ea, Em, sub_ei, sub_ea, Es, Nm, rowptr_e, cur_e, epool);
  scatter_nodes<<<(NE + 255) / 256, 256, 0, stream>>>(
      mol_batch, Nm, sub_batch, Ns, M, rowptr_n, cur_n, npool);

  auto run_gin = [&](int g, int N, const int* x, int nodebase, int segbase,
                     float* pooled, int nseg) {
    embed_nodes<<<(N * 128 + 255) / 256, 256, 0, stream>>>(
        x, atom_emb + (size_t)g * 9 * 64 * 128, h0, N);
    unsigned short* hin = h0; unsigned short* hout = h1;
    for (int l = 0; l < 4; l++) {
      int gl = g * 4 + l;
      gather_z<<<(N + 31) / 32, 256, 0, stream>>>(
          hin, zb, gin_eps + gl, bt16 + (size_t)gl * 3 * 64 * 128,
          epool, rowptr_e, nodebase, N);
      gin_mlp2<<<(N + 63) / 64, 256, 0, stream>>>(
          zb, hout,
          w1t + (size_t)gl * 32768, gin_b1 + gl * 256, bn1g + gl * 256, bn1b + gl * 256,
          w2t + (size_t)gl * 32768, gin_b2 + gl * 128, bn2g + gl * 128, bn2b + gl * 128,
          N, (l != 3) ? 1 : 0);
      unsigned short* tmp = hin; hin = hout; hout = tmp;
    }
    pool_csr<<<nseg, 128, 0, stream>>>(hin, npool, rowptr_n, segbase, pooled, nseg);
  };

  // --- substructure encoder + SAB ---
  run_gin(0, Ns, sub_x, Nm, M, pooled_sub, S);
  gemm_small<<<(S * 128 + 255) / 256, 256, 0, stream>>>(pooled_sub, sab_wq, sab_bq, Qb, S, 128, 128);
  gemm_small<<<(S * 128 + 255) / 256, 256, 0, stream>>>(pooled_sub, sab_wk, sab_bk, Kb, S, 128, 128);
  gemm_small<<<(S * 128 + 255) / 256, 256, 0, stream>>>(pooled_sub, sab_wv, sab_bv, Vb, S, 128, 128);
  sab_attn<<<dim3(S, 2), 256, 0, stream>>>(Qb, Kb, Vb, Ob, S);
  ln_rows<<<S, 128, 0, stream>>>(Ob, Ob, ln1g, ln1b);
  gemm_small<<<(S * 128 + 255) / 256, 256, 0, stream>>>(Ob, sab_wo, sab_bo, O2b, S, 128, 128);
  ln_rows<<<S, 128, 0, stream>>>(O2b, subf, ln2g, ln2b);
  prep_subT<<<(128 * 512 + 255) / 256, 256, 0, stream>>>(subf, subT, S);

  // --- molecule encoder + projection ---
  run_gin(1, Nm, mol_x, 0, 0, pooled_mol, M);
  gemm_small<<<(D * 128 + 255) / 256, 256, 0, stream>>>(avgproj, pooled_mol, (const float*)nullptr, mol_embb, D, 128, M);

  // --- attention aggregation + score ---
  gemm_small<<<(D * 128 + 255) / 256, 256, 0, stream>>>(mol_embb, agg_wq, agg_bq, aggQb, D, 128, 128);
  gemm_small<<<(S * 128 + 255) / 256, 256, 0, stream>>>(subf, agg_wk, agg_bk, aggKb, S, 128, 128);
  agg_attn<<<D, 256, 0, stream>>>(aggQb, aggKb, mask, flags, attnb, D, S);
  agg_mfma<<<D, 256, 0, stream>>>(attnb, patient, subT, aggTb, D, S);
  score_head<<<B * D, 64, 0, stream>>>(aggTb, score_w1, score_b1, score_w2, score_b2, (float*)d_out);
}

// Round 7
// 1613.236 us; speedup vs baseline: 1.7897x; 1.7897x over previous
//
#include <hip/hip_runtime.h>

// ---------------------------------------------------------------------------
// MoleRec pipeline on gfx950.
// R6: edge-parallel gather disproven twice (R3-R6: high occupancy + half the
//     bytes still ~260us; all waves in s_waitcnt). Controlling variable is
//     independent loads in flight per wave-slot, not occupancy. gather_z is
//     now node-parallel (R2's winning structure) in bf16: 8 threads/node x
//     16 ch, register accumulation, no LDS, no atomics; per edge 8
//     independent 16B loads issued at once. MLP stays split (gin_mlp2).
// ---------------------------------------------------------------------------

typedef short short8 __attribute__((ext_vector_type(8)));
typedef unsigned short us8 __attribute__((ext_vector_type(8)));
typedef float f32x4 __attribute__((ext_vector_type(4)));
typedef unsigned short us4 __attribute__((ext_vector_type(4)));

#define BN_RSQ 0.9999950000374997f   // 1/sqrt(1+1e-5)  (BatchNorm eval, var=1)
#define LN_EPS 1e-5f
#define NEGBIG -4294967296.0f        // -(1<<32), matches reference mask fill

__device__ __forceinline__ unsigned short f2bf(float x) {
  union { float f; unsigned int u; } v; v.f = x;
  unsigned int r = v.u + 0x7fffu + ((v.u >> 16) & 1u);   // RNE
  return (unsigned short)(r >> 16);
}
__device__ __forceinline__ float bf2f(unsigned short x) {
  union { unsigned int u; float f; } v; v.u = ((unsigned int)x) << 16;
  return v.f;
}

// ---------------- weight prep: fp32 [K][N] -> bf16 [N][K] ------------------
__global__ void prep_weights(const float* __restrict__ w1, const float* __restrict__ w2,
                             unsigned short* __restrict__ w1t, unsigned short* __restrict__ w2t) {
  int i = blockIdx.x * 256 + threadIdx.x;
  if (i >= 262144) return;
  int gl = i >> 15;
  int k1 = (i >> 8) & 127, c1 = i & 255;
  w1t[(gl << 15) + c1 * 128 + k1] = f2bf(w1[i]);
  int k2 = (i >> 7) & 255, c2 = i & 127;
  w2t[(gl << 15) + c2 * 256 + k2] = f2bf(w2[i]);
}

// ---------------- bond tables fp32 -> bf16 (same layout) --------------------
__global__ void prep_bond(const float* __restrict__ in, unsigned short* __restrict__ out, int n) {
  int i = blockIdx.x * 256 + threadIdx.x;
  if (i < n) out[i] = f2bf(in[i]);
}

// ---------------- mask layout detection ------------------------------------
__global__ void mask_detect(const unsigned char* __restrict__ m, int* __restrict__ flags, int nbytes) {
  int i = blockIdx.x * 256 + threadIdx.x;
  if (i < nbytes && m[i]) {
    if ((i & 3) == 0) atomicOr(flags, 1);
    else atomicOr(flags + 1, 1);
  }
}

// ---------------- CSR build: count ------------------------------------------
__global__ void build_count(const int* __restrict__ ei_m, int Em,
                            const int* __restrict__ ei_s, int Es,
                            const int* __restrict__ bm, int Nm,
                            const int* __restrict__ bs, int Ns,
                            int* __restrict__ deg_e, int* __restrict__ deg_n, int M) {
  int i = blockIdx.x * 256 + threadIdx.x;
  if (i < Em) { atomicAdd(&deg_e[ei_m[i]], 1); return; }
  i -= Em;
  if (i < Es) { atomicAdd(&deg_e[Nm + ei_s[i]], 1); return; }
  i -= Es;
  if (i < Nm) { atomicAdd(&deg_n[bm[i]], 1); return; }
  i -= Nm;
  if (i < Ns) { atomicAdd(&deg_n[M + bs[i]], 1); }
}

// ---------------- CSR build: block-level exclusive scan ---------------------
__global__ __launch_bounds__(256) void scan_block(const int* __restrict__ cnt, int n,
                                                  int* __restrict__ excl, int* __restrict__ bsum) {
  int gid = blockIdx.x * 256 + threadIdx.x;
  int lane = threadIdx.x & 63, w = threadIdx.x >> 6;
  int v = (gid < n) ? cnt[gid] : 0;
  int x = v;
#pragma unroll
  for (int off = 1; off < 64; off <<= 1) {
    int y = __shfl_up(x, off, 64);
    if (lane >= off) x += y;
  }
  __shared__ int wt[4];
  if (lane == 63) wt[w] = x;
  __syncthreads();
  int add = 0;
  for (int i = 0; i < w; i++) add += wt[i];
  x += add;
  if (gid < n) excl[gid] = x - v;
  if (threadIdx.x == 255) bsum[blockIdx.x] = x;
}

__global__ __launch_bounds__(1024) void scan_top(int* __restrict__ bsum, int n) {
  int t = threadIdx.x;
  int lane = t & 63, w = t >> 6;
  int v = (t < n) ? bsum[t] : 0;
  int x = v;
#pragma unroll
  for (int off = 1; off < 64; off <<= 1) {
    int y = __shfl_up(x, off, 64);
    if (lane >= off) x += y;
  }
  __shared__ int wt[16];
  if (lane == 63) wt[w] = x;
  __syncthreads();
  int add = 0;
  for (int i = 0; i < w; i++) add += wt[i];
  x += add;
  if (t < n) bsum[t] = x - v;
}

// ---------------- rowptr finalize: rowptr[i] = excl[i]+bsum[i>>8] -----------
__global__ void finalize_rowptr(const int* __restrict__ excl, const int* __restrict__ bsum,
                                int n, int total, int* __restrict__ rowptr) {
  int i = blockIdx.x * 256 + threadIdx.x;
  if (i < n) rowptr[i] = excl[i] + bsum[i >> 8];
  if (i == n) rowptr[n] = total;
}

// ---------------- CSR build: scatter ----------------------------------------
// epool rec: x=src*128, y=tgt_local, z=p0|(p1<<16), w=p2  (bond elem offsets)
__global__ void scatter_edges(const int* __restrict__ ei_m, const int* __restrict__ ea_m, int Em,
                              const int* __restrict__ ei_s, const int* __restrict__ ea_s, int Es, int Nm,
                              const int* __restrict__ rowptr_e,
                              int* __restrict__ cur_e, int4* __restrict__ epool) {
  int i = blockIdx.x * 256 + threadIdx.x;
  int g, tgt, src, a0, a1, a2;
  if (i < Em) {
    tgt = ei_m[i]; src = ei_m[Em + i]; g = tgt;
    a0 = ea_m[i * 3]; a1 = ea_m[i * 3 + 1]; a2 = ea_m[i * 3 + 2];
  } else {
    int j = i - Em; if (j >= Es) return;
    tgt = ei_s[j]; src = ei_s[Es + j]; g = Nm + tgt;
    a0 = ea_s[j * 3]; a1 = ea_s[j * 3 + 1]; a2 = ea_s[j * 3 + 2];
  }
  int slot = rowptr_e[g] + atomicAdd(&cur_e[g], 1);
  int p0 = a0 * 128, p1 = (64 + a1) * 128, p2 = (128 + a2) * 128;
  epool[slot] = make_int4(src * 128, tgt, p0 | (p1 << 16), p2);
}

__global__ void scatter_nodes(const int* __restrict__ bm, int Nm,
                              const int* __restrict__ bs, int Ns, int M,
                              const int* __restrict__ rowptr_n,
                              int* __restrict__ cur_n, int* __restrict__ npool) {
  int i = blockIdx.x * 256 + threadIdx.x;
  int g, node;
  if (i < Nm) { g = bm[i]; node = i; }
  else { int j = i - Nm; if (j >= Ns) return; g = M + bs[j]; node = j; }
  int slot = rowptr_n[g] + atomicAdd(&cur_n[g], 1);
  npool[slot] = node;
}

// ---------------- node embedding (bf16 out) ---------------------------------
__global__ void embed_nodes(const int* __restrict__ x, const float* __restrict__ table,
                            unsigned short* __restrict__ h, int N) {
  int i = blockIdx.x * 256 + threadIdx.x;
  if (i >= N * 128) return;
  int n = i >> 7, c = i & 127;
  float s = 0.f;
#pragma unroll
  for (int f = 0; f < 9; f++) {
    int v = x[n * 9 + f];
    s += table[(f * 64 + v) * 128 + c];
  }
  h[i] = f2bf(s);
}

// ---------------- edge gather: z = (1+eps)*h + sum relu(h[src]+bond) --------
// Node-parallel, LDS-free: 8 threads/node x 16 ch, register accumulation.
// Per edge: 1 rec load -> 8 independent 16B loads; no atomics.
__global__ __launch_bounds__(256) void gather_z(
    const unsigned short* __restrict__ hin, unsigned short* __restrict__ z,
    const float* __restrict__ eps_p, const unsigned short* __restrict__ bt,
    const int4* __restrict__ epool, const int* __restrict__ rowptr_e, int nodebase,
    int N) {
  int gid = blockIdx.x * 256 + threadIdx.x;
  int n = gid >> 3;
  if (n >= N) return;
  int cb = (gid & 7) * 16;
  float eps1 = 1.0f + *eps_p;
  float acc[16];
  {
    const unsigned short* hr = hin + (size_t)n * 128 + cb;
    us8 v0 = *(const us8*)hr, v1 = *(const us8*)(hr + 8);
#pragma unroll
    for (int k = 0; k < 8; k++) {
      acc[k]     = eps1 * bf2f(v0[k]);
      acc[8 + k] = eps1 * bf2f(v1[k]);
    }
  }
  int e0 = rowptr_e[nodebase + n], e1 = rowptr_e[nodebase + n + 1];
  for (int e = e0; e < e1; e++) {
    int4 rec = epool[e];
    const unsigned short* hs = hin + rec.x + cb;
    const unsigned short* q0 = bt + (rec.z & 0xffff) + cb;
    const unsigned short* q1 = bt + (((unsigned)rec.z) >> 16) + cb;
    const unsigned short* q2 = bt + rec.w + cb;
    us8 a0 = *(const us8*)hs, a1 = *(const us8*)(hs + 8);
    us8 b0 = *(const us8*)q0, b1 = *(const us8*)(q0 + 8);
    us8 c0 = *(const us8*)q1, c1 = *(const us8*)(q1 + 8);
    us8 d0 = *(const us8*)q2, d1 = *(const us8*)(q2 + 8);
#pragma unroll
    for (int k = 0; k < 8; k++) {
      acc[k]     += fmaxf(bf2f(a0[k]) + bf2f(b0[k]) + bf2f(c0[k]) + bf2f(d0[k]), 0.f);
      acc[8 + k] += fmaxf(bf2f(a1[k]) + bf2f(b1[k]) + bf2f(c1[k]) + bf2f(d1[k]), 0.f);
    }
  }
  unsigned short ob[16];
#pragma unroll
  for (int k = 0; k < 16; k++) ob[k] = f2bf(acc[k]);
  unsigned short* zr = z + (size_t)n * 128 + cb;
  *(us8*)zr = *(const us8*)&ob[0];
  *(us8*)(zr + 8) = *(const us8*)&ob[8];
}

// ---------------- GIN MLP: h = bn2(relu(bn1(z@w1+b1))@w2+b2) (+relu) --------
__global__ __launch_bounds__(256) void gin_mlp2(
    const unsigned short* __restrict__ zin, unsigned short* __restrict__ hout,
    const unsigned short* __restrict__ w1t, const float* __restrict__ b1,
    const float* __restrict__ g1, const float* __restrict__ be1,
    const unsigned short* __restrict__ w2t, const float* __restrict__ b2,
    const float* __restrict__ g2, const float* __restrict__ be2,
    int N, int do_relu) {
  __shared__ unsigned short zs[64][136];    // 64x128 bf16, +8 pad
  __shared__ unsigned short z1s[64][264];   // 64x256 bf16, +8 pad
  int t = threadIdx.x;
  int r0 = blockIdx.x * 64;
  for (int i = t; i < 2048; i += 256) {
    int r = i >> 5, c4 = (i & 31) << 2;
    int n = r0 + r;
    us4 v;
    if (n < N) v = *(const us4*)(zin + (size_t)n * 128 + c4);
    else { v.x = 0; v.y = 0; v.z = 0; v.w = 0; }
    *(us4*)&zs[r][c4] = v;
  }
  __syncthreads();
  int lane = t & 63, wave = t >> 6;
  int quad = lane >> 4, l16 = lane & 15;
  // Phase B: z1[64x256] = relu(bn1(z @ w1 + b1)); wave handles 64 cols
  {
    short8 bw[4][4];
    int cb = wave * 64;
#pragma unroll
    for (int nt = 0; nt < 4; nt++) {
      const unsigned short* p = w1t + (cb + nt * 16 + l16) * 128 + quad * 8;
#pragma unroll
      for (int kc = 0; kc < 4; kc++) bw[nt][kc] = *(const short8*)(p + kc * 32);
    }
#pragma unroll
    for (int mt = 0; mt < 4; mt++) {
      short8 af[4];
#pragma unroll
      for (int kc = 0; kc < 4; kc++)
        af[kc] = *(const short8*)&zs[mt * 16 + l16][kc * 32 + quad * 8];
#pragma unroll
      for (int nt = 0; nt < 4; nt++) {
        f32x4 acc = {0.f, 0.f, 0.f, 0.f};
#pragma unroll
        for (int kc = 0; kc < 4; kc++)
          acc = __builtin_amdgcn_mfma_f32_16x16x32_bf16(af[kc], bw[nt][kc], acc, 0, 0, 0);
        int c = cb + nt * 16 + l16;
        float sc = g1[c] * BN_RSQ, sh = be1[c], bb = b1[c];
#pragma unroll
        for (int reg = 0; reg < 4; reg++) {
          int r = mt * 16 + quad * 4 + reg;
          float y = (acc[reg] + bb) * sc + sh;
          z1s[r][c] = f2bf(fmaxf(y, 0.f));
        }
      }
    }
  }
  __syncthreads();
  // Phase C: h_out = bn2(z1 @ w2 + b2) (+relu); wave handles 32 cols
  {
    short8 bw[2][8];
    int cb = wave * 32;
#pragma unroll
    for (int nt = 0; nt < 2; nt++) {
      const unsigned short* p = w2t + (cb + nt * 16 + l16) * 256 + quad * 8;
#pragma unroll
      for (int kc = 0; kc < 8; kc++) bw[nt][kc] = *(const short8*)(p + kc * 32);
    }
#pragma unroll
    for (int mt = 0; mt < 4; mt++) {
      short8 af[8];
#pragma unroll
      for (int kc = 0; kc < 8; kc++)
        af[kc] = *(const short8*)&z1s[mt * 16 + l16][kc * 32 + quad * 8];
#pragma unroll
      for (int nt = 0; nt < 2; nt++) {
        f32x4 acc = {0.f, 0.f, 0.f, 0.f};
#pragma unroll
        for (int kc = 0; kc < 8; kc++)
          acc = __builtin_amdgcn_mfma_f32_16x16x32_bf16(af[kc], bw[nt][kc], acc, 0, 0, 0);
        int c = cb + nt * 16 + l16;
        float sc = g2[c] * BN_RSQ, sh = be2[c], bb = b2[c];
#pragma unroll
        for (int reg = 0; reg < 4; reg++) {
          int n = r0 + mt * 16 + quad * 4 + reg;
          if (n < N) {
            float y = (acc[reg] + bb) * sc + sh;
            if (do_relu) y = fmaxf(y, 0.f);
            hout[n * 128 + c] = f2bf(y);
          }
        }
      }
    }
  }
}

// ---------------- CSR mean pooling (bf16 h) ---------------------------------
__global__ __launch_bounds__(128) void pool_csr(const unsigned short* __restrict__ h,
                                                const int* __restrict__ npool,
                                                const int* __restrict__ rowptr_n,
                                                int segbase, float* __restrict__ pooled, int nseg) {
  int m = blockIdx.x;
  if (m >= nseg) return;
  int g = segbase + m;
  int st = rowptr_n[g];
  int e = rowptr_n[g + 1];
  int len = e - st;
  int c = threadIdx.x;
  float s = 0.f;
  int i = st;
  for (; i + 3 < e; i += 4) {
    int n0 = npool[i], n1 = npool[i + 1], n2 = npool[i + 2], n3 = npool[i + 3];
    float v0 = bf2f(h[(size_t)n0 * 128 + c]);
    float v1 = bf2f(h[(size_t)n1 * 128 + c]);
    float v2 = bf2f(h[(size_t)n2 * 128 + c]);
    float v3 = bf2f(h[(size_t)n3 * 128 + c]);
    s += (v0 + v1) + (v2 + v3);
  }
  for (; i < e; i++) s += bf2f(h[(size_t)npool[i] * 128 + c]);
  pooled[m * 128 + c] = s / ((float)len + 1e-9f);
}

// ---------------- small generic GEMM: C = A[MxK] @ W[KxN] + bias -----------
__global__ void gemm_small(const float* __restrict__ A, const float* __restrict__ W,
                           const float* __restrict__ bias, float* __restrict__ C,
                           int M, int N, int K) {
  int i = blockIdx.x * 256 + threadIdx.x;
  if (i >= M * N) return;
  int r = i / N, c = i - r * N;
  float acc = bias ? bias[c] : 0.f;
  const float* a = A + (size_t)r * K;
  for (int k = 0; k < K; k++) acc = fmaf(a[k], W[(size_t)k * N + c], acc);
  C[i] = acc;
}

// ---------------- SAB attention: O = Qs + softmax(QsKs^T/8) Vs -------------
__global__ __launch_bounds__(256) void sab_attn(const float* __restrict__ Q, const float* __restrict__ K,
                                                const float* __restrict__ V, float* __restrict__ O, int S) {
  int q = blockIdx.x, hd = blockIdx.y;
  int t = threadIdx.x;
  __shared__ float sc[512];
  __shared__ float red[8];
  __shared__ float pacc[4][64];
  const float* qrow = Q + q * 128 + hd * 64;
  for (int k = t; k < 512; k += 256) {
    float d = -1e30f;
    if (k < S) {
      const float* krow = K + k * 128 + hd * 64;
      d = 0.f;
#pragma unroll
      for (int j = 0; j < 64; j += 4) {
        float4 a = *(const float4*)(qrow + j);
        float4 b = *(const float4*)(krow + j);
        d += a.x * b.x + a.y * b.y + a.z * b.z + a.w * b.w;
      }
      d *= 0.125f;
    }
    sc[k] = d;
  }
  __syncthreads();
  float m = fmaxf(sc[t], sc[t + 256]);
  for (int off = 32; off; off >>= 1) m = fmaxf(m, __shfl_down(m, off));
  if ((t & 63) == 0) red[t >> 6] = m;
  __syncthreads();
  m = fmaxf(fmaxf(red[0], red[1]), fmaxf(red[2], red[3]));
  float p0 = __expf(sc[t] - m), p1 = __expf(sc[t + 256] - m);
  sc[t] = p0; sc[t + 256] = p1;
  float s = p0 + p1;
  for (int off = 32; off; off >>= 1) s += __shfl_down(s, off);
  if ((t & 63) == 0) red[4 + (t >> 6)] = s;
  __syncthreads();
  float inv = 1.f / (red[4] + red[5] + red[6] + red[7]);
  int d = t & 63, part = t >> 6;
  float acc = 0.f;
  for (int k = part; k < S; k += 4) acc += sc[k] * V[k * 128 + hd * 64 + d];
  pacc[part][d] = acc;
  __syncthreads();
  if (part == 0) {
    float o = (pacc[0][d] + pacc[1][d] + pacc[2][d] + pacc[3][d]) * inv;
    O[q * 128 + hd * 64 + d] = qrow[d] + o;
  }
}

// ---------------- row LayerNorm over 128 ------------------------------------
__global__ __launch_bounds__(128) void ln_rows(const float* __restrict__ in, float* __restrict__ out,
                                               const float* __restrict__ g, const float* __restrict__ b) {
  int r = blockIdx.x, t = threadIdx.x;
  __shared__ float red[4];
  float x = in[r * 128 + t];
  float s = x;
  for (int off = 32; off; off >>= 1) s += __shfl_down(s, off);
  if ((t & 63) == 0) red[t >> 6] = s;
  __syncthreads();
  float mu = (red[0] + red[1]) * (1.f / 128.f);
  float dd = x - mu;
  float v = dd * dd;
  for (int off = 32; off; off >>= 1) v += __shfl_down(v, off);
  if ((t & 63) == 0) red[2 + (t >> 6)] = v;
  __syncthreads();
  float var = (red[2] + red[3]) * (1.f / 128.f);
  out[r * 128 + t] = g[t] * dd * rsqrtf(var + LN_EPS) + b[t];
}

// ---------------- masked softmax attn: attn[d,s] ----------------------------
__global__ __launch_bounds__(256) void agg_attn(const float* __restrict__ Q, const float* __restrict__ Kt,
                                                const void* __restrict__ mask, const int* __restrict__ flags,
                                                float* __restrict__ attn, int D, int S) {
  int d = blockIdx.x, t = threadIdx.x;
  __shared__ float sc[512];
  __shared__ float red[8];
  int layout = (flags[1] == 0) ? 0 : (flags[0] ? 1 : 2);
  const float* qrow = Q + d * 128;
  for (int s = t; s < 512; s += 256) {
    float v = NEGBIG;
    if (s < S) {
      int mi = d * S + s;
      bool msk;
      if (layout == 0)      msk = ((const int*)mask)[mi] != 0;
      else if (layout == 1) msk = ((const unsigned char*)mask)[mi] != 0;
      else                  msk = ((const float*)mask)[mi] != 0.f;
      if (!msk) {
        float dd = 0.f;
        const float* krow = Kt + s * 128;
#pragma unroll
        for (int j = 0; j < 128; j += 4) {
          float4 a = *(const float4*)(qrow + j);
          float4 b = *(const float4*)(krow + j);
          dd += a.x * b.x + a.y * b.y + a.z * b.z + a.w * b.w;
        }
        v = dd * 0.08838834764831845f;
      }
    }
    sc[s] = v;
  }
  __syncthreads();
  float m = fmaxf(sc[t], sc[t + 256]);
  for (int off = 32; off; off >>= 1) m = fmaxf(m, __shfl_down(m, off));
  if ((t & 63) == 0) red[t >> 6] = m;
  __syncthreads();
  m = fmaxf(fmaxf(red[0], red[1]), fmaxf(red[2], red[3]));
  float p0 = __expf(sc[t] - m), p1 = __expf(sc[t + 256] - m);
  float s2 = p0 + p1;
  for (int off = 32; off; off >>= 1) s2 += __shfl_down(s2, off);
  if ((t & 63) == 0) red[4 + (t >> 6)] = s2;
  __syncthreads();
  float inv = 1.f / (red[4] + red[5] + red[6] + red[7]);
  attn[d * S + t] = p0 * inv;
  if (t + 256 < S) attn[d * S + t + 256] = p1 * inv;
}

// ---------------- subT prep: subf [S][128] f32 -> subT bf16 [128][512] ------
__global__ void prep_subT(const float* __restrict__ subf, unsigned short* __restrict__ subT, int S) {
  int i = blockIdx.x * 256 + threadIdx.x;
  if (i >= 128 * 512) return;
  int hh = i >> 9, k = i & 511;
  subT[i] = (k < S) ? f2bf(subf[k * 128 + hh]) : (unsigned short)0;
}

// ---------------- agg via MFMA: per d, (pat .* attn[d])[64x492] @ sub -------
__global__ __launch_bounds__(256) void agg_mfma(const float* __restrict__ attn, const float* __restrict__ pat,
                                                const unsigned short* __restrict__ subT,
                                                float* __restrict__ aggT, int D, int S) {
  int d = blockIdx.x, t = threadIdx.x;
  __shared__ unsigned short As[64][40];
  int lane = t & 63, wave = t >> 6;
  int quad = lane >> 4, l16 = lane & 15;
  f32x4 acc[8];
#pragma unroll
  for (int nt = 0; nt < 8; nt++) acc[nt] = (f32x4){0.f, 0.f, 0.f, 0.f};
  const float* arow = attn + d * S;
  int srow = t >> 2, skb = (t & 3) * 8;
  for (int c = 0; c < 16; c++) {
    int s0 = c * 32;
    __syncthreads();
    unsigned short v[8];
#pragma unroll
    for (int j = 0; j < 8; j++) {
      int s = s0 + skb + j;
      float x = (s < S) ? arow[s] * pat[srow * S + s] : 0.f;
      v[j] = f2bf(x);
    }
    *(us4*)&As[srow][skb]     = *(us4*)&v[0];
    *(us4*)&As[srow][skb + 4] = *(us4*)&v[4];
    __syncthreads();
    short8 af = *(const short8*)&As[16 * wave + l16][quad * 8];
#pragma unroll
    for (int nt = 0; nt < 8; nt++) {
      short8 bf = *(const short8*)(subT + (nt * 16 + l16) * 512 + s0 + quad * 8);
      acc[nt] = __builtin_amdgcn_mfma_f32_16x16x32_bf16(af, bf, acc[nt], 0, 0, 0);
    }
  }
#pragma unroll
  for (int nt = 0; nt < 8; nt++) {
    int hh = nt * 16 + l16;
#pragma unroll
    for (int reg = 0; reg < 4; reg++) {
      int b = 16 * wave + quad * 4 + reg;
      aggT[((size_t)(b * D + d)) * 128 + hh] = acc[nt][reg];
    }
  }
}

// ---------------- score head: sigmoid(relu(agg@w1+b1)@w2+b2) ---------------
__global__ __launch_bounds__(64) void score_head(const float* __restrict__ aggT,
                                                 const float* __restrict__ w1, const float* __restrict__ b1,
                                                 const float* __restrict__ w2, const float* __restrict__ b2,
                                                 float* __restrict__ out) {
  int i = blockIdx.x;
  int j = threadIdx.x;
  const float* av = aggT + (size_t)i * 128;
  float acc = b1[j];
#pragma unroll 8
  for (int k = 0; k < 128; k++) acc = fmaf(av[k], w1[k * 64 + j], acc);
  acc = fmaxf(acc, 0.f) * w2[j];
  for (int off = 32; off; off >>= 1) acc += __shfl_down(acc, off);
  if (j == 0) {
    float x = acc + b2[0];
    out[i] = 1.f / (1.f + __expf(-x));
  }
}

// ---------------------------------------------------------------------------
extern "C" void kernel_launch(void* const* d_in, const int* in_sizes, int n_in,
                              void* d_out, int out_size, void* d_ws, size_t ws_size,
                              hipStream_t stream) {
  const float* atom_emb = (const float*)d_in[0];
  const float* bond_emb = (const float*)d_in[1];
  const float* gin_eps  = (const float*)d_in[2];
  const float* gin_w1   = (const float*)d_in[3];
  const float* gin_b1   = (const float*)d_in[4];
  const float* bn1g     = (const float*)d_in[5];
  const float* bn1b     = (const float*)d_in[6];
  const float* gin_w2   = (const float*)d_in[7];
  const float* gin_b2   = (const float*)d_in[8];
  const float* bn2g     = (const float*)d_in[9];
  const float* bn2b     = (const float*)d_in[10];
  const float* sab_wq = (const float*)d_in[11];
  const float* sab_wk = (const float*)d_in[12];
  const float* sab_wv = (const float*)d_in[13];
  const float* sab_wo = (const float*)d_in[14];
  const float* sab_bq = (const float*)d_in[15];
  const float* sab_bk = (const float*)d_in[16];
  const float* sab_bv = (const float*)d_in[17];
  const float* sab_bo = (const float*)d_in[18];
  const float* ln1b = (const float*)d_in[19];
  const float* ln2b = (const float*)d_in[20];
  const float* ln1g = (const float*)d_in[21];
  const float* ln2g = (const float*)d_in[22];
  const float* agg_wq = (const float*)d_in[23];
  const float* agg_bq = (const float*)d_in[24];
  const float* agg_wk = (const float*)d_in[25];
  const float* agg_bk = (const float*)d_in[26];
  const float* score_w1 = (const float*)d_in[27];
  const float* score_b1 = (const float*)d_in[28];
  const float* score_w2 = (const float*)d_in[29];
  const float* score_b2 = (const float*)d_in[30];
  const float* patient  = (const float*)d_in[31];
  const float* avgproj  = (const float*)d_in[32];
  const int* sub_x     = (const int*)d_in[33];
  const int* sub_ea    = (const int*)d_in[34];
  const int* sub_ei    = (const int*)d_in[35];
  const int* sub_batch = (const int*)d_in[36];
  const int* mol_x     = (const int*)d_in[37];
  const int* mol_ea    = (const int*)d_in[38];
  const int* mol_ei    = (const int*)d_in[39];
  const int* mol_batch = (const int*)d_in[40];
  const void* mask     = d_in[41];

  const int Ns = in_sizes[33] / 9, Es = in_sizes[34] / 3;
  const int Nm = in_sizes[37] / 9, Em = in_sizes[38] / 3;
  const int S = 492, M = 600, D = 200, B = 64;
  const int NE = Nm + Ns;           // edge-CSR index space (mol first)
  const int NSEG = M + S;           // node-CSR index space (mol first)
  const int ETOT = Em + Es;
  const int BONDE = 2 * 4 * 3 * 64 * 128;   // bond table elements

  // ---- workspace carve-up ----
  char* Wp = (char*)d_ws;
  size_t off = 0;
  auto alloc = [&](size_t bytes) -> void* {
    void* p = Wp + off;
    off = (off + bytes + 255) & ~(size_t)255;
    return p;
  };
  int NR = ((Nm > Ns ? Nm : Ns) + 63) & ~63;
  unsigned short* h0 = (unsigned short*)alloc((size_t)NR * 128 * 2);
  unsigned short* h1 = (unsigned short*)alloc((size_t)NR * 128 * 2);
  unsigned short* zb = (unsigned short*)alloc((size_t)NR * 128 * 2);
  unsigned short* w1t = (unsigned short*)alloc(262144 * 2);
  unsigned short* w2t = (unsigned short*)alloc(262144 * 2);
  unsigned short* bt16 = (unsigned short*)alloc((size_t)BONDE * 2);
  int4* epool  = (int4*)alloc((size_t)ETOT * 16);
  int*  npool  = (int*)alloc((size_t)NE * 4);
  int*  excl_e = (int*)alloc((size_t)NE * 4);
  int*  bsum_e = (int*)alloc(1024 * 4);
  int*  excl_n = (int*)alloc((size_t)NSEG * 4);
  int*  bsum_n = (int*)alloc(1024 * 4);
  int*  rowptr_e = (int*)alloc((size_t)(NE + 1) * 4);
  int*  rowptr_n = (int*)alloc((size_t)(NSEG + 1) * 4);
  char* zstart = Wp + off;                       // region zeroed below
  int*  deg_e  = (int*)alloc((size_t)NE * 4);
  int*  deg_n  = (int*)alloc((size_t)NSEG * 4);
  int*  cur_e  = (int*)alloc((size_t)NE * 4);
  int*  cur_n  = (int*)alloc((size_t)NSEG * 4);
  int*  flags  = (int*)alloc(8);
  size_t zsize = (size_t)((Wp + off) - zstart);
  float* pooled_sub = (float*)alloc((size_t)S * 128 * 4);
  float* pooled_mol = (float*)alloc((size_t)M * 128 * 4);
  float* Qb   = (float*)alloc((size_t)S * 128 * 4);
  float* Kb   = (float*)alloc((size_t)S * 128 * 4);
  float* Vb   = (float*)alloc((size_t)S * 128 * 4);
  float* Ob   = (float*)alloc((size_t)S * 128 * 4);
  float* O2b  = (float*)alloc((size_t)S * 128 * 4);
  float* subf = (float*)alloc((size_t)S * 128 * 4);
  unsigned short* subT = (unsigned short*)alloc((size_t)128 * 512 * 2);
  float* mol_embb = (float*)alloc((size_t)D * 128 * 4);
  float* aggQb = (float*)alloc((size_t)D * 128 * 4);
  float* aggKb = (float*)alloc((size_t)S * 128 * 4);
  float* attnb = (float*)alloc((size_t)D * S * 4);
  float* aggTb = (float*)alloc((size_t)B * D * 128 * 4);
  (void)ws_size; (void)n_in; (void)out_size;

  hipMemsetAsync(zstart, 0, zsize, stream);
  prep_weights<<<1024, 256, 0, stream>>>(gin_w1, gin_w2, w1t, w2t);
  prep_bond<<<(BONDE + 255) / 256, 256, 0, stream>>>(bond_emb, bt16, BONDE);
  mask_detect<<<(D * S + 255) / 256, 256, 0, stream>>>((const unsigned char*)mask, flags, D * S);

  // ---- CSR build (edges by tgt; nodes by batch) ----
  int total_cnt = Em + Es + Nm + Ns;
  build_count<<<(total_cnt + 255) / 256, 256, 0, stream>>>(
      mol_ei, Em, sub_ei, Es, mol_batch, Nm, sub_batch, Ns, deg_e, deg_n, M);
  int nb_e = (NE + 255) / 256;        // <= 1024
  int nb_n = (NSEG + 255) / 256;
  scan_block<<<nb_e, 256, 0, stream>>>(deg_e, NE, excl_e, bsum_e);
  scan_top<<<1, 1024, 0, stream>>>(bsum_e, nb_e);
  scan_block<<<nb_n, 256, 0, stream>>>(deg_n, NSEG, excl_n, bsum_n);
  scan_top<<<1, 1024, 0, stream>>>(bsum_n, nb_n);
  finalize_rowptr<<<(NE + 256) / 256 + 1, 256, 0, stream>>>(excl_e, bsum_e, NE, ETOT, rowptr_e);
  finalize_rowptr<<<(NSEG + 256) / 256 + 1, 256, 0, stream>>>(excl_n, bsum_n, NSEG, NE, rowptr_n);
  scatter_edges<<<(ETOT + 255) / 256, 256, 0, stream>>>(
      mol_ei, mol_ea, Em, sub_ei, sub_ea, Es, Nm, rowptr_e, cur_e, epool);
  scatter_nodes<<<(NE + 255) / 256, 256, 0, stream>>>(
      mol_batch, Nm, sub_batch, Ns, M, rowptr_n, cur_n, npool);

  auto run_gin = [&](int g, int N, const int* x, int nodebase, int segbase,
                     float* pooled, int nseg) {
    embed_nodes<<<(N * 128 + 255) / 256, 256, 0, stream>>>(
        x, atom_emb + (size_t)g * 9 * 64 * 128, h0, N);
    unsigned short* hin = h0; unsigned short* hout = h1;
    for (int l = 0; l < 4; l++) {
      int gl = g * 4 + l;
      gather_z<<<(N * 8 + 255) / 256, 256, 0, stream>>>(
          hin, zb, gin_eps + gl, bt16 + (size_t)gl * 3 * 64 * 128,
          epool, rowptr_e, nodebase, N);
      gin_mlp2<<<(N + 63) / 64, 256, 0, stream>>>(
          zb, hout,
          w1t + (size_t)gl * 32768, gin_b1 + gl * 256, bn1g + gl * 256, bn1b + gl * 256,
          w2t + (size_t)gl * 32768, gin_b2 + gl * 128, bn2g + gl * 128, bn2b + gl * 128,
          N, (l != 3) ? 1 : 0);
      unsigned short* tmp = hin; hin = hout; hout = tmp;
    }
    pool_csr<<<nseg, 128, 0, stream>>>(hin, npool, rowptr_n, segbase, pooled, nseg);
  };

  // --- substructure encoder + SAB ---
  run_gin(0, Ns, sub_x, Nm, M, pooled_sub, S);
  gemm_small<<<(S * 128 + 255) / 256, 256, 0, stream>>>(pooled_sub, sab_wq, sab_bq, Qb, S, 128, 128);
  gemm_small<<<(S * 128 + 255) / 256, 256, 0, stream>>>(pooled_sub, sab_wk, sab_bk, Kb, S, 128, 128);
  gemm_small<<<(S * 128 + 255) / 256, 256, 0, stream>>>(pooled_sub, sab_wv, sab_bv, Vb, S, 128, 128);
  sab_attn<<<dim3(S, 2), 256, 0, stream>>>(Qb, Kb, Vb, Ob, S);
  ln_rows<<<S, 128, 0, stream>>>(Ob, Ob, ln1g, ln1b);
  gemm_small<<<(S * 128 + 255) / 256, 256, 0, stream>>>(Ob, sab_wo, sab_bo, O2b, S, 128, 128);
  ln_rows<<<S, 128, 0, stream>>>(O2b, subf, ln2g, ln2b);
  prep_subT<<<(128 * 512 + 255) / 256, 256, 0, stream>>>(subf, subT, S);

  // --- molecule encoder + projection ---
  run_gin(1, Nm, mol_x, 0, 0, pooled_mol, M);
  gemm_small<<<(D * 128 + 255) / 256, 256, 0, stream>>>(avgproj, pooled_mol, (const float*)nullptr, mol_embb, D, 128, M);

  // --- attention aggregation + score ---
  gemm_small<<<(D * 128 + 255) / 256, 256, 0, stream>>>(mol_embb, agg_wq, agg_bq, aggQb, D, 128, 128);
  gemm_small<<<(S * 128 + 255) / 256, 256, 0, stream>>>(subf, agg_wk, agg_bk, aggKb, S, 128, 128);
  agg_attn<<<D, 256, 0, stream>>>(aggQb, aggKb, mask, flags, attnb, D, S);
  agg_mfma<<<D, 256, 0, stream>>>(attnb, patient, subT, aggTb, D, S);
  score_head<<<B * D, 64, 0, stream>>>(aggTb, score_w1, score_b1, score_w2, score_b2, (float*)d_out);
}

// Round 8
// 1334.418 us; speedup vs baseline: 2.1636x; 1.2089x over previous
//
#include <hip/hip_runtime.h>

// ---------------------------------------------------------------------------
// MoleRec pipeline on gfx950.
// R7: gemm_small (1 thread/output, serial K-loop, 4% occupancy; avgproj@
//     pooled_mol was 144us for 15 MFLOP) replaced by gemm_tile: one block
//     per row, A-row staged in LDS, K split across thread-halves, W reads
//     coalesced over the fixed N=128 columns, unroll-8 for loads in flight.
//     GIN path unchanged from R6 (node-parallel bf16 gather + MFMA MLP).
// ---------------------------------------------------------------------------

typedef short short8 __attribute__((ext_vector_type(8)));
typedef unsigned short us8 __attribute__((ext_vector_type(8)));
typedef float f32x4 __attribute__((ext_vector_type(4)));
typedef unsigned short us4 __attribute__((ext_vector_type(4)));

#define BN_RSQ 0.9999950000374997f   // 1/sqrt(1+1e-5)  (BatchNorm eval, var=1)
#define LN_EPS 1e-5f
#define NEGBIG -4294967296.0f        // -(1<<32), matches reference mask fill

__device__ __forceinline__ unsigned short f2bf(float x) {
  union { float f; unsigned int u; } v; v.f = x;
  unsigned int r = v.u + 0x7fffu + ((v.u >> 16) & 1u);   // RNE
  return (unsigned short)(r >> 16);
}
__device__ __forceinline__ float bf2f(unsigned short x) {
  union { unsigned int u; float f; } v; v.u = ((unsigned int)x) << 16;
  return v.f;
}

// ---------------- weight prep: fp32 [K][N] -> bf16 [N][K] ------------------
__global__ void prep_weights(const float* __restrict__ w1, const float* __restrict__ w2,
                             unsigned short* __restrict__ w1t, unsigned short* __restrict__ w2t) {
  int i = blockIdx.x * 256 + threadIdx.x;
  if (i >= 262144) return;
  int gl = i >> 15;
  int k1 = (i >> 8) & 127, c1 = i & 255;
  w1t[(gl << 15) + c1 * 128 + k1] = f2bf(w1[i]);
  int k2 = (i >> 7) & 255, c2 = i & 127;
  w2t[(gl << 15) + c2 * 256 + k2] = f2bf(w2[i]);
}

// ---------------- bond tables fp32 -> bf16 (same layout) --------------------
__global__ void prep_bond(const float* __restrict__ in, unsigned short* __restrict__ out, int n) {
  int i = blockIdx.x * 256 + threadIdx.x;
  if (i < n) out[i] = f2bf(in[i]);
}

// ---------------- mask layout detection ------------------------------------
__global__ void mask_detect(const unsigned char* __restrict__ m, int* __restrict__ flags, int nbytes) {
  int i = blockIdx.x * 256 + threadIdx.x;
  if (i < nbytes && m[i]) {
    if ((i & 3) == 0) atomicOr(flags, 1);
    else atomicOr(flags + 1, 1);
  }
}

// ---------------- CSR build: count ------------------------------------------
__global__ void build_count(const int* __restrict__ ei_m, int Em,
                            const int* __restrict__ ei_s, int Es,
                            const int* __restrict__ bm, int Nm,
                            const int* __restrict__ bs, int Ns,
                            int* __restrict__ deg_e, int* __restrict__ deg_n, int M) {
  int i = blockIdx.x * 256 + threadIdx.x;
  if (i < Em) { atomicAdd(&deg_e[ei_m[i]], 1); return; }
  i -= Em;
  if (i < Es) { atomicAdd(&deg_e[Nm + ei_s[i]], 1); return; }
  i -= Es;
  if (i < Nm) { atomicAdd(&deg_n[bm[i]], 1); return; }
  i -= Nm;
  if (i < Ns) { atomicAdd(&deg_n[M + bs[i]], 1); }
}

// ---------------- CSR build: block-level exclusive scan ---------------------
__global__ __launch_bounds__(256) void scan_block(const int* __restrict__ cnt, int n,
                                                  int* __restrict__ excl, int* __restrict__ bsum) {
  int gid = blockIdx.x * 256 + threadIdx.x;
  int lane = threadIdx.x & 63, w = threadIdx.x >> 6;
  int v = (gid < n) ? cnt[gid] : 0;
  int x = v;
#pragma unroll
  for (int off = 1; off < 64; off <<= 1) {
    int y = __shfl_up(x, off, 64);
    if (lane >= off) x += y;
  }
  __shared__ int wt[4];
  if (lane == 63) wt[w] = x;
  __syncthreads();
  int add = 0;
  for (int i = 0; i < w; i++) add += wt[i];
  x += add;
  if (gid < n) excl[gid] = x - v;
  if (threadIdx.x == 255) bsum[blockIdx.x] = x;
}

__global__ __launch_bounds__(1024) void scan_top(int* __restrict__ bsum, int n) {
  int t = threadIdx.x;
  int lane = t & 63, w = t >> 6;
  int v = (t < n) ? bsum[t] : 0;
  int x = v;
#pragma unroll
  for (int off = 1; off < 64; off <<= 1) {
    int y = __shfl_up(x, off, 64);
    if (lane >= off) x += y;
  }
  __shared__ int wt[16];
  if (lane == 63) wt[w] = x;
  __syncthreads();
  int add = 0;
  for (int i = 0; i < w; i++) add += wt[i];
  x += add;
  if (t < n) bsum[t] = x - v;
}

// ---------------- rowptr finalize: rowptr[i] = excl[i]+bsum[i>>8] -----------
__global__ void finalize_rowptr(const int* __restrict__ excl, const int* __restrict__ bsum,
                                int n, int total, int* __restrict__ rowptr) {
  int i = blockIdx.x * 256 + threadIdx.x;
  if (i < n) rowptr[i] = excl[i] + bsum[i >> 8];
  if (i == n) rowptr[n] = total;
}

// ---------------- CSR build: scatter ----------------------------------------
// epool rec: x=src*128, y=tgt_local, z=p0|(p1<<16), w=p2  (bond elem offsets)
__global__ void scatter_edges(const int* __restrict__ ei_m, const int* __restrict__ ea_m, int Em,
                              const int* __restrict__ ei_s, const int* __restrict__ ea_s, int Es, int Nm,
                              const int* __restrict__ rowptr_e,
                              int* __restrict__ cur_e, int4* __restrict__ epool) {
  int i = blockIdx.x * 256 + threadIdx.x;
  int g, tgt, src, a0, a1, a2;
  if (i < Em) {
    tgt = ei_m[i]; src = ei_m[Em + i]; g = tgt;
    a0 = ea_m[i * 3]; a1 = ea_m[i * 3 + 1]; a2 = ea_m[i * 3 + 2];
  } else {
    int j = i - Em; if (j >= Es) return;
    tgt = ei_s[j]; src = ei_s[Es + j]; g = Nm + tgt;
    a0 = ea_s[j * 3]; a1 = ea_s[j * 3 + 1]; a2 = ea_s[j * 3 + 2];
  }
  int slot = rowptr_e[g] + atomicAdd(&cur_e[g], 1);
  int p0 = a0 * 128, p1 = (64 + a1) * 128, p2 = (128 + a2) * 128;
  epool[slot] = make_int4(src * 128, tgt, p0 | (p1 << 16), p2);
}

__global__ void scatter_nodes(const int* __restrict__ bm, int Nm,
                              const int* __restrict__ bs, int Ns, int M,
                              const int* __restrict__ rowptr_n,
                              int* __restrict__ cur_n, int* __restrict__ npool) {
  int i = blockIdx.x * 256 + threadIdx.x;
  int g, node;
  if (i < Nm) { g = bm[i]; node = i; }
  else { int j = i - Nm; if (j >= Ns) return; g = M + bs[j]; node = j; }
  int slot = rowptr_n[g] + atomicAdd(&cur_n[g], 1);
  npool[slot] = node;
}

// ---------------- node embedding (bf16 out) ---------------------------------
__global__ void embed_nodes(const int* __restrict__ x, const float* __restrict__ table,
                            unsigned short* __restrict__ h, int N) {
  int i = blockIdx.x * 256 + threadIdx.x;
  if (i >= N * 128) return;
  int n = i >> 7, c = i & 127;
  float s = 0.f;
#pragma unroll
  for (int f = 0; f < 9; f++) {
    int v = x[n * 9 + f];
    s += table[(f * 64 + v) * 128 + c];
  }
  h[i] = f2bf(s);
}

// ---------------- edge gather: z = (1+eps)*h + sum relu(h[src]+bond) --------
// Node-parallel, LDS-free: 8 threads/node x 16 ch, register accumulation.
__global__ __launch_bounds__(256) void gather_z(
    const unsigned short* __restrict__ hin, unsigned short* __restrict__ z,
    const float* __restrict__ eps_p, const unsigned short* __restrict__ bt,
    const int4* __restrict__ epool, const int* __restrict__ rowptr_e, int nodebase,
    int N) {
  int gid = blockIdx.x * 256 + threadIdx.x;
  int n = gid >> 3;
  if (n >= N) return;
  int cb = (gid & 7) * 16;
  float eps1 = 1.0f + *eps_p;
  float acc[16];
  {
    const unsigned short* hr = hin + (size_t)n * 128 + cb;
    us8 v0 = *(const us8*)hr, v1 = *(const us8*)(hr + 8);
#pragma unroll
    for (int k = 0; k < 8; k++) {
      acc[k]     = eps1 * bf2f(v0[k]);
      acc[8 + k] = eps1 * bf2f(v1[k]);
    }
  }
  int e0 = rowptr_e[nodebase + n], e1 = rowptr_e[nodebase + n + 1];
  for (int e = e0; e < e1; e++) {
    int4 rec = epool[e];
    const unsigned short* hs = hin + rec.x + cb;
    const unsigned short* q0 = bt + (rec.z & 0xffff) + cb;
    const unsigned short* q1 = bt + (((unsigned)rec.z) >> 16) + cb;
    const unsigned short* q2 = bt + rec.w + cb;
    us8 a0 = *(const us8*)hs, a1 = *(const us8*)(hs + 8);
    us8 b0 = *(const us8*)q0, b1 = *(const us8*)(q0 + 8);
    us8 c0 = *(const us8*)q1, c1 = *(const us8*)(q1 + 8);
    us8 d0 = *(const us8*)q2, d1 = *(const us8*)(q2 + 8);
#pragma unroll
    for (int k = 0; k < 8; k++) {
      acc[k]     += fmaxf(bf2f(a0[k]) + bf2f(b0[k]) + bf2f(c0[k]) + bf2f(d0[k]), 0.f);
      acc[8 + k] += fmaxf(bf2f(a1[k]) + bf2f(b1[k]) + bf2f(c1[k]) + bf2f(d1[k]), 0.f);
    }
  }
  unsigned short ob[16];
#pragma unroll
  for (int k = 0; k < 16; k++) ob[k] = f2bf(acc[k]);
  unsigned short* zr = z + (size_t)n * 128 + cb;
  *(us8*)zr = *(const us8*)&ob[0];
  *(us8*)(zr + 8) = *(const us8*)&ob[8];
}

// ---------------- GIN MLP: h = bn2(relu(bn1(z@w1+b1))@w2+b2) (+relu) --------
__global__ __launch_bounds__(256) void gin_mlp2(
    const unsigned short* __restrict__ zin, unsigned short* __restrict__ hout,
    const unsigned short* __restrict__ w1t, const float* __restrict__ b1,
    const float* __restrict__ g1, const float* __restrict__ be1,
    const unsigned short* __restrict__ w2t, const float* __restrict__ b2,
    const float* __restrict__ g2, const float* __restrict__ be2,
    int N, int do_relu) {
  __shared__ unsigned short zs[64][136];    // 64x128 bf16, +8 pad
  __shared__ unsigned short z1s[64][264];   // 64x256 bf16, +8 pad
  int t = threadIdx.x;
  int r0 = blockIdx.x * 64;
  for (int i = t; i < 2048; i += 256) {
    int r = i >> 5, c4 = (i & 31) << 2;
    int n = r0 + r;
    us4 v;
    if (n < N) v = *(const us4*)(zin + (size_t)n * 128 + c4);
    else { v.x = 0; v.y = 0; v.z = 0; v.w = 0; }
    *(us4*)&zs[r][c4] = v;
  }
  __syncthreads();
  int lane = t & 63, wave = t >> 6;
  int quad = lane >> 4, l16 = lane & 15;
  // Phase B: z1[64x256] = relu(bn1(z @ w1 + b1)); wave handles 64 cols
  {
    short8 bw[4][4];
    int cb = wave * 64;
#pragma unroll
    for (int nt = 0; nt < 4; nt++) {
      const unsigned short* p = w1t + (cb + nt * 16 + l16) * 128 + quad * 8;
#pragma unroll
      for (int kc = 0; kc < 4; kc++) bw[nt][kc] = *(const short8*)(p + kc * 32);
    }
#pragma unroll
    for (int mt = 0; mt < 4; mt++) {
      short8 af[4];
#pragma unroll
      for (int kc = 0; kc < 4; kc++)
        af[kc] = *(const short8*)&zs[mt * 16 + l16][kc * 32 + quad * 8];
#pragma unroll
      for (int nt = 0; nt < 4; nt++) {
        f32x4 acc = {0.f, 0.f, 0.f, 0.f};
#pragma unroll
        for (int kc = 0; kc < 4; kc++)
          acc = __builtin_amdgcn_mfma_f32_16x16x32_bf16(af[kc], bw[nt][kc], acc, 0, 0, 0);
        int c = cb + nt * 16 + l16;
        float sc = g1[c] * BN_RSQ, sh = be1[c], bb = b1[c];
#pragma unroll
        for (int reg = 0; reg < 4; reg++) {
          int r = mt * 16 + quad * 4 + reg;
          float y = (acc[reg] + bb) * sc + sh;
          z1s[r][c] = f2bf(fmaxf(y, 0.f));
        }
      }
    }
  }
  __syncthreads();
  // Phase C: h_out = bn2(z1 @ w2 + b2) (+relu); wave handles 32 cols
  {
    short8 bw[2][8];
    int cb = wave * 32;
#pragma unroll
    for (int nt = 0; nt < 2; nt++) {
      const unsigned short* p = w2t + (cb + nt * 16 + l16) * 256 + quad * 8;
#pragma unroll
      for (int kc = 0; kc < 8; kc++) bw[nt][kc] = *(const short8*)(p + kc * 32);
    }
#pragma unroll
    for (int mt = 0; mt < 4; mt++) {
      short8 af[8];
#pragma unroll
      for (int kc = 0; kc < 8; kc++)
        af[kc] = *(const short8*)&z1s[mt * 16 + l16][kc * 32 + quad * 8];
#pragma unroll
      for (int nt = 0; nt < 2; nt++) {
        f32x4 acc = {0.f, 0.f, 0.f, 0.f};
#pragma unroll
        for (int kc = 0; kc < 8; kc++)
          acc = __builtin_amdgcn_mfma_f32_16x16x32_bf16(af[kc], bw[nt][kc], acc, 0, 0, 0);
        int c = cb + nt * 16 + l16;
        float sc = g2[c] * BN_RSQ, sh = be2[c], bb = b2[c];
#pragma unroll
        for (int reg = 0; reg < 4; reg++) {
          int n = r0 + mt * 16 + quad * 4 + reg;
          if (n < N) {
            float y = (acc[reg] + bb) * sc + sh;
            if (do_relu) y = fmaxf(y, 0.f);
            hout[n * 128 + c] = f2bf(y);
          }
        }
      }
    }
  }
}

// ---------------- CSR mean pooling (bf16 h) ---------------------------------
__global__ __launch_bounds__(128) void pool_csr(const unsigned short* __restrict__ h,
                                                const int* __restrict__ npool,
                                                const int* __restrict__ rowptr_n,
                                                int segbase, float* __restrict__ pooled, int nseg) {
  int m = blockIdx.x;
  if (m >= nseg) return;
  int g = segbase + m;
  int st = rowptr_n[g];
  int e = rowptr_n[g + 1];
  int len = e - st;
  int c = threadIdx.x;
  float s = 0.f;
  int i = st;
  for (; i + 3 < e; i += 4) {
    int n0 = npool[i], n1 = npool[i + 1], n2 = npool[i + 2], n3 = npool[i + 3];
    float v0 = bf2f(h[(size_t)n0 * 128 + c]);
    float v1 = bf2f(h[(size_t)n1 * 128 + c]);
    float v2 = bf2f(h[(size_t)n2 * 128 + c]);
    float v3 = bf2f(h[(size_t)n3 * 128 + c]);
    s += (v0 + v1) + (v2 + v3);
  }
  for (; i < e; i++) s += bf2f(h[(size_t)npool[i] * 128 + c]);
  pooled[m * 128 + c] = s / ((float)len + 1e-9f);
}

// ---------------- row GEMM (N=128): C[r,:] = A[r,:] @ W + bias --------------
// One block per row. A-row staged in LDS; K split across two thread-halves;
// W reads coalesced over columns; unroll-8 keeps loads in flight.
__global__ __launch_bounds__(256) void gemm_tile(const float* __restrict__ A, const float* __restrict__ W,
                                                 const float* __restrict__ bias, float* __restrict__ C,
                                                 int K) {
  __shared__ float As[608];
  __shared__ float red[128];
  int r = blockIdx.x;
  int t = threadIdx.x;
  for (int i = t; i < K; i += 256) As[i] = A[(size_t)r * K + i];
  __syncthreads();
  int c = t & 127, half = t >> 7;
  int Kh = K >> 1;                 // K is even for all call sites (128, 600)
  int k0 = half * Kh, k1 = k0 + Kh;
  float acc = 0.f;
#pragma unroll 8
  for (int k = k0; k < k1; k++) acc = fmaf(As[k], W[(size_t)k * 128 + c], acc);
  if (half) red[c] = acc;
  __syncthreads();
  if (!half) {
    float v = acc + red[c] + (bias ? bias[c] : 0.f);
    C[(size_t)r * 128 + c] = v;
  }
}

// ---------------- SAB attention: O = Qs + softmax(QsKs^T/8) Vs -------------
__global__ __launch_bounds__(256) void sab_attn(const float* __restrict__ Q, const float* __restrict__ K,
                                                const float* __restrict__ V, float* __restrict__ O, int S) {
  int q = blockIdx.x, hd = blockIdx.y;
  int t = threadIdx.x;
  __shared__ float sc[512];
  __shared__ float red[8];
  __shared__ float pacc[4][64];
  const float* qrow = Q + q * 128 + hd * 64;
  for (int k = t; k < 512; k += 256) {
    float d = -1e30f;
    if (k < S) {
      const float* krow = K + k * 128 + hd * 64;
      d = 0.f;
#pragma unroll
      for (int j = 0; j < 64; j += 4) {
        float4 a = *(const float4*)(qrow + j);
        float4 b = *(const float4*)(krow + j);
        d += a.x * b.x + a.y * b.y + a.z * b.z + a.w * b.w;
      }
      d *= 0.125f;
    }
    sc[k] = d;
  }
  __syncthreads();
  float m = fmaxf(sc[t], sc[t + 256]);
  for (int off = 32; off; off >>= 1) m = fmaxf(m, __shfl_down(m, off));
  if ((t & 63) == 0) red[t >> 6] = m;
  __syncthreads();
  m = fmaxf(fmaxf(red[0], red[1]), fmaxf(red[2], red[3]));
  float p0 = __expf(sc[t] - m), p1 = __expf(sc[t + 256] - m);
  sc[t] = p0; sc[t + 256] = p1;
  float s = p0 + p1;
  for (int off = 32; off; off >>= 1) s += __shfl_down(s, off);
  if ((t & 63) == 0) red[4 + (t >> 6)] = s;
  __syncthreads();
  float inv = 1.f / (red[4] + red[5] + red[6] + red[7]);
  int d = t & 63, part = t >> 6;
  float acc = 0.f;
  for (int k = part; k < S; k += 4) acc += sc[k] * V[k * 128 + hd * 64 + d];
  pacc[part][d] = acc;
  __syncthreads();
  if (part == 0) {
    float o = (pacc[0][d] + pacc[1][d] + pacc[2][d] + pacc[3][d]) * inv;
    O[q * 128 + hd * 64 + d] = qrow[d] + o;
  }
}

// ---------------- row LayerNorm over 128 ------------------------------------
__global__ __launch_bounds__(128) void ln_rows(const float* __restrict__ in, float* __restrict__ out,
                                               const float* __restrict__ g, const float* __restrict__ b) {
  int r = blockIdx.x, t = threadIdx.x;
  __shared__ float red[4];
  float x = in[r * 128 + t];
  float s = x;
  for (int off = 32; off; off >>= 1) s += __shfl_down(s, off);
  if ((t & 63) == 0) red[t >> 6] = s;
  __syncthreads();
  float mu = (red[0] + red[1]) * (1.f / 128.f);
  float dd = x - mu;
  float v = dd * dd;
  for (int off = 32; off; off >>= 1) v += __shfl_down(v, off);
  if ((t & 63) == 0) red[2 + (t >> 6)] = v;
  __syncthreads();
  float var = (red[2] + red[3]) * (1.f / 128.f);
  out[r * 128 + t] = g[t] * dd * rsqrtf(var + LN_EPS) + b[t];
}

// ---------------- masked softmax attn: attn[d,s] ----------------------------
__global__ __launch_bounds__(256) void agg_attn(const float* __restrict__ Q, const float* __restrict__ Kt,
                                                const void* __restrict__ mask, const int* __restrict__ flags,
                                                float* __restrict__ attn, int D, int S) {
  int d = blockIdx.x, t = threadIdx.x;
  __shared__ float sc[512];
  __shared__ float red[8];
  int layout = (flags[1] == 0) ? 0 : (flags[0] ? 1 : 2);
  const float* qrow = Q + d * 128;
  for (int s = t; s < 512; s += 256) {
    float v = NEGBIG;
    if (s < S) {
      int mi = d * S + s;
      bool msk;
      if (layout == 0)      msk = ((const int*)mask)[mi] != 0;
      else if (layout == 1) msk = ((const unsigned char*)mask)[mi] != 0;
      else                  msk = ((const float*)mask)[mi] != 0.f;
      if (!msk) {
        float dd = 0.f;
        const float* krow = Kt + s * 128;
#pragma unroll
        for (int j = 0; j < 128; j += 4) {
          float4 a = *(const float4*)(qrow + j);
          float4 b = *(const float4*)(krow + j);
          dd += a.x * b.x + a.y * b.y + a.z * b.z + a.w * b.w;
        }
        v = dd * 0.08838834764831845f;
      }
    }
    sc[s] = v;
  }
  __syncthreads();
  float m = fmaxf(sc[t], sc[t + 256]);
  for (int off = 32; off; off >>= 1) m = fmaxf(m, __shfl_down(m, off));
  if ((t & 63) == 0) red[t >> 6] = m;
  __syncthreads();
  m = fmaxf(fmaxf(red[0], red[1]), fmaxf(red[2], red[3]));
  float p0 = __expf(sc[t] - m), p1 = __expf(sc[t + 256] - m);
  float s2 = p0 + p1;
  for (int off = 32; off; off >>= 1) s2 += __shfl_down(s2, off);
  if ((t & 63) == 0) red[4 + (t >> 6)] = s2;
  __syncthreads();
  float inv = 1.f / (red[4] + red[5] + red[6] + red[7]);
  attn[d * S + t] = p0 * inv;
  if (t + 256 < S) attn[d * S + t + 256] = p1 * inv;
}

// ---------------- subT prep: subf [S][128] f32 -> subT bf16 [128][512] ------
__global__ void prep_subT(const float* __restrict__ subf, unsigned short* __restrict__ subT, int S) {
  int i = blockIdx.x * 256 + threadIdx.x;
  if (i >= 128 * 512) return;
  int hh = i >> 9, k = i & 511;
  subT[i] = (k < S) ? f2bf(subf[k * 128 + hh]) : (unsigned short)0;
}

// ---------------- agg via MFMA: per d, (pat .* attn[d])[64x492] @ sub -------
__global__ __launch_bounds__(256) void agg_mfma(const float* __restrict__ attn, const float* __restrict__ pat,
                                                const unsigned short* __restrict__ subT,
                                                float* __restrict__ aggT, int D, int S) {
  int d = blockIdx.x, t = threadIdx.x;
  __shared__ unsigned short As[64][40];
  int lane = t & 63, wave = t >> 6;
  int quad = lane >> 4, l16 = lane & 15;
  f32x4 acc[8];
#pragma unroll
  for (int nt = 0; nt < 8; nt++) acc[nt] = (f32x4){0.f, 0.f, 0.f, 0.f};
  const float* arow = attn + d * S;
  int srow = t >> 2, skb = (t & 3) * 8;
  for (int c = 0; c < 16; c++) {
    int s0 = c * 32;
    __syncthreads();
    unsigned short v[8];
#pragma unroll
    for (int j = 0; j < 8; j++) {
      int s = s0 + skb + j;
      float x = (s < S) ? arow[s] * pat[srow * S + s] : 0.f;
      v[j] = f2bf(x);
    }
    *(us4*)&As[srow][skb]     = *(us4*)&v[0];
    *(us4*)&As[srow][skb + 4] = *(us4*)&v[4];
    __syncthreads();
    short8 af = *(const short8*)&As[16 * wave + l16][quad * 8];
#pragma unroll
    for (int nt = 0; nt < 8; nt++) {
      short8 bf = *(const short8*)(subT + (nt * 16 + l16) * 512 + s0 + quad * 8);
      acc[nt] = __builtin_amdgcn_mfma_f32_16x16x32_bf16(af, bf, acc[nt], 0, 0, 0);
    }
  }
#pragma unroll
  for (int nt = 0; nt < 8; nt++) {
    int hh = nt * 16 + l16;
#pragma unroll
    for (int reg = 0; reg < 4; reg++) {
      int b = 16 * wave + quad * 4 + reg;
      aggT[((size_t)(b * D + d)) * 128 + hh] = acc[nt][reg];
    }
  }
}

// ---------------- score head: sigmoid(relu(agg@w1+b1)@w2+b2) ---------------
__global__ __launch_bounds__(64) void score_head(const float* __restrict__ aggT,
                                                 const float* __restrict__ w1, const float* __restrict__ b1,
                                                 const float* __restrict__ w2, const float* __restrict__ b2,
                                                 float* __restrict__ out) {
  int i = blockIdx.x;
  int j = threadIdx.x;
  const float* av = aggT + (size_t)i * 128;
  float acc = b1[j];
#pragma unroll 8
  for (int k = 0; k < 128; k++) acc = fmaf(av[k], w1[k * 64 + j], acc);
  acc = fmaxf(acc, 0.f) * w2[j];
  for (int off = 32; off; off >>= 1) acc += __shfl_down(acc, off);
  if (j == 0) {
    float x = acc + b2[0];
    out[i] = 1.f / (1.f + __expf(-x));
  }
}

// ---------------------------------------------------------------------------
extern "C" void kernel_launch(void* const* d_in, const int* in_sizes, int n_in,
                              void* d_out, int out_size, void* d_ws, size_t ws_size,
                              hipStream_t stream) {
  const float* atom_emb = (const float*)d_in[0];
  const float* bond_emb = (const float*)d_in[1];
  const float* gin_eps  = (const float*)d_in[2];
  const float* gin_w1   = (const float*)d_in[3];
  const float* gin_b1   = (const float*)d_in[4];
  const float* bn1g     = (const float*)d_in[5];
  const float* bn1b     = (const float*)d_in[6];
  const float* gin_w2   = (const float*)d_in[7];
  const float* gin_b2   = (const float*)d_in[8];
  const float* bn2g     = (const float*)d_in[9];
  const float* bn2b     = (const float*)d_in[10];
  const float* sab_wq = (const float*)d_in[11];
  const float* sab_wk = (const float*)d_in[12];
  const float* sab_wv = (const float*)d_in[13];
  const float* sab_wo = (const float*)d_in[14];
  const float* sab_bq = (const float*)d_in[15];
  const float* sab_bk = (const float*)d_in[16];
  const float* sab_bv = (const float*)d_in[17];
  const float* sab_bo = (const float*)d_in[18];
  const float* ln1b = (const float*)d_in[19];
  const float* ln2b = (const float*)d_in[20];
  const float* ln1g = (const float*)d_in[21];
  const float* ln2g = (const float*)d_in[22];
  const float* agg_wq = (const float*)d_in[23];
  const float* agg_bq = (const float*)d_in[24];
  const float* agg_wk = (const float*)d_in[25];
  const float* agg_bk = (const float*)d_in[26];
  const float* score_w1 = (const float*)d_in[27];
  const float* score_b1 = (const float*)d_in[28];
  const float* score_w2 = (const float*)d_in[29];
  const float* score_b2 = (const float*)d_in[30];
  const float* patient  = (const float*)d_in[31];
  const float* avgproj  = (const float*)d_in[32];
  const int* sub_x     = (const int*)d_in[33];
  const int* sub_ea    = (const int*)d_in[34];
  const int* sub_ei    = (const int*)d_in[35];
  const int* sub_batch = (const int*)d_in[36];
  const int* mol_x     = (const int*)d_in[37];
  const int* mol_ea    = (const int*)d_in[38];
  const int* mol_ei    = (const int*)d_in[39];
  const int* mol_batch = (const int*)d_in[40];
  const void* mask     = d_in[41];

  const int Ns = in_sizes[33] / 9, Es = in_sizes[34] / 3;
  const int Nm = in_sizes[37] / 9, Em = in_sizes[38] / 3;
  const int S = 492, M = 600, D = 200, B = 64;
  const int NE = Nm + Ns;           // edge-CSR index space (mol first)
  const int NSEG = M + S;           // node-CSR index space (mol first)
  const int ETOT = Em + Es;
  const int BONDE = 2 * 4 * 3 * 64 * 128;   // bond table elements

  // ---- workspace carve-up ----
  char* Wp = (char*)d_ws;
  size_t off = 0;
  auto alloc = [&](size_t bytes) -> void* {
    void* p = Wp + off;
    off = (off + bytes + 255) & ~(size_t)255;
    return p;
  };
  int NR = ((Nm > Ns ? Nm : Ns) + 63) & ~63;
  unsigned short* h0 = (unsigned short*)alloc((size_t)NR * 128 * 2);
  unsigned short* h1 = (unsigned short*)alloc((size_t)NR * 128 * 2);
  unsigned short* zb = (unsigned short*)alloc((size_t)NR * 128 * 2);
  unsigned short* w1t = (unsigned short*)alloc(262144 * 2);
  unsigned short* w2t = (unsigned short*)alloc(262144 * 2);
  unsigned short* bt16 = (unsigned short*)alloc((size_t)BONDE * 2);
  int4* epool  = (int4*)alloc((size_t)ETOT * 16);
  int*  npool  = (int*)alloc((size_t)NE * 4);
  int*  excl_e = (int*)alloc((size_t)NE * 4);
  int*  bsum_e = (int*)alloc(1024 * 4);
  int*  excl_n = (int*)alloc((size_t)NSEG * 4);
  int*  bsum_n = (int*)alloc(1024 * 4);
  int*  rowptr_e = (int*)alloc((size_t)(NE + 1) * 4);
  int*  rowptr_n = (int*)alloc((size_t)(NSEG + 1) * 4);
  char* zstart = Wp + off;                       // region zeroed below
  int*  deg_e  = (int*)alloc((size_t)NE * 4);
  int*  deg_n  = (int*)alloc((size_t)NSEG * 4);
  int*  cur_e  = (int*)alloc((size_t)NE * 4);
  int*  cur_n  = (int*)alloc((size_t)NSEG * 4);
  int*  flags  = (int*)alloc(8);
  size_t zsize = (size_t)((Wp + off) - zstart);
  float* pooled_sub = (float*)alloc((size_t)S * 128 * 4);
  float* pooled_mol = (float*)alloc((size_t)M * 128 * 4);
  float* Qb   = (float*)alloc((size_t)S * 128 * 4);
  float* Kb   = (float*)alloc((size_t)S * 128 * 4);
  float* Vb   = (float*)alloc((size_t)S * 128 * 4);
  float* Ob   = (float*)alloc((size_t)S * 128 * 4);
  float* O2b  = (float*)alloc((size_t)S * 128 * 4);
  float* subf = (float*)alloc((size_t)S * 128 * 4);
  unsigned short* subT = (unsigned short*)alloc((size_t)128 * 512 * 2);
  float* mol_embb = (float*)alloc((size_t)D * 128 * 4);
  float* aggQb = (float*)alloc((size_t)D * 128 * 4);
  float* aggKb = (float*)alloc((size_t)S * 128 * 4);
  float* attnb = (float*)alloc((size_t)D * S * 4);
  float* aggTb = (float*)alloc((size_t)B * D * 128 * 4);
  (void)ws_size; (void)n_in; (void)out_size;

  hipMemsetAsync(zstart, 0, zsize, stream);
  prep_weights<<<1024, 256, 0, stream>>>(gin_w1, gin_w2, w1t, w2t);
  prep_bond<<<(BONDE + 255) / 256, 256, 0, stream>>>(bond_emb, bt16, BONDE);
  mask_detect<<<(D * S + 255) / 256, 256, 0, stream>>>((const unsigned char*)mask, flags, D * S);

  // ---- CSR build (edges by tgt; nodes by batch) ----
  int total_cnt = Em + Es + Nm + Ns;
  build_count<<<(total_cnt + 255) / 256, 256, 0, stream>>>(
      mol_ei, Em, sub_ei, Es, mol_batch, Nm, sub_batch, Ns, deg_e, deg_n, M);
  int nb_e = (NE + 255) / 256;        // <= 1024
  int nb_n = (NSEG + 255) / 256;
  scan_block<<<nb_e, 256, 0, stream>>>(deg_e, NE, excl_e, bsum_e);
  scan_top<<<1, 1024, 0, stream>>>(bsum_e, nb_e);
  scan_block<<<nb_n, 256, 0, stream>>>(deg_n, NSEG, excl_n, bsum_n);
  scan_top<<<1, 1024, 0, stream>>>(bsum_n, nb_n);
  finalize_rowptr<<<(NE + 256) / 256 + 1, 256, 0, stream>>>(excl_e, bsum_e, NE, ETOT, rowptr_e);
  finalize_rowptr<<<(NSEG + 256) / 256 + 1, 256, 0, stream>>>(excl_n, bsum_n, NSEG, NE, rowptr_n);
  scatter_edges<<<(ETOT + 255) / 256, 256, 0, stream>>>(
      mol_ei, mol_ea, Em, sub_ei, sub_ea, Es, Nm, rowptr_e, cur_e, epool);
  scatter_nodes<<<(NE + 255) / 256, 256, 0, stream>>>(
      mol_batch, Nm, sub_batch, Ns, M, rowptr_n, cur_n, npool);

  auto run_gin = [&](int g, int N, const int* x, int nodebase, int segbase,
                     float* pooled, int nseg) {
    embed_nodes<<<(N * 128 + 255) / 256, 256, 0, stream>>>(
        x, atom_emb + (size_t)g * 9 * 64 * 128, h0, N);
    unsigned short* hin = h0; unsigned short* hout = h1;
    for (int l = 0; l < 4; l++) {
      int gl = g * 4 + l;
      gather_z<<<(N * 8 + 255) / 256, 256, 0, stream>>>(
          hin, zb, gin_eps + gl, bt16 + (size_t)gl * 3 * 64 * 128,
          epool, rowptr_e, nodebase, N);
      gin_mlp2<<<(N + 63) / 64, 256, 0, stream>>>(
          zb, hout,
          w1t + (size_t)gl * 32768, gin_b1 + gl * 256, bn1g + gl * 256, bn1b + gl * 256,
          w2t + (size_t)gl * 32768, gin_b2 + gl * 128, bn2g + gl * 128, bn2b + gl * 128,
          N, (l != 3) ? 1 : 0);
      unsigned short* tmp = hin; hin = hout; hout = tmp;
    }
    pool_csr<<<nseg, 128, 0, stream>>>(hin, npool, rowptr_n, segbase, pooled, nseg);
  };

  // --- substructure encoder + SAB ---
  run_gin(0, Ns, sub_x, Nm, M, pooled_sub, S);
  gemm_tile<<<S, 256, 0, stream>>>(pooled_sub, sab_wq, sab_bq, Qb, 128);
  gemm_tile<<<S, 256, 0, stream>>>(pooled_sub, sab_wk, sab_bk, Kb, 128);
  gemm_tile<<<S, 256, 0, stream>>>(pooled_sub, sab_wv, sab_bv, Vb, 128);
  sab_attn<<<dim3(S, 2), 256, 0, stream>>>(Qb, Kb, Vb, Ob, S);
  ln_rows<<<S, 128, 0, stream>>>(Ob, Ob, ln1g, ln1b);
  gemm_tile<<<S, 256, 0, stream>>>(Ob, sab_wo, sab_bo, O2b, 128);
  ln_rows<<<S, 128, 0, stream>>>(O2b, subf, ln2g, ln2b);
  prep_subT<<<(128 * 512 + 255) / 256, 256, 0, stream>>>(subf, subT, S);

  // --- molecule encoder + projection ---
  run_gin(1, Nm, mol_x, 0, 0, pooled_mol, M);
  gemm_tile<<<D, 256, 0, stream>>>(avgproj, pooled_mol, (const float*)nullptr, mol_embb, 600);

  // --- attention aggregation + score ---
  gemm_tile<<<D, 256, 0, stream>>>(mol_embb, agg_wq, agg_bq, aggQb, 128);
  gemm_tile<<<S, 256, 0, stream>>>(subf, agg_wk, agg_bk, aggKb, 128);
  agg_attn<<<D, 256, 0, stream>>>(aggQb, aggKb, mask, flags, attnb, D, S);
  agg_mfma<<<D, 256, 0, stream>>>(attnb, patient, subT, aggTb, D, S);
  score_head<<<B * D, 64, 0, stream>>>(aggTb, score_w1, score_b1, score_w2, score_b2, (float*)d_out);
}

// Round 9
// 1252.617 us; speedup vs baseline: 2.3049x; 1.0653x over previous
//
#include <hip/hip_runtime.h>

// ---------------------------------------------------------------------------
// MoleRec pipeline on gfx950.
// R8: mask_detect was 86.7us for a 98KB scan — ~29K same-address global
//     atomicOr ops serialized at the L2 RMW point (VALUBusy 0.03%). Now:
//     64 grid-stride blocks, register flags -> block LDS atomicOr -> <=2
//     global atomics per block (<=128 total). score_head batched 4 outputs
//     per 256-thread block (was 12800 single-wave blocks).
// ---------------------------------------------------------------------------

typedef short short8 __attribute__((ext_vector_type(8)));
typedef unsigned short us8 __attribute__((ext_vector_type(8)));
typedef float f32x4 __attribute__((ext_vector_type(4)));
typedef unsigned short us4 __attribute__((ext_vector_type(4)));

#define BN_RSQ 0.9999950000374997f   // 1/sqrt(1+1e-5)  (BatchNorm eval, var=1)
#define LN_EPS 1e-5f
#define NEGBIG -4294967296.0f        // -(1<<32), matches reference mask fill

__device__ __forceinline__ unsigned short f2bf(float x) {
  union { float f; unsigned int u; } v; v.f = x;
  unsigned int r = v.u + 0x7fffu + ((v.u >> 16) & 1u);   // RNE
  return (unsigned short)(r >> 16);
}
__device__ __forceinline__ float bf2f(unsigned short x) {
  union { unsigned int u; float f; } v; v.u = ((unsigned int)x) << 16;
  return v.f;
}

// ---------------- weight prep: fp32 [K][N] -> bf16 [N][K] ------------------
__global__ void prep_weights(const float* __restrict__ w1, const float* __restrict__ w2,
                             unsigned short* __restrict__ w1t, unsigned short* __restrict__ w2t) {
  int i = blockIdx.x * 256 + threadIdx.x;
  if (i >= 262144) return;
  int gl = i >> 15;
  int k1 = (i >> 8) & 127, c1 = i & 255;
  w1t[(gl << 15) + c1 * 128 + k1] = f2bf(w1[i]);
  int k2 = (i >> 7) & 255, c2 = i & 127;
  w2t[(gl << 15) + c2 * 256 + k2] = f2bf(w2[i]);
}

// ---------------- bond tables fp32 -> bf16 (same layout) --------------------
__global__ void prep_bond(const float* __restrict__ in, unsigned short* __restrict__ out, int n) {
  int i = blockIdx.x * 256 + threadIdx.x;
  if (i < n) out[i] = f2bf(in[i]);
}

// ---------------- mask layout detection (block-reduced, R8) -----------------
__global__ __launch_bounds__(256) void mask_detect(const unsigned char* __restrict__ m,
                                                   int* __restrict__ flags, int nbytes) {
  __shared__ int lf[2];
  if (threadIdx.x == 0) { lf[0] = 0; lf[1] = 0; }
  __syncthreads();
  int f0 = 0, f1 = 0;
  for (int i = blockIdx.x * 256 + threadIdx.x; i < nbytes; i += gridDim.x * 256) {
    if (m[i]) { if ((i & 3) == 0) f0 = 1; else f1 = 1; }
  }
  if (f0) atomicOr(&lf[0], 1);
  if (f1) atomicOr(&lf[1], 1);
  __syncthreads();
  if (threadIdx.x == 0) {
    if (lf[0]) atomicOr(flags, 1);
    if (lf[1]) atomicOr(flags + 1, 1);
  }
}

// ---------------- CSR build: count ------------------------------------------
__global__ void build_count(const int* __restrict__ ei_m, int Em,
                            const int* __restrict__ ei_s, int Es,
                            const int* __restrict__ bm, int Nm,
                            const int* __restrict__ bs, int Ns,
                            int* __restrict__ deg_e, int* __restrict__ deg_n, int M) {
  int i = blockIdx.x * 256 + threadIdx.x;
  if (i < Em) { atomicAdd(&deg_e[ei_m[i]], 1); return; }
  i -= Em;
  if (i < Es) { atomicAdd(&deg_e[Nm + ei_s[i]], 1); return; }
  i -= Es;
  if (i < Nm) { atomicAdd(&deg_n[bm[i]], 1); return; }
  i -= Nm;
  if (i < Ns) { atomicAdd(&deg_n[M + bs[i]], 1); }
}

// ---------------- CSR build: block-level exclusive scan ---------------------
__global__ __launch_bounds__(256) void scan_block(const int* __restrict__ cnt, int n,
                                                  int* __restrict__ excl, int* __restrict__ bsum) {
  int gid = blockIdx.x * 256 + threadIdx.x;
  int lane = threadIdx.x & 63, w = threadIdx.x >> 6;
  int v = (gid < n) ? cnt[gid] : 0;
  int x = v;
#pragma unroll
  for (int off = 1; off < 64; off <<= 1) {
    int y = __shfl_up(x, off, 64);
    if (lane >= off) x += y;
  }
  __shared__ int wt[4];
  if (lane == 63) wt[w] = x;
  __syncthreads();
  int add = 0;
  for (int i = 0; i < w; i++) add += wt[i];
  x += add;
  if (gid < n) excl[gid] = x - v;
  if (threadIdx.x == 255) bsum[blockIdx.x] = x;
}

__global__ __launch_bounds__(1024) void scan_top(int* __restrict__ bsum, int n) {
  int t = threadIdx.x;
  int lane = t & 63, w = t >> 6;
  int v = (t < n) ? bsum[t] : 0;
  int x = v;
#pragma unroll
  for (int off = 1; off < 64; off <<= 1) {
    int y = __shfl_up(x, off, 64);
    if (lane >= off) x += y;
  }
  __shared__ int wt[16];
  if (lane == 63) wt[w] = x;
  __syncthreads();
  int add = 0;
  for (int i = 0; i < w; i++) add += wt[i];
  x += add;
  if (t < n) bsum[t] = x - v;
}

// ---------------- rowptr finalize: rowptr[i] = excl[i]+bsum[i>>8] -----------
__global__ void finalize_rowptr(const int* __restrict__ excl, const int* __restrict__ bsum,
                                int n, int total, int* __restrict__ rowptr) {
  int i = blockIdx.x * 256 + threadIdx.x;
  if (i < n) rowptr[i] = excl[i] + bsum[i >> 8];
  if (i == n) rowptr[n] = total;
}

// ---------------- CSR build: scatter ----------------------------------------
// epool rec: x=src*128, y=tgt_local, z=p0|(p1<<16), w=p2  (bond elem offsets)
__global__ void scatter_edges(const int* __restrict__ ei_m, const int* __restrict__ ea_m, int Em,
                              const int* __restrict__ ei_s, const int* __restrict__ ea_s, int Es, int Nm,
                              const int* __restrict__ rowptr_e,
                              int* __restrict__ cur_e, int4* __restrict__ epool) {
  int i = blockIdx.x * 256 + threadIdx.x;
  int g, tgt, src, a0, a1, a2;
  if (i < Em) {
    tgt = ei_m[i]; src = ei_m[Em + i]; g = tgt;
    a0 = ea_m[i * 3]; a1 = ea_m[i * 3 + 1]; a2 = ea_m[i * 3 + 2];
  } else {
    int j = i - Em; if (j >= Es) return;
    tgt = ei_s[j]; src = ei_s[Es + j]; g = Nm + tgt;
    a0 = ea_s[j * 3]; a1 = ea_s[j * 3 + 1]; a2 = ea_s[j * 3 + 2];
  }
  int slot = rowptr_e[g] + atomicAdd(&cur_e[g], 1);
  int p0 = a0 * 128, p1 = (64 + a1) * 128, p2 = (128 + a2) * 128;
  epool[slot] = make_int4(src * 128, tgt, p0 | (p1 << 16), p2);
}

__global__ void scatter_nodes(const int* __restrict__ bm, int Nm,
                              const int* __restrict__ bs, int Ns, int M,
                              const int* __restrict__ rowptr_n,
                              int* __restrict__ cur_n, int* __restrict__ npool) {
  int i = blockIdx.x * 256 + threadIdx.x;
  int g, node;
  if (i < Nm) { g = bm[i]; node = i; }
  else { int j = i - Nm; if (j >= Ns) return; g = M + bs[j]; node = j; }
  int slot = rowptr_n[g] + atomicAdd(&cur_n[g], 1);
  npool[slot] = node;
}

// ---------------- node embedding (bf16 out) ---------------------------------
__global__ void embed_nodes(const int* __restrict__ x, const float* __restrict__ table,
                            unsigned short* __restrict__ h, int N) {
  int i = blockIdx.x * 256 + threadIdx.x;
  if (i >= N * 128) return;
  int n = i >> 7, c = i & 127;
  float s = 0.f;
#pragma unroll
  for (int f = 0; f < 9; f++) {
    int v = x[n * 9 + f];
    s += table[(f * 64 + v) * 128 + c];
  }
  h[i] = f2bf(s);
}

// ---------------- edge gather: z = (1+eps)*h + sum relu(h[src]+bond) --------
// Node-parallel, LDS-free: 8 threads/node x 16 ch, register accumulation.
__global__ __launch_bounds__(256) void gather_z(
    const unsigned short* __restrict__ hin, unsigned short* __restrict__ z,
    const float* __restrict__ eps_p, const unsigned short* __restrict__ bt,
    const int4* __restrict__ epool, const int* __restrict__ rowptr_e, int nodebase,
    int N) {
  int gid = blockIdx.x * 256 + threadIdx.x;
  int n = gid >> 3;
  if (n >= N) return;
  int cb = (gid & 7) * 16;
  float eps1 = 1.0f + *eps_p;
  float acc[16];
  {
    const unsigned short* hr = hin + (size_t)n * 128 + cb;
    us8 v0 = *(const us8*)hr, v1 = *(const us8*)(hr + 8);
#pragma unroll
    for (int k = 0; k < 8; k++) {
      acc[k]     = eps1 * bf2f(v0[k]);
      acc[8 + k] = eps1 * bf2f(v1[k]);
    }
  }
  int e0 = rowptr_e[nodebase + n], e1 = rowptr_e[nodebase + n + 1];
  for (int e = e0; e < e1; e++) {
    int4 rec = epool[e];
    const unsigned short* hs = hin + rec.x + cb;
    const unsigned short* q0 = bt + (rec.z & 0xffff) + cb;
    const unsigned short* q1 = bt + (((unsigned)rec.z) >> 16) + cb;
    const unsigned short* q2 = bt + rec.w + cb;
    us8 a0 = *(const us8*)hs, a1 = *(const us8*)(hs + 8);
    us8 b0 = *(const us8*)q0, b1 = *(const us8*)(q0 + 8);
    us8 c0 = *(const us8*)q1, c1 = *(const us8*)(q1 + 8);
    us8 d0 = *(const us8*)q2, d1 = *(const us8*)(q2 + 8);
#pragma unroll
    for (int k = 0; k < 8; k++) {
      acc[k]     += fmaxf(bf2f(a0[k]) + bf2f(b0[k]) + bf2f(c0[k]) + bf2f(d0[k]), 0.f);
      acc[8 + k] += fmaxf(bf2f(a1[k]) + bf2f(b1[k]) + bf2f(c1[k]) + bf2f(d1[k]), 0.f);
    }
  }
  unsigned short ob[16];
#pragma unroll
  for (int k = 0; k < 16; k++) ob[k] = f2bf(acc[k]);
  unsigned short* zr = z + (size_t)n * 128 + cb;
  *(us8*)zr = *(const us8*)&ob[0];
  *(us8*)(zr + 8) = *(const us8*)&ob[8];
}

// ---------------- GIN MLP: h = bn2(relu(bn1(z@w1+b1))@w2+b2) (+relu) --------
__global__ __launch_bounds__(256) void gin_mlp2(
    const unsigned short* __restrict__ zin, unsigned short* __restrict__ hout,
    const unsigned short* __restrict__ w1t, const float* __restrict__ b1,
    const float* __restrict__ g1, const float* __restrict__ be1,
    const unsigned short* __restrict__ w2t, const float* __restrict__ b2,
    const float* __restrict__ g2, const float* __restrict__ be2,
    int N, int do_relu) {
  __shared__ unsigned short zs[64][136];    // 64x128 bf16, +8 pad
  __shared__ unsigned short z1s[64][264];   // 64x256 bf16, +8 pad
  int t = threadIdx.x;
  int r0 = blockIdx.x * 64;
  for (int i = t; i < 2048; i += 256) {
    int r = i >> 5, c4 = (i & 31) << 2;
    int n = r0 + r;
    us4 v;
    if (n < N) v = *(const us4*)(zin + (size_t)n * 128 + c4);
    else { v.x = 0; v.y = 0; v.z = 0; v.w = 0; }
    *(us4*)&zs[r][c4] = v;
  }
  __syncthreads();
  int lane = t & 63, wave = t >> 6;
  int quad = lane >> 4, l16 = lane & 15;
  // Phase B: z1[64x256] = relu(bn1(z @ w1 + b1)); wave handles 64 cols
  {
    short8 bw[4][4];
    int cb = wave * 64;
#pragma unroll
    for (int nt = 0; nt < 4; nt++) {
      const unsigned short* p = w1t + (cb + nt * 16 + l16) * 128 + quad * 8;
#pragma unroll
      for (int kc = 0; kc < 4; kc++) bw[nt][kc] = *(const short8*)(p + kc * 32);
    }
#pragma unroll
    for (int mt = 0; mt < 4; mt++) {
      short8 af[4];
#pragma unroll
      for (int kc = 0; kc < 4; kc++)
        af[kc] = *(const short8*)&zs[mt * 16 + l16][kc * 32 + quad * 8];
#pragma unroll
      for (int nt = 0; nt < 4; nt++) {
        f32x4 acc = {0.f, 0.f, 0.f, 0.f};
#pragma unroll
        for (int kc = 0; kc < 4; kc++)
          acc = __builtin_amdgcn_mfma_f32_16x16x32_bf16(af[kc], bw[nt][kc], acc, 0, 0, 0);
        int c = cb + nt * 16 + l16;
        float sc = g1[c] * BN_RSQ, sh = be1[c], bb = b1[c];
#pragma unroll
        for (int reg = 0; reg < 4; reg++) {
          int r = mt * 16 + quad * 4 + reg;
          float y = (acc[reg] + bb) * sc + sh;
          z1s[r][c] = f2bf(fmaxf(y, 0.f));
        }
      }
    }
  }
  __syncthreads();
  // Phase C: h_out = bn2(z1 @ w2 + b2) (+relu); wave handles 32 cols
  {
    short8 bw[2][8];
    int cb = wave * 32;
#pragma unroll
    for (int nt = 0; nt < 2; nt++) {
      const unsigned short* p = w2t + (cb + nt * 16 + l16) * 256 + quad * 8;
#pragma unroll
      for (int kc = 0; kc < 8; kc++) bw[nt][kc] = *(const short8*)(p + kc * 32);
    }
#pragma unroll
    for (int mt = 0; mt < 4; mt++) {
      short8 af[8];
#pragma unroll
      for (int kc = 0; kc < 8; kc++)
        af[kc] = *(const short8*)&z1s[mt * 16 + l16][kc * 32 + quad * 8];
#pragma unroll
      for (int nt = 0; nt < 2; nt++) {
        f32x4 acc = {0.f, 0.f, 0.f, 0.f};
#pragma unroll
        for (int kc = 0; kc < 8; kc++)
          acc = __builtin_amdgcn_mfma_f32_16x16x32_bf16(af[kc], bw[nt][kc], acc, 0, 0, 0);
        int c = cb + nt * 16 + l16;
        float sc = g2[c] * BN_RSQ, sh = be2[c], bb = b2[c];
#pragma unroll
        for (int reg = 0; reg < 4; reg++) {
          int n = r0 + mt * 16 + quad * 4 + reg;
          if (n < N) {
            float y = (acc[reg] + bb) * sc + sh;
            if (do_relu) y = fmaxf(y, 0.f);
            hout[n * 128 + c] = f2bf(y);
          }
        }
      }
    }
  }
}

// ---------------- CSR mean pooling (bf16 h) ---------------------------------
__global__ __launch_bounds__(128) void pool_csr(const unsigned short* __restrict__ h,
                                                const int* __restrict__ npool,
                                                const int* __restrict__ rowptr_n,
                                                int segbase, float* __restrict__ pooled, int nseg) {
  int m = blockIdx.x;
  if (m >= nseg) return;
  int g = segbase + m;
  int st = rowptr_n[g];
  int e = rowptr_n[g + 1];
  int len = e - st;
  int c = threadIdx.x;
  float s = 0.f;
  int i = st;
  for (; i + 3 < e; i += 4) {
    int n0 = npool[i], n1 = npool[i + 1], n2 = npool[i + 2], n3 = npool[i + 3];
    float v0 = bf2f(h[(size_t)n0 * 128 + c]);
    float v1 = bf2f(h[(size_t)n1 * 128 + c]);
    float v2 = bf2f(h[(size_t)n2 * 128 + c]);
    float v3 = bf2f(h[(size_t)n3 * 128 + c]);
    s += (v0 + v1) + (v2 + v3);
  }
  for (; i < e; i++) s += bf2f(h[(size_t)npool[i] * 128 + c]);
  pooled[m * 128 + c] = s / ((float)len + 1e-9f);
}

// ---------------- row GEMM (N=128): C[r,:] = A[r,:] @ W + bias --------------
__global__ __launch_bounds__(256) void gemm_tile(const float* __restrict__ A, const float* __restrict__ W,
                                                 const float* __restrict__ bias, float* __restrict__ C,
                                                 int K) {
  __shared__ float As[608];
  __shared__ float red[128];
  int r = blockIdx.x;
  int t = threadIdx.x;
  for (int i = t; i < K; i += 256) As[i] = A[(size_t)r * K + i];
  __syncthreads();
  int c = t & 127, half = t >> 7;
  int Kh = K >> 1;
  int k0 = half * Kh, k1 = k0 + Kh;
  float acc = 0.f;
#pragma unroll 8
  for (int k = k0; k < k1; k++) acc = fmaf(As[k], W[(size_t)k * 128 + c], acc);
  if (half) red[c] = acc;
  __syncthreads();
  if (!half) {
    float v = acc + red[c] + (bias ? bias[c] : 0.f);
    C[(size_t)r * 128 + c] = v;
  }
}

// ---------------- SAB attention: O = Qs + softmax(QsKs^T/8) Vs -------------
__global__ __launch_bounds__(256) void sab_attn(const float* __restrict__ Q, const float* __restrict__ K,
                                                const float* __restrict__ V, float* __restrict__ O, int S) {
  int q = blockIdx.x, hd = blockIdx.y;
  int t = threadIdx.x;
  __shared__ float sc[512];
  __shared__ float red[8];
  __shared__ float pacc[4][64];
  const float* qrow = Q + q * 128 + hd * 64;
  for (int k = t; k < 512; k += 256) {
    float d = -1e30f;
    if (k < S) {
      const float* krow = K + k * 128 + hd * 64;
      d = 0.f;
#pragma unroll
      for (int j = 0; j < 64; j += 4) {
        float4 a = *(const float4*)(qrow + j);
        float4 b = *(const float4*)(krow + j);
        d += a.x * b.x + a.y * b.y + a.z * b.z + a.w * b.w;
      }
      d *= 0.125f;
    }
    sc[k] = d;
  }
  __syncthreads();
  float m = fmaxf(sc[t], sc[t + 256]);
  for (int off = 32; off; off >>= 1) m = fmaxf(m, __shfl_down(m, off));
  if ((t & 63) == 0) red[t >> 6] = m;
  __syncthreads();
  m = fmaxf(fmaxf(red[0], red[1]), fmaxf(red[2], red[3]));
  float p0 = __expf(sc[t] - m), p1 = __expf(sc[t + 256] - m);
  sc[t] = p0; sc[t + 256] = p1;
  float s = p0 + p1;
  for (int off = 32; off; off >>= 1) s += __shfl_down(s, off);
  if ((t & 63) == 0) red[4 + (t >> 6)] = s;
  __syncthreads();
  float inv = 1.f / (red[4] + red[5] + red[6] + red[7]);
  int d = t & 63, part = t >> 6;
  float acc = 0.f;
  for (int k = part; k < S; k += 4) acc += sc[k] * V[k * 128 + hd * 64 + d];
  pacc[part][d] = acc;
  __syncthreads();
  if (part == 0) {
    float o = (pacc[0][d] + pacc[1][d] + pacc[2][d] + pacc[3][d]) * inv;
    O[q * 128 + hd * 64 + d] = qrow[d] + o;
  }
}

// ---------------- row LayerNorm over 128 ------------------------------------
__global__ __launch_bounds__(128) void ln_rows(const float* __restrict__ in, float* __restrict__ out,
                                               const float* __restrict__ g, const float* __restrict__ b) {
  int r = blockIdx.x, t = threadIdx.x;
  __shared__ float red[4];
  float x = in[r * 128 + t];
  float s = x;
  for (int off = 32; off; off >>= 1) s += __shfl_down(s, off);
  if ((t & 63) == 0) red[t >> 6] = s;
  __syncthreads();
  float mu = (red[0] + red[1]) * (1.f / 128.f);
  float dd = x - mu;
  float v = dd * dd;
  for (int off = 32; off; off >>= 1) v += __shfl_down(v, off);
  if ((t & 63) == 0) red[2 + (t >> 6)] = v;
  __syncthreads();
  float var = (red[2] + red[3]) * (1.f / 128.f);
  out[r * 128 + t] = g[t] * dd * rsqrtf(var + LN_EPS) + b[t];
}

// ---------------- masked softmax attn: attn[d,s] ----------------------------
__global__ __launch_bounds__(256) void agg_attn(const float* __restrict__ Q, const float* __restrict__ Kt,
                                                const void* __restrict__ mask, const int* __restrict__ flags,
                                                float* __restrict__ attn, int D, int S) {
  int d = blockIdx.x, t = threadIdx.x;
  __shared__ float sc[512];
  __shared__ float red[8];
  int layout = (flags[1] == 0) ? 0 : (flags[0] ? 1 : 2);
  const float* qrow = Q + d * 128;
  for (int s = t; s < 512; s += 256) {
    float v = NEGBIG;
    if (s < S) {
      int mi = d * S + s;
      bool msk;
      if (layout == 0)      msk = ((const int*)mask)[mi] != 0;
      else if (layout == 1) msk = ((const unsigned char*)mask)[mi] != 0;
      else                  msk = ((const float*)mask)[mi] != 0.f;
      if (!msk) {
        float dd = 0.f;
        const float* krow = Kt + s * 128;
#pragma unroll
        for (int j = 0; j < 128; j += 4) {
          float4 a = *(const float4*)(qrow + j);
          float4 b = *(const float4*)(krow + j);
          dd += a.x * b.x + a.y * b.y + a.z * b.z + a.w * b.w;
        }
        v = dd * 0.08838834764831845f;
      }
    }
    sc[s] = v;
  }
  __syncthreads();
  float m = fmaxf(sc[t], sc[t + 256]);
  for (int off = 32; off; off >>= 1) m = fmaxf(m, __shfl_down(m, off));
  if ((t & 63) == 0) red[t >> 6] = m;
  __syncthreads();
  m = fmaxf(fmaxf(red[0], red[1]), fmaxf(red[2], red[3]));
  float p0 = __expf(sc[t] - m), p1 = __expf(sc[t + 256] - m);
  float s2 = p0 + p1;
  for (int off = 32; off; off >>= 1) s2 += __shfl_down(s2, off);
  if ((t & 63) == 0) red[4 + (t >> 6)] = s2;
  __syncthreads();
  float inv = 1.f / (red[4] + red[5] + red[6] + red[7]);
  attn[d * S + t] = p0 * inv;
  if (t + 256 < S) attn[d * S + t + 256] = p1 * inv;
}

// ---------------- subT prep: subf [S][128] f32 -> subT bf16 [128][512] ------
__global__ void prep_subT(const float* __restrict__ subf, unsigned short* __restrict__ subT, int S) {
  int i = blockIdx.x * 256 + threadIdx.x;
  if (i >= 128 * 512) return;
  int hh = i >> 9, k = i & 511;
  subT[i] = (k < S) ? f2bf(subf[k * 128 + hh]) : (unsigned short)0;
}

// ---------------- agg via MFMA: per d, (pat .* attn[d])[64x492] @ sub -------
__global__ __launch_bounds__(256) void agg_mfma(const float* __restrict__ attn, const float* __restrict__ pat,
                                                const unsigned short* __restrict__ subT,
                                                float* __restrict__ aggT, int D, int S) {
  int d = blockIdx.x, t = threadIdx.x;
  __shared__ unsigned short As[64][40];
  int lane = t & 63, wave = t >> 6;
  int quad = lane >> 4, l16 = lane & 15;
  f32x4 acc[8];
#pragma unroll
  for (int nt = 0; nt < 8; nt++) acc[nt] = (f32x4){0.f, 0.f, 0.f, 0.f};
  const float* arow = attn + d * S;
  int srow = t >> 2, skb = (t & 3) * 8;
  for (int c = 0; c < 16; c++) {
    int s0 = c * 32;
    __syncthreads();
    unsigned short v[8];
#pragma unroll
    for (int j = 0; j < 8; j++) {
      int s = s0 + skb + j;
      float x = (s < S) ? arow[s] * pat[srow * S + s] : 0.f;
      v[j] = f2bf(x);
    }
    *(us4*)&As[srow][skb]     = *(us4*)&v[0];
    *(us4*)&As[srow][skb + 4] = *(us4*)&v[4];
    __syncthreads();
    short8 af = *(const short8*)&As[16 * wave + l16][quad * 8];
#pragma unroll
    for (int nt = 0; nt < 8; nt++) {
      short8 bf = *(const short8*)(subT + (nt * 16 + l16) * 512 + s0 + quad * 8);
      acc[nt] = __builtin_amdgcn_mfma_f32_16x16x32_bf16(af, bf, acc[nt], 0, 0, 0);
    }
  }
#pragma unroll
  for (int nt = 0; nt < 8; nt++) {
    int hh = nt * 16 + l16;
#pragma unroll
    for (int reg = 0; reg < 4; reg++) {
      int b = 16 * wave + quad * 4 + reg;
      aggT[((size_t)(b * D + d)) * 128 + hh] = acc[nt][reg];
    }
  }
}

// ---------------- score head: sigmoid(relu(agg@w1+b1)@w2+b2), 4 rows/block --
__global__ __launch_bounds__(256) void score_head(const float* __restrict__ aggT,
                                                  const float* __restrict__ w1, const float* __restrict__ b1,
                                                  const float* __restrict__ w2, const float* __restrict__ b2,
                                                  float* __restrict__ out, int total) {
  int i = blockIdx.x * 4 + (threadIdx.x >> 6);   // one output per wave
  int j = threadIdx.x & 63;
  if (i >= total) return;
  const float* av = aggT + (size_t)i * 128;
  float acc = b1[j];
#pragma unroll 8
  for (int k = 0; k < 128; k++) acc = fmaf(av[k], w1[k * 64 + j], acc);
  acc = fmaxf(acc, 0.f) * w2[j];
  for (int off = 32; off; off >>= 1) acc += __shfl_down(acc, off);
  if (j == 0) {
    float x = acc + b2[0];
    out[i] = 1.f / (1.f + __expf(-x));
  }
}

// ---------------------------------------------------------------------------
extern "C" void kernel_launch(void* const* d_in, const int* in_sizes, int n_in,
                              void* d_out, int out_size, void* d_ws, size_t ws_size,
                              hipStream_t stream) {
  const float* atom_emb = (const float*)d_in[0];
  const float* bond_emb = (const float*)d_in[1];
  const float* gin_eps  = (const float*)d_in[2];
  const float* gin_w1   = (const float*)d_in[3];
  const float* gin_b1   = (const float*)d_in[4];
  const float* bn1g     = (const float*)d_in[5];
  const float* bn1b     = (const float*)d_in[6];
  const float* gin_w2   = (const float*)d_in[7];
  const float* gin_b2   = (const float*)d_in[8];
  const float* bn2g     = (const float*)d_in[9];
  const float* bn2b     = (const float*)d_in[10];
  const float* sab_wq = (const float*)d_in[11];
  const float* sab_wk = (const float*)d_in[12];
  const float* sab_wv = (const float*)d_in[13];
  const float* sab_wo = (const float*)d_in[14];
  const float* sab_bq = (const float*)d_in[15];
  const float* sab_bk = (const float*)d_in[16];
  const float* sab_bv = (const float*)d_in[17];
  const float* sab_bo = (const float*)d_in[18];
  const float* ln1b = (const float*)d_in[19];
  const float* ln2b = (const float*)d_in[20];
  const float* ln1g = (const float*)d_in[21];
  const float* ln2g = (const float*)d_in[22];
  const float* agg_wq = (const float*)d_in[23];
  const float* agg_bq = (const float*)d_in[24];
  const float* agg_wk = (const float*)d_in[25];
  const float* agg_bk = (const float*)d_in[26];
  const float* score_w1 = (const float*)d_in[27];
  const float* score_b1 = (const float*)d_in[28];
  const float* score_w2 = (const float*)d_in[29];
  const float* score_b2 = (const float*)d_in[30];
  const float* patient  = (const float*)d_in[31];
  const float* avgproj  = (const float*)d_in[32];
  const int* sub_x     = (const int*)d_in[33];
  const int* sub_ea    = (const int*)d_in[34];
  const int* sub_ei    = (const int*)d_in[35];
  const int* sub_batch = (const int*)d_in[36];
  const int* mol_x     = (const int*)d_in[37];
  const int* mol_ea    = (const int*)d_in[38];
  const int* mol_ei    = (const int*)d_in[39];
  const int* mol_batch = (const int*)d_in[40];
  const void* mask     = d_in[41];

  const int Ns = in_sizes[33] / 9, Es = in_sizes[34] / 3;
  const int Nm = in_sizes[37] / 9, Em = in_sizes[38] / 3;
  const int S = 492, M = 600, D = 200, B = 64;
  const int NE = Nm + Ns;           // edge-CSR index space (mol first)
  const int NSEG = M + S;           // node-CSR index space (mol first)
  const int ETOT = Em + Es;
  const int BONDE = 2 * 4 * 3 * 64 * 128;   // bond table elements

  // ---- workspace carve-up ----
  char* Wp = (char*)d_ws;
  size_t off = 0;
  auto alloc = [&](size_t bytes) -> void* {
    void* p = Wp + off;
    off = (off + bytes + 255) & ~(size_t)255;
    return p;
  };
  int NR = ((Nm > Ns ? Nm : Ns) + 63) & ~63;
  unsigned short* h0 = (unsigned short*)alloc((size_t)NR * 128 * 2);
  unsigned short* h1 = (unsigned short*)alloc((size_t)NR * 128 * 2);
  unsigned short* zb = (unsigned short*)alloc((size_t)NR * 128 * 2);
  unsigned short* w1t = (unsigned short*)alloc(262144 * 2);
  unsigned short* w2t = (unsigned short*)alloc(262144 * 2);
  unsigned short* bt16 = (unsigned short*)alloc((size_t)BONDE * 2);
  int4* epool  = (int4*)alloc((size_t)ETOT * 16);
  int*  npool  = (int*)alloc((size_t)NE * 4);
  int*  excl_e = (int*)alloc((size_t)NE * 4);
  int*  bsum_e = (int*)alloc(1024 * 4);
  int*  excl_n = (int*)alloc((size_t)NSEG * 4);
  int*  bsum_n = (int*)alloc(1024 * 4);
  int*  rowptr_e = (int*)alloc((size_t)(NE + 1) * 4);
  int*  rowptr_n = (int*)alloc((size_t)(NSEG + 1) * 4);
  char* zstart = Wp + off;                       // region zeroed below
  int*  deg_e  = (int*)alloc((size_t)NE * 4);
  int*  deg_n  = (int*)alloc((size_t)NSEG * 4);
  int*  cur_e  = (int*)alloc((size_t)NE * 4);
  int*  cur_n  = (int*)alloc((size_t)NSEG * 4);
  int*  flags  = (int*)alloc(8);
  size_t zsize = (size_t)((Wp + off) - zstart);
  float* pooled_sub = (float*)alloc((size_t)S * 128 * 4);
  float* pooled_mol = (float*)alloc((size_t)M * 128 * 4);
  float* Qb   = (float*)alloc((size_t)S * 128 * 4);
  float* Kb   = (float*)alloc((size_t)S * 128 * 4);
  float* Vb   = (float*)alloc((size_t)S * 128 * 4);
  float* Ob   = (float*)alloc((size_t)S * 128 * 4);
  float* O2b  = (float*)alloc((size_t)S * 128 * 4);
  float* subf = (float*)alloc((size_t)S * 128 * 4);
  unsigned short* subT = (unsigned short*)alloc((size_t)128 * 512 * 2);
  float* mol_embb = (float*)alloc((size_t)D * 128 * 4);
  float* aggQb = (float*)alloc((size_t)D * 128 * 4);
  float* aggKb = (float*)alloc((size_t)S * 128 * 4);
  float* attnb = (float*)alloc((size_t)D * S * 4);
  float* aggTb = (float*)alloc((size_t)B * D * 128 * 4);
  (void)ws_size; (void)n_in; (void)out_size;

  hipMemsetAsync(zstart, 0, zsize, stream);
  prep_weights<<<1024, 256, 0, stream>>>(gin_w1, gin_w2, w1t, w2t);
  prep_bond<<<(BONDE + 255) / 256, 256, 0, stream>>>(bond_emb, bt16, BONDE);
  mask_detect<<<64, 256, 0, stream>>>((const unsigned char*)mask, flags, D * S);

  // ---- CSR build (edges by tgt; nodes by batch) ----
  int total_cnt = Em + Es + Nm + Ns;
  build_count<<<(total_cnt + 255) / 256, 256, 0, stream>>>(
      mol_ei, Em, sub_ei, Es, mol_batch, Nm, sub_batch, Ns, deg_e, deg_n, M);
  int nb_e = (NE + 255) / 256;        // <= 1024
  int nb_n = (NSEG + 255) / 256;
  scan_block<<<nb_e, 256, 0, stream>>>(deg_e, NE, excl_e, bsum_e);
  scan_top<<<1, 1024, 0, stream>>>(bsum_e, nb_e);
  scan_block<<<nb_n, 256, 0, stream>>>(deg_n, NSEG, excl_n, bsum_n);
  scan_top<<<1, 1024, 0, stream>>>(bsum_n, nb_n);
  finalize_rowptr<<<(NE + 256) / 256 + 1, 256, 0, stream>>>(excl_e, bsum_e, NE, ETOT, rowptr_e);
  finalize_rowptr<<<(NSEG + 256) / 256 + 1, 256, 0, stream>>>(excl_n, bsum_n, NSEG, NE, rowptr_n);
  scatter_edges<<<(ETOT + 255) / 256, 256, 0, stream>>>(
      mol_ei, mol_ea, Em, sub_ei, sub_ea, Es, Nm, rowptr_e, cur_e, epool);
  scatter_nodes<<<(NE + 255) / 256, 256, 0, stream>>>(
      mol_batch, Nm, sub_batch, Ns, M, rowptr_n, cur_n, npool);

  auto run_gin = [&](int g, int N, const int* x, int nodebase, int segbase,
                     float* pooled, int nseg) {
    embed_nodes<<<(N * 128 + 255) / 256, 256, 0, stream>>>(
        x, atom_emb + (size_t)g * 9 * 64 * 128, h0, N);
    unsigned short* hin = h0; unsigned short* hout = h1;
    for (int l = 0; l < 4; l++) {
      int gl = g * 4 + l;
      gather_z<<<(N * 8 + 255) / 256, 256, 0, stream>>>(
          hin, zb, gin_eps + gl, bt16 + (size_t)gl * 3 * 64 * 128,
          epool, rowptr_e, nodebase, N);
      gin_mlp2<<<(N + 63) / 64, 256, 0, stream>>>(
          zb, hout,
          w1t + (size_t)gl * 32768, gin_b1 + gl * 256, bn1g + gl * 256, bn1b + gl * 256,
          w2t + (size_t)gl * 32768, gin_b2 + gl * 128, bn2g + gl * 128, bn2b + gl * 128,
          N, (l != 3) ? 1 : 0);
      unsigned short* tmp = hin; hin = hout; hout = tmp;
    }
    pool_csr<<<nseg, 128, 0, stream>>>(hin, npool, rowptr_n, segbase, pooled, nseg);
  };

  // --- substructure encoder + SAB ---
  run_gin(0, Ns, sub_x, Nm, M, pooled_sub, S);
  gemm_tile<<<S, 256, 0, stream>>>(pooled_sub, sab_wq, sab_bq, Qb, 128);
  gemm_tile<<<S, 256, 0, stream>>>(pooled_sub, sab_wk, sab_bk, Kb, 128);
  gemm_tile<<<S, 256, 0, stream>>>(pooled_sub, sab_wv, sab_bv, Vb, 128);
  sab_attn<<<dim3(S, 2), 256, 0, stream>>>(Qb, Kb, Vb, Ob, S);
  ln_rows<<<S, 128, 0, stream>>>(Ob, Ob, ln1g, ln1b);
  gemm_tile<<<S, 256, 0, stream>>>(Ob, sab_wo, sab_bo, O2b, 128);
  ln_rows<<<S, 128, 0, stream>>>(O2b, subf, ln2g, ln2b);
  prep_subT<<<(128 * 512 + 255) / 256, 256, 0, stream>>>(subf, subT, S);

  // --- molecule encoder + projection ---
  run_gin(1, Nm, mol_x, 0, 0, pooled_mol, M);
  gemm_tile<<<D, 256, 0, stream>>>(avgproj, pooled_mol, (const float*)nullptr, mol_embb, 600);

  // --- attention aggregation + score ---
  gemm_tile<<<D, 256, 0, stream>>>(mol_embb, agg_wq, agg_bq, aggQb, 128);
  gemm_tile<<<S, 256, 0, stream>>>(subf, agg_wk, agg_bk, aggKb, 128);
  agg_attn<<<D, 256, 0, stream>>>(aggQb, aggKb, mask, flags, attnb, D, S);
  agg_mfma<<<D, 256, 0, stream>>>(attnb, patient, subT, aggTb, D, S);
  score_head<<<(B * D + 3) / 4, 256, 0, stream>>>(aggTb, score_w1, score_b1, score_w2, score_b2,
                                                  (float*)d_out, B * D);
}

// Round 10
// 1196.216 us; speedup vs baseline: 2.4136x; 1.0471x over previous
//
#include <hip/hip_runtime.h>

// ---------------------------------------------------------------------------
// MoleRec pipeline on gfx950.
// R9: gin_mlp2 was latency-bound at 26% occupancy (MfmaUtil 10%, VALU 20%,
//     HBM 10% — nothing busy; 51.2KB LDS -> 3 blocks/CU). zs and z1s now
//     OVERLAY in one 38144B buffer: Phase B runs per-mt with a barrier, so
//     z1s rows grow over zs rows already consumed (zs at +20736; worst-case
//     (m+1)*8448 <= 20736+m*4352, equality at m=3). 4 blocks/CU, 16
//     waves/CU. QKV projections fused into one gemm_qkv launch.
// ---------------------------------------------------------------------------

typedef short short8 __attribute__((ext_vector_type(8)));
typedef unsigned short us8 __attribute__((ext_vector_type(8)));
typedef float f32x4 __attribute__((ext_vector_type(4)));
typedef unsigned short us4 __attribute__((ext_vector_type(4)));

#define BN_RSQ 0.9999950000374997f   // 1/sqrt(1+1e-5)  (BatchNorm eval, var=1)
#define LN_EPS 1e-5f
#define NEGBIG -4294967296.0f        // -(1<<32), matches reference mask fill

__device__ __forceinline__ unsigned short f2bf(float x) {
  union { float f; unsigned int u; } v; v.f = x;
  unsigned int r = v.u + 0x7fffu + ((v.u >> 16) & 1u);   // RNE
  return (unsigned short)(r >> 16);
}
__device__ __forceinline__ float bf2f(unsigned short x) {
  union { unsigned int u; float f; } v; v.u = ((unsigned int)x) << 16;
  return v.f;
}

// ---------------- weight prep: fp32 [K][N] -> bf16 [N][K] ------------------
__global__ void prep_weights(const float* __restrict__ w1, const float* __restrict__ w2,
                             unsigned short* __restrict__ w1t, unsigned short* __restrict__ w2t) {
  int i = blockIdx.x * 256 + threadIdx.x;
  if (i >= 262144) return;
  int gl = i >> 15;
  int k1 = (i >> 8) & 127, c1 = i & 255;
  w1t[(gl << 15) + c1 * 128 + k1] = f2bf(w1[i]);
  int k2 = (i >> 7) & 255, c2 = i & 127;
  w2t[(gl << 15) + c2 * 256 + k2] = f2bf(w2[i]);
}

// ---------------- bond tables fp32 -> bf16 (same layout) --------------------
__global__ void prep_bond(const float* __restrict__ in, unsigned short* __restrict__ out, int n) {
  int i = blockIdx.x * 256 + threadIdx.x;
  if (i < n) out[i] = f2bf(in[i]);
}

// ---------------- mask layout detection (block-reduced) ---------------------
__global__ __launch_bounds__(256) void mask_detect(const unsigned char* __restrict__ m,
                                                   int* __restrict__ flags, int nbytes) {
  __shared__ int lf[2];
  if (threadIdx.x == 0) { lf[0] = 0; lf[1] = 0; }
  __syncthreads();
  int f0 = 0, f1 = 0;
  for (int i = blockIdx.x * 256 + threadIdx.x; i < nbytes; i += gridDim.x * 256) {
    if (m[i]) { if ((i & 3) == 0) f0 = 1; else f1 = 1; }
  }
  if (f0) atomicOr(&lf[0], 1);
  if (f1) atomicOr(&lf[1], 1);
  __syncthreads();
  if (threadIdx.x == 0) {
    if (lf[0]) atomicOr(flags, 1);
    if (lf[1]) atomicOr(flags + 1, 1);
  }
}

// ---------------- CSR build: count ------------------------------------------
__global__ void build_count(const int* __restrict__ ei_m, int Em,
                            const int* __restrict__ ei_s, int Es,
                            const int* __restrict__ bm, int Nm,
                            const int* __restrict__ bs, int Ns,
                            int* __restrict__ deg_e, int* __restrict__ deg_n, int M) {
  int i = blockIdx.x * 256 + threadIdx.x;
  if (i < Em) { atomicAdd(&deg_e[ei_m[i]], 1); return; }
  i -= Em;
  if (i < Es) { atomicAdd(&deg_e[Nm + ei_s[i]], 1); return; }
  i -= Es;
  if (i < Nm) { atomicAdd(&deg_n[bm[i]], 1); return; }
  i -= Nm;
  if (i < Ns) { atomicAdd(&deg_n[M + bs[i]], 1); }
}

// ---------------- CSR build: block-level exclusive scan ---------------------
__global__ __launch_bounds__(256) void scan_block(const int* __restrict__ cnt, int n,
                                                  int* __restrict__ excl, int* __restrict__ bsum) {
  int gid = blockIdx.x * 256 + threadIdx.x;
  int lane = threadIdx.x & 63, w = threadIdx.x >> 6;
  int v = (gid < n) ? cnt[gid] : 0;
  int x = v;
#pragma unroll
  for (int off = 1; off < 64; off <<= 1) {
    int y = __shfl_up(x, off, 64);
    if (lane >= off) x += y;
  }
  __shared__ int wt[4];
  if (lane == 63) wt[w] = x;
  __syncthreads();
  int add = 0;
  for (int i = 0; i < w; i++) add += wt[i];
  x += add;
  if (gid < n) excl[gid] = x - v;
  if (threadIdx.x == 255) bsum[blockIdx.x] = x;
}

__global__ __launch_bounds__(1024) void scan_top(int* __restrict__ bsum, int n) {
  int t = threadIdx.x;
  int lane = t & 63, w = t >> 6;
  int v = (t < n) ? bsum[t] : 0;
  int x = v;
#pragma unroll
  for (int off = 1; off < 64; off <<= 1) {
    int y = __shfl_up(x, off, 64);
    if (lane >= off) x += y;
  }
  __shared__ int wt[16];
  if (lane == 63) wt[w] = x;
  __syncthreads();
  int add = 0;
  for (int i = 0; i < w; i++) add += wt[i];
  x += add;
  if (t < n) bsum[t] = x - v;
}

// ---------------- rowptr finalize: rowptr[i] = excl[i]+bsum[i>>8] -----------
__global__ void finalize_rowptr(const int* __restrict__ excl, const int* __restrict__ bsum,
                                int n, int total, int* __restrict__ rowptr) {
  int i = blockIdx.x * 256 + threadIdx.x;
  if (i < n) rowptr[i] = excl[i] + bsum[i >> 8];
  if (i == n) rowptr[n] = total;
}

// ---------------- CSR build: scatter ----------------------------------------
// epool rec: x=src*128, y=tgt_local, z=p0|(p1<<16), w=p2  (bond elem offsets)
__global__ void scatter_edges(const int* __restrict__ ei_m, const int* __restrict__ ea_m, int Em,
                              const int* __restrict__ ei_s, const int* __restrict__ ea_s, int Es, int Nm,
                              const int* __restrict__ rowptr_e,
                              int* __restrict__ cur_e, int4* __restrict__ epool) {
  int i = blockIdx.x * 256 + threadIdx.x;
  int g, tgt, src, a0, a1, a2;
  if (i < Em) {
    tgt = ei_m[i]; src = ei_m[Em + i]; g = tgt;
    a0 = ea_m[i * 3]; a1 = ea_m[i * 3 + 1]; a2 = ea_m[i * 3 + 2];
  } else {
    int j = i - Em; if (j >= Es) return;
    tgt = ei_s[j]; src = ei_s[Es + j]; g = Nm + tgt;
    a0 = ea_s[j * 3]; a1 = ea_s[j * 3 + 1]; a2 = ea_s[j * 3 + 2];
  }
  int slot = rowptr_e[g] + atomicAdd(&cur_e[g], 1);
  int p0 = a0 * 128, p1 = (64 + a1) * 128, p2 = (128 + a2) * 128;
  epool[slot] = make_int4(src * 128, tgt, p0 | (p1 << 16), p2);
}

__global__ void scatter_nodes(const int* __restrict__ bm, int Nm,
                              const int* __restrict__ bs, int Ns, int M,
                              const int* __restrict__ rowptr_n,
                              int* __restrict__ cur_n, int* __restrict__ npool) {
  int i = blockIdx.x * 256 + threadIdx.x;
  int g, node;
  if (i < Nm) { g = bm[i]; node = i; }
  else { int j = i - Nm; if (j >= Ns) return; g = M + bs[j]; node = j; }
  int slot = rowptr_n[g] + atomicAdd(&cur_n[g], 1);
  npool[slot] = node;
}

// ---------------- node embedding (bf16 out) ---------------------------------
__global__ void embed_nodes(const int* __restrict__ x, const float* __restrict__ table,
                            unsigned short* __restrict__ h, int N) {
  int i = blockIdx.x * 256 + threadIdx.x;
  if (i >= N * 128) return;
  int n = i >> 7, c = i & 127;
  float s = 0.f;
#pragma unroll
  for (int f = 0; f < 9; f++) {
    int v = x[n * 9 + f];
    s += table[(f * 64 + v) * 128 + c];
  }
  h[i] = f2bf(s);
}

// ---------------- edge gather: z = (1+eps)*h + sum relu(h[src]+bond) --------
// Node-parallel, LDS-free: 8 threads/node x 16 ch, register accumulation.
__global__ __launch_bounds__(256) void gather_z(
    const unsigned short* __restrict__ hin, unsigned short* __restrict__ z,
    const float* __restrict__ eps_p, const unsigned short* __restrict__ bt,
    const int4* __restrict__ epool, const int* __restrict__ rowptr_e, int nodebase,
    int N) {
  int gid = blockIdx.x * 256 + threadIdx.x;
  int n = gid >> 3;
  if (n >= N) return;
  int cb = (gid & 7) * 16;
  float eps1 = 1.0f + *eps_p;
  float acc[16];
  {
    const unsigned short* hr = hin + (size_t)n * 128 + cb;
    us8 v0 = *(const us8*)hr, v1 = *(const us8*)(hr + 8);
#pragma unroll
    for (int k = 0; k < 8; k++) {
      acc[k]     = eps1 * bf2f(v0[k]);
      acc[8 + k] = eps1 * bf2f(v1[k]);
    }
  }
  int e0 = rowptr_e[nodebase + n], e1 = rowptr_e[nodebase + n + 1];
  for (int e = e0; e < e1; e++) {
    int4 rec = epool[e];
    const unsigned short* hs = hin + rec.x + cb;
    const unsigned short* q0 = bt + (rec.z & 0xffff) + cb;
    const unsigned short* q1 = bt + (((unsigned)rec.z) >> 16) + cb;
    const unsigned short* q2 = bt + rec.w + cb;
    us8 a0 = *(const us8*)hs, a1 = *(const us8*)(hs + 8);
    us8 b0 = *(const us8*)q0, b1 = *(const us8*)(q0 + 8);
    us8 c0 = *(const us8*)q1, c1 = *(const us8*)(q1 + 8);
    us8 d0 = *(const us8*)q2, d1 = *(const us8*)(q2 + 8);
#pragma unroll
    for (int k = 0; k < 8; k++) {
      acc[k]     += fmaxf(bf2f(a0[k]) + bf2f(b0[k]) + bf2f(c0[k]) + bf2f(d0[k]), 0.f);
      acc[8 + k] += fmaxf(bf2f(a1[k]) + bf2f(b1[k]) + bf2f(c1[k]) + bf2f(d1[k]), 0.f);
    }
  }
  unsigned short ob[16];
#pragma unroll
  for (int k = 0; k < 16; k++) ob[k] = f2bf(acc[k]);
  unsigned short* zr = z + (size_t)n * 128 + cb;
  *(us8*)zr = *(const us8*)&ob[0];
  *(us8*)(zr + 8) = *(const us8*)&ob[8];
}

// ---------------- GIN MLP: h = bn2(relu(bn1(z@w1+b1))@w2+b2) (+relu) --------
// R9: zs/z1s overlay in one 38144B buffer; per-mt barriers in Phase B.
//   z1s row r: bytes [r*528, r*528+528)     (stride 264 u16, 4-bank shift)
//   zs  row r: bytes [20736+r*272, ...+272) (stride 136 u16, 4-bank shift)
// Safety: after tile m, z1s top (m+1)*8448 <= 20736 + m*4352 (equality m=3),
// and the per-mt __syncthreads keeps all waves in the same tile.
__global__ __launch_bounds__(256) void gin_mlp2(
    const unsigned short* __restrict__ zin, unsigned short* __restrict__ hout,
    const unsigned short* __restrict__ w1t, const float* __restrict__ b1,
    const float* __restrict__ g1, const float* __restrict__ be1,
    const unsigned short* __restrict__ w2t, const float* __restrict__ b2,
    const float* __restrict__ g2, const float* __restrict__ be2,
    int N, int do_relu) {
  __shared__ __align__(16) unsigned char smem[38144];
  unsigned short* z1s = (unsigned short*)smem;              // u16 idx: r*264 + c
  unsigned short* zs  = (unsigned short*)(smem + 20736);    // u16 idx: r*136 + c
  int t = threadIdx.x;
  int r0 = blockIdx.x * 64;
  // Phase A: stage z tile (sequential us4 loads)
  for (int i = t; i < 2048; i += 256) {
    int r = i >> 5, c4 = (i & 31) << 2;
    int n = r0 + r;
    us4 v;
    if (n < N) v = *(const us4*)(zin + (size_t)n * 128 + c4);
    else { v.x = 0; v.y = 0; v.z = 0; v.w = 0; }
    *(us4*)(zs + r * 136 + c4) = v;
  }
  __syncthreads();
  int lane = t & 63, wave = t >> 6;
  int quad = lane >> 4, l16 = lane & 15;
  // Phase B: z1[64x256] = relu(bn1(z @ w1 + b1)); wave handles 64 cols.
  // Per-mt barrier so z1s writes stay behind zs reads (overlay contract).
  {
    short8 bw[4][4];
    int cb = wave * 64;
#pragma unroll
    for (int nt = 0; nt < 4; nt++) {
      const unsigned short* p = w1t + (cb + nt * 16 + l16) * 128 + quad * 8;
#pragma unroll
      for (int kc = 0; kc < 4; kc++) bw[nt][kc] = *(const short8*)(p + kc * 32);
    }
    for (int mt = 0; mt < 4; mt++) {
      short8 af[4];
      const unsigned short* zrow = zs + (mt * 16 + l16) * 136 + quad * 8;
#pragma unroll
      for (int kc = 0; kc < 4; kc++)
        af[kc] = *(const short8*)(zrow + kc * 32);
#pragma unroll
      for (int nt = 0; nt < 4; nt++) {
        f32x4 acc = {0.f, 0.f, 0.f, 0.f};
#pragma unroll
        for (int kc = 0; kc < 4; kc++)
          acc = __builtin_amdgcn_mfma_f32_16x16x32_bf16(af[kc], bw[nt][kc], acc, 0, 0, 0);
        int c = cb + nt * 16 + l16;
        float sc = g1[c] * BN_RSQ, sh = be1[c], bb = b1[c];
#pragma unroll
        for (int reg = 0; reg < 4; reg++) {
          int r = mt * 16 + quad * 4 + reg;
          float y = (acc[reg] + bb) * sc + sh;
          z1s[r * 264 + c] = f2bf(fmaxf(y, 0.f));
        }
      }
      __syncthreads();   // all waves finish tile mt before any writes tile mt+1
    }
  }
  // Phase C: h_out = bn2(z1 @ w2 + b2) (+relu); wave handles 32 cols
  {
    short8 bw[2][8];
    int cb = wave * 32;
#pragma unroll
    for (int nt = 0; nt < 2; nt++) {
      const unsigned short* p = w2t + (cb + nt * 16 + l16) * 256 + quad * 8;
#pragma unroll
      for (int kc = 0; kc < 8; kc++) bw[nt][kc] = *(const short8*)(p + kc * 32);
    }
#pragma unroll
    for (int mt = 0; mt < 4; mt++) {
      short8 af[8];
      const unsigned short* zrow = z1s + (mt * 16 + l16) * 264 + quad * 8;
#pragma unroll
      for (int kc = 0; kc < 8; kc++)
        af[kc] = *(const short8*)(zrow + kc * 32);
#pragma unroll
      for (int nt = 0; nt < 2; nt++) {
        f32x4 acc = {0.f, 0.f, 0.f, 0.f};
#pragma unroll
        for (int kc = 0; kc < 8; kc++)
          acc = __builtin_amdgcn_mfma_f32_16x16x32_bf16(af[kc], bw[nt][kc], acc, 0, 0, 0);
        int c = cb + nt * 16 + l16;
        float sc = g2[c] * BN_RSQ, sh = be2[c], bb = b2[c];
#pragma unroll
        for (int reg = 0; reg < 4; reg++) {
          int n = r0 + mt * 16 + quad * 4 + reg;
          if (n < N) {
            float y = (acc[reg] + bb) * sc + sh;
            if (do_relu) y = fmaxf(y, 0.f);
            hout[n * 128 + c] = f2bf(y);
          }
        }
      }
    }
  }
}

// ---------------- CSR mean pooling (bf16 h) ---------------------------------
__global__ __launch_bounds__(128) void pool_csr(const unsigned short* __restrict__ h,
                                                const int* __restrict__ npool,
                                                const int* __restrict__ rowptr_n,
                                                int segbase, float* __restrict__ pooled, int nseg) {
  int m = blockIdx.x;
  if (m >= nseg) return;
  int g = segbase + m;
  int st = rowptr_n[g];
  int e = rowptr_n[g + 1];
  int len = e - st;
  int c = threadIdx.x;
  float s = 0.f;
  int i = st;
  for (; i + 3 < e; i += 4) {
    int n0 = npool[i], n1 = npool[i + 1], n2 = npool[i + 2], n3 = npool[i + 3];
    float v0 = bf2f(h[(size_t)n0 * 128 + c]);
    float v1 = bf2f(h[(size_t)n1 * 128 + c]);
    float v2 = bf2f(h[(size_t)n2 * 128 + c]);
    float v3 = bf2f(h[(size_t)n3 * 128 + c]);
    s += (v0 + v1) + (v2 + v3);
  }
  for (; i < e; i++) s += bf2f(h[(size_t)npool[i] * 128 + c]);
  pooled[m * 128 + c] = s / ((float)len + 1e-9f);
}

// ---------------- row GEMM (N=128): C[r,:] = A[r,:] @ W + bias --------------
__global__ __launch_bounds__(256) void gemm_tile(const float* __restrict__ A, const float* __restrict__ W,
                                                 const float* __restrict__ bias, float* __restrict__ C,
                                                 int K) {
  __shared__ float As[608];
  __shared__ float red[128];
  int r = blockIdx.x;
  int t = threadIdx.x;
  for (int i = t; i < K; i += 256) As[i] = A[(size_t)r * K + i];
  __syncthreads();
  int c = t & 127, half = t >> 7;
  int Kh = K >> 1;
  int k0 = half * Kh, k1 = k0 + Kh;
  float acc = 0.f;
#pragma unroll 8
  for (int k = k0; k < k1; k++) acc = fmaf(As[k], W[(size_t)k * 128 + c], acc);
  if (half) red[c] = acc;
  __syncthreads();
  if (!half) {
    float v = acc + red[c] + (bias ? bias[c] : 0.f);
    C[(size_t)r * 128 + c] = v;
  }
}

// ---------------- fused QKV row GEMM (K=128), blockIdx.y picks W/bias/out ---
__global__ __launch_bounds__(256) void gemm_qkv(const float* __restrict__ A,
                                                const float* __restrict__ W0, const float* __restrict__ bi0, float* __restrict__ C0,
                                                const float* __restrict__ W1, const float* __restrict__ bi1, float* __restrict__ C1,
                                                const float* __restrict__ W2, const float* __restrict__ bi2, float* __restrict__ C2) {
  __shared__ float As[128];
  __shared__ float red[128];
  int r = blockIdx.x, which = blockIdx.y;
  const float* W = (which == 0) ? W0 : (which == 1) ? W1 : W2;
  const float* bias = (which == 0) ? bi0 : (which == 1) ? bi1 : bi2;
  float* C = (which == 0) ? C0 : (which == 1) ? C1 : C2;
  int t = threadIdx.x;
  if (t < 128) As[t] = A[(size_t)r * 128 + t];
  __syncthreads();
  int c = t & 127, half = t >> 7;
  int k0 = half * 64, k1 = k0 + 64;
  float acc = 0.f;
#pragma unroll 8
  for (int k = k0; k < k1; k++) acc = fmaf(As[k], W[(size_t)k * 128 + c], acc);
  if (half) red[c] = acc;
  __syncthreads();
  if (!half) C[(size_t)r * 128 + c] = acc + red[c] + bias[c];
}

// ---------------- SAB attention: O = Qs + softmax(QsKs^T/8) Vs -------------
__global__ __launch_bounds__(256) void sab_attn(const float* __restrict__ Q, const float* __restrict__ K,
                                                const float* __restrict__ V, float* __restrict__ O, int S) {
  int q = blockIdx.x, hd = blockIdx.y;
  int t = threadIdx.x;
  __shared__ float sc[512];
  __shared__ float red[8];
  __shared__ float pacc[4][64];
  const float* qrow = Q + q * 128 + hd * 64;
  for (int k = t; k < 512; k += 256) {
    float d = -1e30f;
    if (k < S) {
      const float* krow = K + k * 128 + hd * 64;
      d = 0.f;
#pragma unroll
      for (int j = 0; j < 64; j += 4) {
        float4 a = *(const float4*)(qrow + j);
        float4 b = *(const float4*)(krow + j);
        d += a.x * b.x + a.y * b.y + a.z * b.z + a.w * b.w;
      }
      d *= 0.125f;
    }
    sc[k] = d;
  }
  __syncthreads();
  float m = fmaxf(sc[t], sc[t + 256]);
  for (int off = 32; off; off >>= 1) m = fmaxf(m, __shfl_down(m, off));
  if ((t & 63) == 0) red[t >> 6] = m;
  __syncthreads();
  m = fmaxf(fmaxf(red[0], red[1]), fmaxf(red[2], red[3]));
  float p0 = __expf(sc[t] - m), p1 = __expf(sc[t + 256] - m);
  sc[t] = p0; sc[t + 256] = p1;
  float s = p0 + p1;
  for (int off = 32; off; off >>= 1) s += __shfl_down(s, off);
  if ((t & 63) == 0) red[4 + (t >> 6)] = s;
  __syncthreads();
  float inv = 1.f / (red[4] + red[5] + red[6] + red[7]);
  int d = t & 63, part = t >> 6;
  float acc = 0.f;
  for (int k = part; k < S; k += 4) acc += sc[k] * V[k * 128 + hd * 64 + d];
  pacc[part][d] = acc;
  __syncthreads();
  if (part == 0) {
    float o = (pacc[0][d] + pacc[1][d] + pacc[2][d] + pacc[3][d]) * inv;
    O[q * 128 + hd * 64 + d] = qrow[d] + o;
  }
}

// ---------------- row LayerNorm over 128 ------------------------------------
__global__ __launch_bounds__(128) void ln_rows(const float* __restrict__ in, float* __restrict__ out,
                                               const float* __restrict__ g, const float* __restrict__ b) {
  int r = blockIdx.x, t = threadIdx.x;
  __shared__ float red[4];
  float x = in[r * 128 + t];
  float s = x;
  for (int off = 32; off; off >>= 1) s += __shfl_down(s, off);
  if ((t & 63) == 0) red[t >> 6] = s;
  __syncthreads();
  float mu = (red[0] + red[1]) * (1.f / 128.f);
  float dd = x - mu;
  float v = dd * dd;
  for (int off = 32; off; off >>= 1) v += __shfl_down(v, off);
  if ((t & 63) == 0) red[2 + (t >> 6)] = v;
  __syncthreads();
  float var = (red[2] + red[3]) * (1.f / 128.f);
  out[r * 128 + t] = g[t] * dd * rsqrtf(var + LN_EPS) + b[t];
}

// ---------------- masked softmax attn: attn[d,s] ----------------------------
__global__ __launch_bounds__(256) void agg_attn(const float* __restrict__ Q, const float* __restrict__ Kt,
                                                const void* __restrict__ mask, const int* __restrict__ flags,
                                                float* __restrict__ attn, int D, int S) {
  int d = blockIdx.x, t = threadIdx.x;
  __shared__ float sc[512];
  __shared__ float red[8];
  int layout = (flags[1] == 0) ? 0 : (flags[0] ? 1 : 2);
  const float* qrow = Q + d * 128;
  for (int s = t; s < 512; s += 256) {
    float v = NEGBIG;
    if (s < S) {
      int mi = d * S + s;
      bool msk;
      if (layout == 0)      msk = ((const int*)mask)[mi] != 0;
      else if (layout == 1) msk = ((const unsigned char*)mask)[mi] != 0;
      else                  msk = ((const float*)mask)[mi] != 0.f;
      if (!msk) {
        float dd = 0.f;
        const float* krow = Kt + s * 128;
#pragma unroll
        for (int j = 0; j < 128; j += 4) {
          float4 a = *(const float4*)(qrow + j);
          float4 b = *(const float4*)(krow + j);
          dd += a.x * b.x + a.y * b.y + a.z * b.z + a.w * b.w;
        }
        v = dd * 0.08838834764831845f;
      }
    }
    sc[s] = v;
  }
  __syncthreads();
  float m = fmaxf(sc[t], sc[t + 256]);
  for (int off = 32; off; off >>= 1) m = fmaxf(m, __shfl_down(m, off));
  if ((t & 63) == 0) red[t >> 6] = m;
  __syncthreads();
  m = fmaxf(fmaxf(red[0], red[1]), fmaxf(red[2], red[3]));
  float p0 = __expf(sc[t] - m), p1 = __expf(sc[t + 256] - m);
  float s2 = p0 + p1;
  for (int off = 32; off; off >>= 1) s2 += __shfl_down(s2, off);
  if ((t & 63) == 0) red[4 + (t >> 6)] = s2;
  __syncthreads();
  float inv = 1.f / (red[4] + red[5] + red[6] + red[7]);
  attn[d * S + t] = p0 * inv;
  if (t + 256 < S) attn[d * S + t + 256] = p1 * inv;
}

// ---------------- subT prep: subf [S][128] f32 -> subT bf16 [128][512] ------
__global__ void prep_subT(const float* __restrict__ subf, unsigned short* __restrict__ subT, int S) {
  int i = blockIdx.x * 256 + threadIdx.x;
  if (i >= 128 * 512) return;
  int hh = i >> 9, k = i & 511;
  subT[i] = (k < S) ? f2bf(subf[k * 128 + hh]) : (unsigned short)0;
}

// ---------------- agg via MFMA: per d, (pat .* attn[d])[64x492] @ sub -------
__global__ __launch_bounds__(256) void agg_mfma(const float* __restrict__ attn, const float* __restrict__ pat,
                                                const unsigned short* __restrict__ subT,
                                                float* __restrict__ aggT, int D, int S) {
  int d = blockIdx.x, t = threadIdx.x;
  __shared__ unsigned short As[64][40];
  int lane = t & 63, wave = t >> 6;
  int quad = lane >> 4, l16 = lane & 15;
  f32x4 acc[8];
#pragma unroll
  for (int nt = 0; nt < 8; nt++) acc[nt] = (f32x4){0.f, 0.f, 0.f, 0.f};
  const float* arow = attn + d * S;
  int srow = t >> 2, skb = (t & 3) * 8;
  for (int c = 0; c < 16; c++) {
    int s0 = c * 32;
    __syncthreads();
    unsigned short v[8];
#pragma unroll
    for (int j = 0; j < 8; j++) {
      int s = s0 + skb + j;
      float x = (s < S) ? arow[s] * pat[srow * S + s] : 0.f;
      v[j] = f2bf(x);
    }
    *(us4*)&As[srow][skb]     = *(us4*)&v[0];
    *(us4*)&As[srow][skb + 4] = *(us4*)&v[4];
    __syncthreads();
    short8 af = *(const short8*)&As[16 * wave + l16][quad * 8];
#pragma unroll
    for (int nt = 0; nt < 8; nt++) {
      short8 bf = *(const short8*)(subT + (nt * 16 + l16) * 512 + s0 + quad * 8);
      acc[nt] = __builtin_amdgcn_mfma_f32_16x16x32_bf16(af, bf, acc[nt], 0, 0, 0);
    }
  }
#pragma unroll
  for (int nt = 0; nt < 8; nt++) {
    int hh = nt * 16 + l16;
#pragma unroll
    for (int reg = 0; reg < 4; reg++) {
      int b = 16 * wave + quad * 4 + reg;
      aggT[((size_t)(b * D + d)) * 128 + hh] = acc[nt][reg];
    }
  }
}

// ---------------- score head: sigmoid(relu(agg@w1+b1)@w2+b2), 4 rows/block --
__global__ __launch_bounds__(256) void score_head(const float* __restrict__ aggT,
                                                  const float* __restrict__ w1, const float* __restrict__ b1,
                                                  const float* __restrict__ w2, const float* __restrict__ b2,
                                                  float* __restrict__ out, int total) {
  int i = blockIdx.x * 4 + (threadIdx.x >> 6);   // one output per wave
  int j = threadIdx.x & 63;
  if (i >= total) return;
  const float* av = aggT + (size_t)i * 128;
  float acc = b1[j];
#pragma unroll 8
  for (int k = 0; k < 128; k++) acc = fmaf(av[k], w1[k * 64 + j], acc);
  acc = fmaxf(acc, 0.f) * w2[j];
  for (int off = 32; off; off >>= 1) acc += __shfl_down(acc, off);
  if (j == 0) {
    float x = acc + b2[0];
    out[i] = 1.f / (1.f + __expf(-x));
  }
}

// ---------------------------------------------------------------------------
extern "C" void kernel_launch(void* const* d_in, const int* in_sizes, int n_in,
                              void* d_out, int out_size, void* d_ws, size_t ws_size,
                              hipStream_t stream) {
  const float* atom_emb = (const float*)d_in[0];
  const float* bond_emb = (const float*)d_in[1];
  const float* gin_eps  = (const float*)d_in[2];
  const float* gin_w1   = (const float*)d_in[3];
  const float* gin_b1   = (const float*)d_in[4];
  const float* bn1g     = (const float*)d_in[5];
  const float* bn1b     = (const float*)d_in[6];
  const float* gin_w2   = (const float*)d_in[7];
  const float* gin_b2   = (const float*)d_in[8];
  const float* bn2g     = (const float*)d_in[9];
  const float* bn2b     = (const float*)d_in[10];
  const float* sab_wq = (const float*)d_in[11];
  const float* sab_wk = (const float*)d_in[12];
  const float* sab_wv = (const float*)d_in[13];
  const float* sab_wo = (const float*)d_in[14];
  const float* sab_bq = (const float*)d_in[15];
  const float* sab_bk = (const float*)d_in[16];
  const float* sab_bv = (const float*)d_in[17];
  const float* sab_bo = (const float*)d_in[18];
  const float* ln1b = (const float*)d_in[19];
  const float* ln2b = (const float*)d_in[20];
  const float* ln1g = (const float*)d_in[21];
  const float* ln2g = (const float*)d_in[22];
  const float* agg_wq = (const float*)d_in[23];
  const float* agg_bq = (const float*)d_in[24];
  const float* agg_wk = (const float*)d_in[25];
  const float* agg_bk = (const float*)d_in[26];
  const float* score_w1 = (const float*)d_in[27];
  const float* score_b1 = (const float*)d_in[28];
  const float* score_w2 = (const float*)d_in[29];
  const float* score_b2 = (const float*)d_in[30];
  const float* patient  = (const float*)d_in[31];
  const float* avgproj  = (const float*)d_in[32];
  const int* sub_x     = (const int*)d_in[33];
  const int* sub_ea    = (const int*)d_in[34];
  const int* sub_ei    = (const int*)d_in[35];
  const int* sub_batch = (const int*)d_in[36];
  const int* mol_x     = (const int*)d_in[37];
  const int* mol_ea    = (const int*)d_in[38];
  const int* mol_ei    = (const int*)d_in[39];
  const int* mol_batch = (const int*)d_in[40];
  const void* mask     = d_in[41];

  const int Ns = in_sizes[33] / 9, Es = in_sizes[34] / 3;
  const int Nm = in_sizes[37] / 9, Em = in_sizes[38] / 3;
  const int S = 492, M = 600, D = 200, B = 64;
  const int NE = Nm + Ns;           // edge-CSR index space (mol first)
  const int NSEG = M + S;           // node-CSR index space (mol first)
  const int ETOT = Em + Es;
  const int BONDE = 2 * 4 * 3 * 64 * 128;   // bond table elements

  // ---- workspace carve-up ----
  char* Wp = (char*)d_ws;
  size_t off = 0;
  auto alloc = [&](size_t bytes) -> void* {
    void* p = Wp + off;
    off = (off + bytes + 255) & ~(size_t)255;
    return p;
  };
  int NR = ((Nm > Ns ? Nm : Ns) + 63) & ~63;
  unsigned short* h0 = (unsigned short*)alloc((size_t)NR * 128 * 2);
  unsigned short* h1 = (unsigned short*)alloc((size_t)NR * 128 * 2);
  unsigned short* zb = (unsigned short*)alloc((size_t)NR * 128 * 2);
  unsigned short* w1t = (unsigned short*)alloc(262144 * 2);
  unsigned short* w2t = (unsigned short*)alloc(262144 * 2);
  unsigned short* bt16 = (unsigned short*)alloc((size_t)BONDE * 2);
  int4* epool  = (int4*)alloc((size_t)ETOT * 16);
  int*  npool  = (int*)alloc((size_t)NE * 4);
  int*  excl_e = (int*)alloc((size_t)NE * 4);
  int*  bsum_e = (int*)alloc(1024 * 4);
  int*  excl_n = (int*)alloc((size_t)NSEG * 4);
  int*  bsum_n = (int*)alloc(1024 * 4);
  int*  rowptr_e = (int*)alloc((size_t)(NE + 1) * 4);
  int*  rowptr_n = (int*)alloc((size_t)(NSEG + 1) * 4);
  char* zstart = Wp + off;                       // region zeroed below
  int*  deg_e  = (int*)alloc((size_t)NE * 4);
  int*  deg_n  = (int*)alloc((size_t)NSEG * 4);
  int*  cur_e  = (int*)alloc((size_t)NE * 4);
  int*  cur_n  = (int*)alloc((size_t)NSEG * 4);
  int*  flags  = (int*)alloc(8);
  size_t zsize = (size_t)((Wp + off) - zstart);
  float* pooled_sub = (float*)alloc((size_t)S * 128 * 4);
  float* pooled_mol = (float*)alloc((size_t)M * 128 * 4);
  float* Qb   = (float*)alloc((size_t)S * 128 * 4);
  float* Kb   = (float*)alloc((size_t)S * 128 * 4);
  float* Vb   = (float*)alloc((size_t)S * 128 * 4);
  float* Ob   = (float*)alloc((size_t)S * 128 * 4);
  float* O2b  = (float*)alloc((size_t)S * 128 * 4);
  float* subf = (float*)alloc((size_t)S * 128 * 4);
  unsigned short* subT = (unsigned short*)alloc((size_t)128 * 512 * 2);
  float* mol_embb = (float*)alloc((size_t)D * 128 * 4);
  float* aggQb = (float*)alloc((size_t)D * 128 * 4);
  float* aggKb = (float*)alloc((size_t)S * 128 * 4);
  float* attnb = (float*)alloc((size_t)D * S * 4);
  float* aggTb = (float*)alloc((size_t)B * D * 128 * 4);
  (void)ws_size; (void)n_in; (void)out_size;

  hipMemsetAsync(zstart, 0, zsize, stream);
  prep_weights<<<1024, 256, 0, stream>>>(gin_w1, gin_w2, w1t, w2t);
  prep_bond<<<(BONDE + 255) / 256, 256, 0, stream>>>(bond_emb, bt16, BONDE);
  mask_detect<<<64, 256, 0, stream>>>((const unsigned char*)mask, flags, D * S);

  // ---- CSR build (edges by tgt; nodes by batch) ----
  int total_cnt = Em + Es + Nm + Ns;
  build_count<<<(total_cnt + 255) / 256, 256, 0, stream>>>(
      mol_ei, Em, sub_ei, Es, mol_batch, Nm, sub_batch, Ns, deg_e, deg_n, M);
  int nb_e = (NE + 255) / 256;        // <= 1024
  int nb_n = (NSEG + 255) / 256;
  scan_block<<<nb_e, 256, 0, stream>>>(deg_e, NE, excl_e, bsum_e);
  scan_top<<<1, 1024, 0, stream>>>(bsum_e, nb_e);
  scan_block<<<nb_n, 256, 0, stream>>>(deg_n, NSEG, excl_n, bsum_n);
  scan_top<<<1, 1024, 0, stream>>>(bsum_n, nb_n);
  finalize_rowptr<<<(NE + 256) / 256 + 1, 256, 0, stream>>>(excl_e, bsum_e, NE, ETOT, rowptr_e);
  finalize_rowptr<<<(NSEG + 256) / 256 + 1, 256, 0, stream>>>(excl_n, bsum_n, NSEG, NE, rowptr_n);
  scatter_edges<<<(ETOT + 255) / 256, 256, 0, stream>>>(
      mol_ei, mol_ea, Em, sub_ei, sub_ea, Es, Nm, rowptr_e, cur_e, epool);
  scatter_nodes<<<(NE + 255) / 256, 256, 0, stream>>>(
      mol_batch, Nm, sub_batch, Ns, M, rowptr_n, cur_n, npool);

  auto run_gin = [&](int g, int N, const int* x, int nodebase, int segbase,
                     float* pooled, int nseg) {
    embed_nodes<<<(N * 128 + 255) / 256, 256, 0, stream>>>(
        x, atom_emb + (size_t)g * 9 * 64 * 128, h0, N);
    unsigned short* hin = h0; unsigned short* hout = h1;
    for (int l = 0; l < 4; l++) {
      int gl = g * 4 + l;
      gather_z<<<(N * 8 + 255) / 256, 256, 0, stream>>>(
          hin, zb, gin_eps + gl, bt16 + (size_t)gl * 3 * 64 * 128,
          epool, rowptr_e, nodebase, N);
      gin_mlp2<<<(N + 63) / 64, 256, 0, stream>>>(
          zb, hout,
          w1t + (size_t)gl * 32768, gin_b1 + gl * 256, bn1g + gl * 256, bn1b + gl * 256,
          w2t + (size_t)gl * 32768, gin_b2 + gl * 128, bn2g + gl * 128, bn2b + gl * 128,
          N, (l != 3) ? 1 : 0);
      unsigned short* tmp = hin; hin = hout; hout = tmp;
    }
    pool_csr<<<nseg, 128, 0, stream>>>(hin, npool, rowptr_n, segbase, pooled, nseg);
  };

  // --- substructure encoder + SAB ---
  run_gin(0, Ns, sub_x, Nm, M, pooled_sub, S);
  gemm_qkv<<<dim3(S, 3), 256, 0, stream>>>(pooled_sub,
                                           sab_wq, sab_bq, Qb,
                                           sab_wk, sab_bk, Kb,
                                           sab_wv, sab_bv, Vb);
  sab_attn<<<dim3(S, 2), 256, 0, stream>>>(Qb, Kb, Vb, Ob, S);
  ln_rows<<<S, 128, 0, stream>>>(Ob, Ob, ln1g, ln1b);
  gemm_tile<<<S, 256, 0, stream>>>(Ob, sab_wo, sab_bo, O2b, 128);
  ln_rows<<<S, 128, 0, stream>>>(O2b, subf, ln2g, ln2b);
  prep_subT<<<(128 * 512 + 255) / 256, 256, 0, stream>>>(subf, subT, S);

  // --- molecule encoder + projection ---
  run_gin(1, Nm, mol_x, 0, 0, pooled_mol, M);
  gemm_tile<<<D, 256, 0, stream>>>(avgproj, pooled_mol, (const float*)nullptr, mol_embb, 600);

  // --- attention aggregation + score ---
  gemm_tile<<<D, 256, 0, stream>>>(mol_embb, agg_wq, agg_bq, aggQb, 128);
  gemm_tile<<<S, 256, 0, stream>>>(subf, agg_wk, agg_bk, aggKb, 128);
  agg_attn<<<D, 256, 0, stream>>>(aggQb, aggKb, mask, flags, attnb, D, S);
  agg_mfma<<<D, 256, 0, stream>>>(attnb, patient, subT, aggTb, D, S);
  score_head<<<(B * D + 3) / 4, 256, 0, stream>>>(aggTb, score_w1, score_b1, score_w2, score_b2,
                                                  (float*)d_out, B * D);
}

// Round 11
// 1117.788 us; speedup vs baseline: 2.5829x; 1.0702x over previous
//
#include <hip/hip_runtime.h>

// ---------------------------------------------------------------------------
// MoleRec pipeline on gfx950.
// R10: (1) gather_z fused into the MLP kernel (gin_fused3): node-parallel
//      register gather (R6's proven shape, 8 thr/node x 16ch, no atomics)
//      writes bf16 straight into the zs LDS overlay -> z global round-trip
//      (77MB/mol-layer) eliminated. (2) sub+mol merged into one padded node
//      space (mol [0,NmR), sub [NmR,NTOT), both 64-aligned) -> 4 GIN
//      launches total, one pooling launch, bigger grids.
// ---------------------------------------------------------------------------

typedef short short8 __attribute__((ext_vector_type(8)));
typedef unsigned short us8 __attribute__((ext_vector_type(8)));
typedef float f32x4 __attribute__((ext_vector_type(4)));
typedef unsigned short us4 __attribute__((ext_vector_type(4)));

#define BN_RSQ 0.9999950000374997f   // 1/sqrt(1+1e-5)  (BatchNorm eval, var=1)
#define LN_EPS 1e-5f
#define NEGBIG -4294967296.0f        // -(1<<32), matches reference mask fill

__device__ __forceinline__ unsigned short f2bf(float x) {
  union { float f; unsigned int u; } v; v.f = x;
  unsigned int r = v.u + 0x7fffu + ((v.u >> 16) & 1u);   // RNE
  return (unsigned short)(r >> 16);
}
__device__ __forceinline__ float bf2f(unsigned short x) {
  union { unsigned int u; float f; } v; v.u = ((unsigned int)x) << 16;
  return v.f;
}

// ---------------- weight prep: fp32 [K][N] -> bf16 [N][K] ------------------
__global__ void prep_weights(const float* __restrict__ w1, const float* __restrict__ w2,
                             unsigned short* __restrict__ w1t, unsigned short* __restrict__ w2t) {
  int i = blockIdx.x * 256 + threadIdx.x;
  if (i >= 262144) return;
  int gl = i >> 15;
  int k1 = (i >> 8) & 127, c1 = i & 255;
  w1t[(gl << 15) + c1 * 128 + k1] = f2bf(w1[i]);
  int k2 = (i >> 7) & 255, c2 = i & 127;
  w2t[(gl << 15) + c2 * 256 + k2] = f2bf(w2[i]);
}

// ---------------- bond tables fp32 -> bf16 (same layout) --------------------
__global__ void prep_bond(const float* __restrict__ in, unsigned short* __restrict__ out, int n) {
  int i = blockIdx.x * 256 + threadIdx.x;
  if (i < n) out[i] = f2bf(in[i]);
}

// ---------------- mask layout detection (block-reduced) ---------------------
__global__ __launch_bounds__(256) void mask_detect(const unsigned char* __restrict__ m,
                                                   int* __restrict__ flags, int nbytes) {
  __shared__ int lf[2];
  if (threadIdx.x == 0) { lf[0] = 0; lf[1] = 0; }
  __syncthreads();
  int f0 = 0, f1 = 0;
  for (int i = blockIdx.x * 256 + threadIdx.x; i < nbytes; i += gridDim.x * 256) {
    if (m[i]) { if ((i & 3) == 0) f0 = 1; else f1 = 1; }
  }
  if (f0) atomicOr(&lf[0], 1);
  if (f1) atomicOr(&lf[1], 1);
  __syncthreads();
  if (threadIdx.x == 0) {
    if (lf[0]) atomicOr(flags, 1);
    if (lf[1]) atomicOr(flags + 1, 1);
  }
}

// ---------------- CSR build: count (padded merged node space) ---------------
// mol tgt -> deg_e[tgt]; sub tgt -> deg_e[NmR + tgt]
__global__ void build_count(const int* __restrict__ ei_m, int Em,
                            const int* __restrict__ ei_s, int Es,
                            const int* __restrict__ bm, int Nm,
                            const int* __restrict__ bs, int Ns,
                            int* __restrict__ deg_e, int* __restrict__ deg_n,
                            int M, int NmR) {
  int i = blockIdx.x * 256 + threadIdx.x;
  if (i < Em) { atomicAdd(&deg_e[ei_m[i]], 1); return; }
  i -= Em;
  if (i < Es) { atomicAdd(&deg_e[NmR + ei_s[i]], 1); return; }
  i -= Es;
  if (i < Nm) { atomicAdd(&deg_n[bm[i]], 1); return; }
  i -= Nm;
  if (i < Ns) { atomicAdd(&deg_n[M + bs[i]], 1); }
}

// ---------------- CSR build: block-level exclusive scan ---------------------
__global__ __launch_bounds__(256) void scan_block(const int* __restrict__ cnt, int n,
                                                  int* __restrict__ excl, int* __restrict__ bsum) {
  int gid = blockIdx.x * 256 + threadIdx.x;
  int lane = threadIdx.x & 63, w = threadIdx.x >> 6;
  int v = (gid < n) ? cnt[gid] : 0;
  int x = v;
#pragma unroll
  for (int off = 1; off < 64; off <<= 1) {
    int y = __shfl_up(x, off, 64);
    if (lane >= off) x += y;
  }
  __shared__ int wt[4];
  if (lane == 63) wt[w] = x;
  __syncthreads();
  int add = 0;
  for (int i = 0; i < w; i++) add += wt[i];
  x += add;
  if (gid < n) excl[gid] = x - v;
  if (threadIdx.x == 255) bsum[blockIdx.x] = x;
}

__global__ __launch_bounds__(1024) void scan_top(int* __restrict__ bsum, int n) {
  int t = threadIdx.x;
  int lane = t & 63, w = t >> 6;
  int v = (t < n) ? bsum[t] : 0;
  int x = v;
#pragma unroll
  for (int off = 1; off < 64; off <<= 1) {
    int y = __shfl_up(x, off, 64);
    if (lane >= off) x += y;
  }
  __shared__ int wt[16];
  if (lane == 63) wt[w] = x;
  __syncthreads();
  int add = 0;
  for (int i = 0; i < w; i++) add += wt[i];
  x += add;
  if (t < n) bsum[t] = x - v;
}

// ---------------- rowptr finalize: rowptr[i] = excl[i]+bsum[i>>8] -----------
__global__ void finalize_rowptr(const int* __restrict__ excl, const int* __restrict__ bsum,
                                int n, int total, int* __restrict__ rowptr) {
  int i = blockIdx.x * 256 + threadIdx.x;
  if (i < n) rowptr[i] = excl[i] + bsum[i >> 8];
  if (i == n) rowptr[n] = total;
}

// ---------------- CSR build: scatter ----------------------------------------
// epool rec: x=src_merged*128, y=unused, z=p0|(p1<<16), w=p2
__global__ void scatter_edges(const int* __restrict__ ei_m, const int* __restrict__ ea_m, int Em,
                              const int* __restrict__ ei_s, const int* __restrict__ ea_s, int Es, int NmR,
                              const int* __restrict__ rowptr_e,
                              int* __restrict__ cur_e, int4* __restrict__ epool) {
  int i = blockIdx.x * 256 + threadIdx.x;
  int g, src, a0, a1, a2;
  if (i < Em) {
    g = ei_m[i]; src = ei_m[Em + i];
    a0 = ea_m[i * 3]; a1 = ea_m[i * 3 + 1]; a2 = ea_m[i * 3 + 2];
  } else {
    int j = i - Em; if (j >= Es) return;
    g = NmR + ei_s[j]; src = NmR + ei_s[Es + j];
    a0 = ea_s[j * 3]; a1 = ea_s[j * 3 + 1]; a2 = ea_s[j * 3 + 2];
  }
  int slot = rowptr_e[g] + atomicAdd(&cur_e[g], 1);
  int p0 = a0 * 128, p1 = (64 + a1) * 128, p2 = (128 + a2) * 128;
  epool[slot] = make_int4(src * 128, 0, p0 | (p1 << 16), p2);
}

__global__ void scatter_nodes(const int* __restrict__ bm, int Nm,
                              const int* __restrict__ bs, int Ns, int M, int NmR,
                              const int* __restrict__ rowptr_n,
                              int* __restrict__ cur_n, int* __restrict__ npool) {
  int i = blockIdx.x * 256 + threadIdx.x;
  int g, node;
  if (i < Nm) { g = bm[i]; node = i; }
  else { int j = i - Nm; if (j >= Ns) return; g = M + bs[j]; node = NmR + j; }
  int slot = rowptr_n[g] + atomicAdd(&cur_n[g], 1);
  npool[slot] = node;
}

// ---------------- node embedding (bf16 out) ---------------------------------
__global__ void embed_nodes(const int* __restrict__ x, const float* __restrict__ table,
                            unsigned short* __restrict__ h, int N) {
  int i = blockIdx.x * 256 + threadIdx.x;
  if (i >= N * 128) return;
  int n = i >> 7, c = i & 127;
  float s = 0.f;
#pragma unroll
  for (int f = 0; f < 9; f++) {
    int v = x[n * 9 + f];
    s += table[(f * 64 + v) * 128 + c];
  }
  h[i] = f2bf(s);
}

// ---------------- fused GIN layer (R10) -------------------------------------
// Phase A: node-parallel gather (8 thr/node x 16ch, register acc, no atomics)
//          -> zs LDS overlay. Two 32-node passes per 64-row tile.
// Phase B/C: R9's MFMA MLP with zs/z1s overlay (per-mt barriers in B).
// Tile graph-homogeneous: r0 < NmR -> mol (g=1) else sub (g=0).
__global__ __launch_bounds__(256, 4) void gin_fused3(
    const unsigned short* __restrict__ hin, unsigned short* __restrict__ hout,
    const float* __restrict__ eps_all, int l, int NmR,
    const unsigned short* __restrict__ bt16,
    const int4* __restrict__ epool, const int* __restrict__ rowptr_e,
    const unsigned short* __restrict__ w1t_a, const float* __restrict__ b1_a,
    const float* __restrict__ g1_a, const float* __restrict__ be1_a,
    const unsigned short* __restrict__ w2t_a, const float* __restrict__ b2_a,
    const float* __restrict__ g2_a, const float* __restrict__ be2_a) {
  __shared__ __align__(16) unsigned char smem[38144];
  unsigned short* z1s = (unsigned short*)smem;              // u16 idx: r*264 + c
  unsigned short* zs  = (unsigned short*)(smem + 20736);    // u16 idx: r*136 + c
  int t = threadIdx.x;
  int r0 = blockIdx.x * 64;
  int g = (r0 < NmR) ? 1 : 0;
  int gl = g * 4 + l;
  const unsigned short* bt = bt16 + (size_t)gl * 3 * 64 * 128;
  const unsigned short* w1t = w1t_a + (size_t)gl * 32768;
  const unsigned short* w2t = w2t_a + (size_t)gl * 32768;
  const float* b1 = b1_a + gl * 256;
  const float* g1 = g1_a + gl * 256;
  const float* be1 = be1_a + gl * 256;
  const float* b2 = b2_a + gl * 128;
  const float* g2 = g2_a + gl * 128;
  const float* be2 = be2_a + gl * 128;
  float eps1 = 1.0f + eps_all[gl];
  int do_relu = (l != 3);

  // Phase A: gather into zs
#pragma unroll
  for (int p = 0; p < 2; p++) {
    int lr = p * 32 + (t >> 3);
    int n = r0 + lr;
    int cb = (t & 7) * 16;
    float acc[16];
    {
      const unsigned short* hr = hin + (size_t)n * 128 + cb;
      us8 v0 = *(const us8*)hr, v1 = *(const us8*)(hr + 8);
#pragma unroll
      for (int k = 0; k < 8; k++) {
        acc[k]     = eps1 * bf2f(v0[k]);
        acc[8 + k] = eps1 * bf2f(v1[k]);
      }
    }
    int e0 = rowptr_e[n], e1 = rowptr_e[n + 1];
    for (int e = e0; e < e1; e++) {
      int4 rec = epool[e];
      const unsigned short* hs = hin + rec.x + cb;
      const unsigned short* q0 = bt + (rec.z & 0xffff) + cb;
      const unsigned short* q1 = bt + (((unsigned)rec.z) >> 16) + cb;
      const unsigned short* q2 = bt + rec.w + cb;
      us8 a0 = *(const us8*)hs, a1 = *(const us8*)(hs + 8);
      us8 b0 = *(const us8*)q0, b1v = *(const us8*)(q0 + 8);
      us8 c0 = *(const us8*)q1, c1 = *(const us8*)(q1 + 8);
      us8 d0 = *(const us8*)q2, d1 = *(const us8*)(q2 + 8);
#pragma unroll
      for (int k = 0; k < 8; k++) {
        acc[k]     += fmaxf(bf2f(a0[k]) + bf2f(b0[k]) + bf2f(c0[k]) + bf2f(d0[k]), 0.f);
        acc[8 + k] += fmaxf(bf2f(a1[k]) + bf2f(b1v[k]) + bf2f(c1[k]) + bf2f(d1[k]), 0.f);
      }
    }
    unsigned short ob[16];
#pragma unroll
    for (int k = 0; k < 16; k++) ob[k] = f2bf(acc[k]);
    unsigned short* zr = zs + lr * 136 + cb;
    *(us8*)zr = *(const us8*)&ob[0];
    *(us8*)(zr + 8) = *(const us8*)&ob[8];
  }
  __syncthreads();

  int lane = t & 63, wave = t >> 6;
  int quad = lane >> 4, l16 = lane & 15;
  // Phase B: z1[64x256] = relu(bn1(z @ w1 + b1)); per-mt barrier (overlay)
  {
    short8 bw[4][4];
    int cb = wave * 64;
#pragma unroll
    for (int nt = 0; nt < 4; nt++) {
      const unsigned short* p = w1t + (cb + nt * 16 + l16) * 128 + quad * 8;
#pragma unroll
      for (int kc = 0; kc < 4; kc++) bw[nt][kc] = *(const short8*)(p + kc * 32);
    }
    for (int mt = 0; mt < 4; mt++) {
      short8 af[4];
      const unsigned short* zrow = zs + (mt * 16 + l16) * 136 + quad * 8;
#pragma unroll
      for (int kc = 0; kc < 4; kc++)
        af[kc] = *(const short8*)(zrow + kc * 32);
#pragma unroll
      for (int nt = 0; nt < 4; nt++) {
        f32x4 acc = {0.f, 0.f, 0.f, 0.f};
#pragma unroll
        for (int kc = 0; kc < 4; kc++)
          acc = __builtin_amdgcn_mfma_f32_16x16x32_bf16(af[kc], bw[nt][kc], acc, 0, 0, 0);
        int c = cb + nt * 16 + l16;
        float sc = g1[c] * BN_RSQ, sh = be1[c], bb = b1[c];
#pragma unroll
        for (int reg = 0; reg < 4; reg++) {
          int r = mt * 16 + quad * 4 + reg;
          float y = (acc[reg] + bb) * sc + sh;
          z1s[r * 264 + c] = f2bf(fmaxf(y, 0.f));
        }
      }
      __syncthreads();
    }
  }
  // Phase C: h_out = bn2(z1 @ w2 + b2) (+relu)
  {
    short8 bw[2][8];
    int cb = wave * 32;
#pragma unroll
    for (int nt = 0; nt < 2; nt++) {
      const unsigned short* p = w2t + (cb + nt * 16 + l16) * 256 + quad * 8;
#pragma unroll
      for (int kc = 0; kc < 8; kc++) bw[nt][kc] = *(const short8*)(p + kc * 32);
    }
#pragma unroll
    for (int mt = 0; mt < 4; mt++) {
      short8 af[8];
      const unsigned short* zrow = z1s + (mt * 16 + l16) * 264 + quad * 8;
#pragma unroll
      for (int kc = 0; kc < 8; kc++)
        af[kc] = *(const short8*)(zrow + kc * 32);
#pragma unroll
      for (int nt = 0; nt < 2; nt++) {
        f32x4 acc = {0.f, 0.f, 0.f, 0.f};
#pragma unroll
        for (int kc = 0; kc < 8; kc++)
          acc = __builtin_amdgcn_mfma_f32_16x16x32_bf16(af[kc], bw[nt][kc], acc, 0, 0, 0);
        int c = cb + nt * 16 + l16;
        float sc = g2[c] * BN_RSQ, sh = be2[c], bb = b2[c];
#pragma unroll
        for (int reg = 0; reg < 4; reg++) {
          int n = r0 + mt * 16 + quad * 4 + reg;
          float y = (acc[reg] + bb) * sc + sh;
          if (do_relu) y = fmaxf(y, 0.f);
          hout[(size_t)n * 128 + c] = f2bf(y);
        }
      }
    }
  }
}

// ---------------- CSR mean pooling (bf16 h, merged node ids) ----------------
__global__ __launch_bounds__(128) void pool_csr(const unsigned short* __restrict__ h,
                                                const int* __restrict__ npool,
                                                const int* __restrict__ rowptr_n,
                                                float* __restrict__ pooled, int nseg) {
  int m = blockIdx.x;
  if (m >= nseg) return;
  int st = rowptr_n[m];
  int e = rowptr_n[m + 1];
  int len = e - st;
  int c = threadIdx.x;
  float s = 0.f;
  int i = st;
  for (; i + 3 < e; i += 4) {
    int n0 = npool[i], n1 = npool[i + 1], n2 = npool[i + 2], n3 = npool[i + 3];
    float v0 = bf2f(h[(size_t)n0 * 128 + c]);
    float v1 = bf2f(h[(size_t)n1 * 128 + c]);
    float v2 = bf2f(h[(size_t)n2 * 128 + c]);
    float v3 = bf2f(h[(size_t)n3 * 128 + c]);
    s += (v0 + v1) + (v2 + v3);
  }
  for (; i < e; i++) s += bf2f(h[(size_t)npool[i] * 128 + c]);
  pooled[m * 128 + c] = s / ((float)len + 1e-9f);
}

// ---------------- row GEMM (N=128): C[r,:] = A[r,:] @ W + bias --------------
__global__ __launch_bounds__(256) void gemm_tile(const float* __restrict__ A, const float* __restrict__ W,
                                                 const float* __restrict__ bias, float* __restrict__ C,
                                                 int K) {
  __shared__ float As[608];
  __shared__ float red[128];
  int r = blockIdx.x;
  int t = threadIdx.x;
  for (int i = t; i < K; i += 256) As[i] = A[(size_t)r * K + i];
  __syncthreads();
  int c = t & 127, half = t >> 7;
  int Kh = K >> 1;
  int k0 = half * Kh, k1 = k0 + Kh;
  float acc = 0.f;
#pragma unroll 8
  for (int k = k0; k < k1; k++) acc = fmaf(As[k], W[(size_t)k * 128 + c], acc);
  if (half) red[c] = acc;
  __syncthreads();
  if (!half) {
    float v = acc + red[c] + (bias ? bias[c] : 0.f);
    C[(size_t)r * 128 + c] = v;
  }
}

// ---------------- fused QKV row GEMM (K=128), blockIdx.y picks W/bias/out ---
__global__ __launch_bounds__(256) void gemm_qkv(const float* __restrict__ A,
                                                const float* __restrict__ W0, const float* __restrict__ bi0, float* __restrict__ C0,
                                                const float* __restrict__ W1, const float* __restrict__ bi1, float* __restrict__ C1,
                                                const float* __restrict__ W2, const float* __restrict__ bi2, float* __restrict__ C2) {
  __shared__ float As[128];
  __shared__ float red[128];
  int r = blockIdx.x, which = blockIdx.y;
  const float* W = (which == 0) ? W0 : (which == 1) ? W1 : W2;
  const float* bias = (which == 0) ? bi0 : (which == 1) ? bi1 : bi2;
  float* C = (which == 0) ? C0 : (which == 1) ? C1 : C2;
  int t = threadIdx.x;
  if (t < 128) As[t] = A[(size_t)r * 128 + t];
  __syncthreads();
  int c = t & 127, half = t >> 7;
  int k0 = half * 64, k1 = k0 + 64;
  float acc = 0.f;
#pragma unroll 8
  for (int k = k0; k < k1; k++) acc = fmaf(As[k], W[(size_t)k * 128 + c], acc);
  if (half) red[c] = acc;
  __syncthreads();
  if (!half) C[(size_t)r * 128 + c] = acc + red[c] + bias[c];
}

// ---------------- SAB attention: O = Qs + softmax(QsKs^T/8) Vs -------------
__global__ __launch_bounds__(256) void sab_attn(const float* __restrict__ Q, const float* __restrict__ K,
                                                const float* __restrict__ V, float* __restrict__ O, int S) {
  int q = blockIdx.x, hd = blockIdx.y;
  int t = threadIdx.x;
  __shared__ float sc[512];
  __shared__ float red[8];
  __shared__ float pacc[4][64];
  const float* qrow = Q + q * 128 + hd * 64;
  for (int k = t; k < 512; k += 256) {
    float d = -1e30f;
    if (k < S) {
      const float* krow = K + k * 128 + hd * 64;
      d = 0.f;
#pragma unroll
      for (int j = 0; j < 64; j += 4) {
        float4 a = *(const float4*)(qrow + j);
        float4 b = *(const float4*)(krow + j);
        d += a.x * b.x + a.y * b.y + a.z * b.z + a.w * b.w;
      }
      d *= 0.125f;
    }
    sc[k] = d;
  }
  __syncthreads();
  float m = fmaxf(sc[t], sc[t + 256]);
  for (int off = 32; off; off >>= 1) m = fmaxf(m, __shfl_down(m, off));
  if ((t & 63) == 0) red[t >> 6] = m;
  __syncthreads();
  m = fmaxf(fmaxf(red[0], red[1]), fmaxf(red[2], red[3]));
  float p0 = __expf(sc[t] - m), p1 = __expf(sc[t + 256] - m);
  sc[t] = p0; sc[t + 256] = p1;
  float s = p0 + p1;
  for (int off = 32; off; off >>= 1) s += __shfl_down(s, off);
  if ((t & 63) == 0) red[4 + (t >> 6)] = s;
  __syncthreads();
  float inv = 1.f / (red[4] + red[5] + red[6] + red[7]);
  int d = t & 63, part = t >> 6;
  float acc = 0.f;
  for (int k = part; k < S; k += 4) acc += sc[k] * V[k * 128 + hd * 64 + d];
  pacc[part][d] = acc;
  __syncthreads();
  if (part == 0) {
    float o = (pacc[0][d] + pacc[1][d] + pacc[2][d] + pacc[3][d]) * inv;
    O[q * 128 + hd * 64 + d] = qrow[d] + o;
  }
}

// ---------------- row LayerNorm over 128 ------------------------------------
__global__ __launch_bounds__(128) void ln_rows(const float* __restrict__ in, float* __restrict__ out,
                                               const float* __restrict__ g, const float* __restrict__ b) {
  int r = blockIdx.x, t = threadIdx.x;
  __shared__ float red[4];
  float x = in[r * 128 + t];
  float s = x;
  for (int off = 32; off; off >>= 1) s += __shfl_down(s, off);
  if ((t & 63) == 0) red[t >> 6] = s;
  __syncthreads();
  float mu = (red[0] + red[1]) * (1.f / 128.f);
  float dd = x - mu;
  float v = dd * dd;
  for (int off = 32; off; off >>= 1) v += __shfl_down(v, off);
  if ((t & 63) == 0) red[2 + (t >> 6)] = v;
  __syncthreads();
  float var = (red[2] + red[3]) * (1.f / 128.f);
  out[r * 128 + t] = g[t] * dd * rsqrtf(var + LN_EPS) + b[t];
}

// ---------------- masked softmax attn: attn[d,s] ----------------------------
__global__ __launch_bounds__(256) void agg_attn(const float* __restrict__ Q, const float* __restrict__ Kt,
                                                const void* __restrict__ mask, const int* __restrict__ flags,
                                                float* __restrict__ attn, int D, int S) {
  int d = blockIdx.x, t = threadIdx.x;
  __shared__ float sc[512];
  __shared__ float red[8];
  int layout = (flags[1] == 0) ? 0 : (flags[0] ? 1 : 2);
  const float* qrow = Q + d * 128;
  for (int s = t; s < 512; s += 256) {
    float v = NEGBIG;
    if (s < S) {
      int mi = d * S + s;
      bool msk;
      if (layout == 0)      msk = ((const int*)mask)[mi] != 0;
      else if (layout == 1) msk = ((const unsigned char*)mask)[mi] != 0;
      else                  msk = ((const float*)mask)[mi] != 0.f;
      if (!msk) {
        float dd = 0.f;
        const float* krow = Kt + s * 128;
#pragma unroll
        for (int j = 0; j < 128; j += 4) {
          float4 a = *(const float4*)(qrow + j);
          float4 b = *(const float4*)(krow + j);
          dd += a.x * b.x + a.y * b.y + a.z * b.z + a.w * b.w;
        }
        v = dd * 0.08838834764831845f;
      }
    }
    sc[s] = v;
  }
  __syncthreads();
  float m = fmaxf(sc[t], sc[t + 256]);
  for (int off = 32; off; off >>= 1) m = fmaxf(m, __shfl_down(m, off));
  if ((t & 63) == 0) red[t >> 6] = m;
  __syncthreads();
  m = fmaxf(fmaxf(red[0], red[1]), fmaxf(red[2], red[3]));
  float p0 = __expf(sc[t] - m), p1 = __expf(sc[t + 256] - m);
  float s2 = p0 + p1;
  for (int off = 32; off; off >>= 1) s2 += __shfl_down(s2, off);
  if ((t & 63) == 0) red[4 + (t >> 6)] = s2;
  __syncthreads();
  float inv = 1.f / (red[4] + red[5] + red[6] + red[7]);
  attn[d * S + t] = p0 * inv;
  if (t + 256 < S) attn[d * S + t + 256] = p1 * inv;
}

// ---------------- subT prep: subf [S][128] f32 -> subT bf16 [128][512] ------
__global__ void prep_subT(const float* __restrict__ subf, unsigned short* __restrict__ subT, int S) {
  int i = blockIdx.x * 256 + threadIdx.x;
  if (i >= 128 * 512) return;
  int hh = i >> 9, k = i & 511;
  subT[i] = (k < S) ? f2bf(subf[k * 128 + hh]) : (unsigned short)0;
}

// ---------------- agg via MFMA: per d, (pat .* attn[d])[64x492] @ sub -------
__global__ __launch_bounds__(256) void agg_mfma(const float* __restrict__ attn, const float* __restrict__ pat,
                                                const unsigned short* __restrict__ subT,
                                                float* __restrict__ aggT, int D, int S) {
  int d = blockIdx.x, t = threadIdx.x;
  __shared__ unsigned short As[64][40];
  int lane = t & 63, wave = t >> 6;
  int quad = lane >> 4, l16 = lane & 15;
  f32x4 acc[8];
#pragma unroll
  for (int nt = 0; nt < 8; nt++) acc[nt] = (f32x4){0.f, 0.f, 0.f, 0.f};
  const float* arow = attn + d * S;
  int srow = t >> 2, skb = (t & 3) * 8;
  for (int c = 0; c < 16; c++) {
    int s0 = c * 32;
    __syncthreads();
    unsigned short v[8];
#pragma unroll
    for (int j = 0; j < 8; j++) {
      int s = s0 + skb + j;
      float x = (s < S) ? arow[s] * pat[srow * S + s] : 0.f;
      v[j] = f2bf(x);
    }
    *(us4*)&As[srow][skb]     = *(us4*)&v[0];
    *(us4*)&As[srow][skb + 4] = *(us4*)&v[4];
    __syncthreads();
    short8 af = *(const short8*)&As[16 * wave + l16][quad * 8];
#pragma unroll
    for (int nt = 0; nt < 8; nt++) {
      short8 bf = *(const short8*)(subT + (nt * 16 + l16) * 512 + s0 + quad * 8);
      acc[nt] = __builtin_amdgcn_mfma_f32_16x16x32_bf16(af, bf, acc[nt], 0, 0, 0);
    }
  }
#pragma unroll
  for (int nt = 0; nt < 8; nt++) {
    int hh = nt * 16 + l16;
#pragma unroll
    for (int reg = 0; reg < 4; reg++) {
      int b = 16 * wave + quad * 4 + reg;
      aggT[((size_t)(b * D + d)) * 128 + hh] = acc[nt][reg];
    }
  }
}

// ---------------- score head: sigmoid(relu(agg@w1+b1)@w2+b2), 4 rows/block --
__global__ __launch_bounds__(256) void score_head(const float* __restrict__ aggT,
                                                  const float* __restrict__ w1, const float* __restrict__ b1,
                                                  const float* __restrict__ w2, const float* __restrict__ b2,
                                                  float* __restrict__ out, int total) {
  int i = blockIdx.x * 4 + (threadIdx.x >> 6);   // one output per wave
  int j = threadIdx.x & 63;
  if (i >= total) return;
  const float* av = aggT + (size_t)i * 128;
  float acc = b1[j];
#pragma unroll 8
  for (int k = 0; k < 128; k++) acc = fmaf(av[k], w1[k * 64 + j], acc);
  acc = fmaxf(acc, 0.f) * w2[j];
  for (int off = 32; off; off >>= 1) acc += __shfl_down(acc, off);
  if (j == 0) {
    float x = acc + b2[0];
    out[i] = 1.f / (1.f + __expf(-x));
  }
}

// ---------------------------------------------------------------------------
extern "C" void kernel_launch(void* const* d_in, const int* in_sizes, int n_in,
                              void* d_out, int out_size, void* d_ws, size_t ws_size,
                              hipStream_t stream) {
  const float* atom_emb = (const float*)d_in[0];
  const float* bond_emb = (const float*)d_in[1];
  const float* gin_eps  = (const float*)d_in[2];
  const float* gin_w1   = (const float*)d_in[3];
  const float* gin_b1   = (const float*)d_in[4];
  const float* bn1g     = (const float*)d_in[5];
  const float* bn1b     = (const float*)d_in[6];
  const float* gin_w2   = (const float*)d_in[7];
  const float* gin_b2   = (const float*)d_in[8];
  const float* bn2g     = (const float*)d_in[9];
  const float* bn2b     = (const float*)d_in[10];
  const float* sab_wq = (const float*)d_in[11];
  const float* sab_wk = (const float*)d_in[12];
  const float* sab_wv = (const float*)d_in[13];
  const float* sab_wo = (const float*)d_in[14];
  const float* sab_bq = (const float*)d_in[15];
  const float* sab_bk = (const float*)d_in[16];
  const float* sab_bv = (const float*)d_in[17];
  const float* sab_bo = (const float*)d_in[18];
  const float* ln1b = (const float*)d_in[19];
  const float* ln2b = (const float*)d_in[20];
  const float* ln1g = (const float*)d_in[21];
  const float* ln2g = (const float*)d_in[22];
  const float* agg_wq = (const float*)d_in[23];
  const float* agg_bq = (const float*)d_in[24];
  const float* agg_wk = (const float*)d_in[25];
  const float* agg_bk = (const float*)d_in[26];
  const float* score_w1 = (const float*)d_in[27];
  const float* score_b1 = (const float*)d_in[28];
  const float* score_w2 = (const float*)d_in[29];
  const float* score_b2 = (const float*)d_in[30];
  const float* patient  = (const float*)d_in[31];
  const float* avgproj  = (const float*)d_in[32];
  const int* sub_x     = (const int*)d_in[33];
  const int* sub_ea    = (const int*)d_in[34];
  const int* sub_ei    = (const int*)d_in[35];
  const int* sub_batch = (const int*)d_in[36];
  const int* mol_x     = (const int*)d_in[37];
  const int* mol_ea    = (const int*)d_in[38];
  const int* mol_ei    = (const int*)d_in[39];
  const int* mol_batch = (const int*)d_in[40];
  const void* mask     = d_in[41];

  const int Ns = in_sizes[33] / 9, Es = in_sizes[34] / 3;
  const int Nm = in_sizes[37] / 9, Em = in_sizes[38] / 3;
  const int S = 492, M = 600, D = 200, B = 64;
  const int NmR = (Nm + 63) & ~63;       // mol padded (64-aligned)
  const int NsR = (Ns + 63) & ~63;       // sub padded
  const int NTOT = NmR + NsR;            // merged padded node space
  const int NSEG = M + S;                // segments (mol first)
  const int ETOT = Em + Es;
  const int BONDE = 2 * 4 * 3 * 64 * 128;

  // ---- workspace carve-up ----
  char* Wp = (char*)d_ws;
  size_t off = 0;
  auto alloc = [&](size_t bytes) -> void* {
    void* p = Wp + off;
    off = (off + bytes + 255) & ~(size_t)255;
    return p;
  };
  unsigned short* h0 = (unsigned short*)alloc((size_t)NTOT * 128 * 2);
  unsigned short* h1 = (unsigned short*)alloc((size_t)NTOT * 128 * 2);
  unsigned short* w1t = (unsigned short*)alloc(262144 * 2);
  unsigned short* w2t = (unsigned short*)alloc(262144 * 2);
  unsigned short* bt16 = (unsigned short*)alloc((size_t)BONDE * 2);
  int4* epool  = (int4*)alloc((size_t)ETOT * 16);
  int*  npool  = (int*)alloc((size_t)(Nm + Ns) * 4);
  int*  excl_e = (int*)alloc((size_t)NTOT * 4);
  int*  bsum_e = (int*)alloc(1024 * 4);
  int*  excl_n = (int*)alloc((size_t)NSEG * 4);
  int*  bsum_n = (int*)alloc(1024 * 4);
  int*  rowptr_e = (int*)alloc((size_t)(NTOT + 1) * 4);
  int*  rowptr_n = (int*)alloc((size_t)(NSEG + 1) * 4);
  char* zstart = Wp + off;                       // region zeroed below
  int*  deg_e  = (int*)alloc((size_t)NTOT * 4);
  int*  deg_n  = (int*)alloc((size_t)NSEG * 4);
  int*  cur_e  = (int*)alloc((size_t)NTOT * 4);
  int*  cur_n  = (int*)alloc((size_t)NSEG * 4);
  int*  flags  = (int*)alloc(8);
  size_t zsize = (size_t)((Wp + off) - zstart);
  float* pooled_all = (float*)alloc((size_t)NSEG * 128 * 4);
  float* pooled_mol = pooled_all;
  float* pooled_sub = pooled_all + (size_t)M * 128;
  float* Qb   = (float*)alloc((size_t)S * 128 * 4);
  float* Kb   = (float*)alloc((size_t)S * 128 * 4);
  float* Vb   = (float*)alloc((size_t)S * 128 * 4);
  float* Ob   = (float*)alloc((size_t)S * 128 * 4);
  float* O2b  = (float*)alloc((size_t)S * 128 * 4);
  float* subf = (float*)alloc((size_t)S * 128 * 4);
  unsigned short* subT = (unsigned short*)alloc((size_t)128 * 512 * 2);
  float* mol_embb = (float*)alloc((size_t)D * 128 * 4);
  float* aggQb = (float*)alloc((size_t)D * 128 * 4);
  float* aggKb = (float*)alloc((size_t)S * 128 * 4);
  float* attnb = (float*)alloc((size_t)D * S * 4);
  float* aggTb = (float*)alloc((size_t)B * D * 128 * 4);
  (void)ws_size; (void)n_in; (void)out_size;

  hipMemsetAsync(zstart, 0, zsize, stream);
  prep_weights<<<1024, 256, 0, stream>>>(gin_w1, gin_w2, w1t, w2t);
  prep_bond<<<(BONDE + 255) / 256, 256, 0, stream>>>(bond_emb, bt16, BONDE);
  mask_detect<<<64, 256, 0, stream>>>((const unsigned char*)mask, flags, D * S);

  // ---- CSR build over padded merged space ----
  int total_cnt = Em + Es + Nm + Ns;
  build_count<<<(total_cnt + 255) / 256, 256, 0, stream>>>(
      mol_ei, Em, sub_ei, Es, mol_batch, Nm, sub_batch, Ns, deg_e, deg_n, M, NmR);
  int nb_e = (NTOT + 255) / 256;      // 821 <= 1024
  int nb_n = (NSEG + 255) / 256;
  scan_block<<<nb_e, 256, 0, stream>>>(deg_e, NTOT, excl_e, bsum_e);
  scan_top<<<1, 1024, 0, stream>>>(bsum_e, nb_e);
  scan_block<<<nb_n, 256, 0, stream>>>(deg_n, NSEG, excl_n, bsum_n);
  scan_top<<<1, 1024, 0, stream>>>(bsum_n, nb_n);
  finalize_rowptr<<<(NTOT + 256) / 256 + 1, 256, 0, stream>>>(excl_e, bsum_e, NTOT, ETOT, rowptr_e);
  finalize_rowptr<<<(NSEG + 256) / 256 + 1, 256, 0, stream>>>(excl_n, bsum_n, NSEG, Nm + Ns, rowptr_n);
  scatter_edges<<<(ETOT + 255) / 256, 256, 0, stream>>>(
      mol_ei, mol_ea, Em, sub_ei, sub_ea, Es, NmR, rowptr_e, cur_e, epool);
  scatter_nodes<<<(Nm + Ns + 255) / 256, 256, 0, stream>>>(
      mol_batch, Nm, sub_batch, Ns, M, NmR, rowptr_n, cur_n, npool);

  // ---- merged GIN: embed both graphs, 4 fused layers, one pooling ----
  embed_nodes<<<(Nm * 128 + 255) / 256, 256, 0, stream>>>(
      mol_x, atom_emb + (size_t)1 * 9 * 64 * 128, h0, Nm);
  embed_nodes<<<(Ns * 128 + 255) / 256, 256, 0, stream>>>(
      sub_x, atom_emb + (size_t)0 * 9 * 64 * 128, h0 + (size_t)NmR * 128, Ns);
  unsigned short* hin = h0; unsigned short* hout = h1;
  for (int l = 0; l < 4; l++) {
    gin_fused3<<<NTOT / 64, 256, 0, stream>>>(
        hin, hout, gin_eps, l, NmR, bt16, epool, rowptr_e,
        w1t, gin_b1, bn1g, bn1b, w2t, gin_b2, bn2g, bn2b);
    unsigned short* tmp = hin; hin = hout; hout = tmp;
  }
  pool_csr<<<NSEG, 128, 0, stream>>>(hin, npool, rowptr_n, pooled_all, NSEG);

  // --- SAB on sub pooled ---
  gemm_qkv<<<dim3(S, 3), 256, 0, stream>>>(pooled_sub,
                                           sab_wq, sab_bq, Qb,
                                           sab_wk, sab_bk, Kb,
                                           sab_wv, sab_bv, Vb);
  sab_attn<<<dim3(S, 2), 256, 0, stream>>>(Qb, Kb, Vb, Ob, S);
  ln_rows<<<S, 128, 0, stream>>>(Ob, Ob, ln1g, ln1b);
  gemm_tile<<<S, 256, 0, stream>>>(Ob, sab_wo, sab_bo, O2b, 128);
  ln_rows<<<S, 128, 0, stream>>>(O2b, subf, ln2g, ln2b);
  prep_subT<<<(128 * 512 + 255) / 256, 256, 0, stream>>>(subf, subT, S);

  // --- molecule projection ---
  gemm_tile<<<D, 256, 0, stream>>>(avgproj, pooled_mol, (const float*)nullptr, mol_embb, 600);

  // --- attention aggregation + score ---
  gemm_tile<<<D, 256, 0, stream>>>(mol_embb, agg_wq, agg_bq, aggQb, 128);
  gemm_tile<<<S, 256, 0, stream>>>(subf, agg_wk, agg_bk, aggKb, 128);
  agg_attn<<<D, 256, 0, stream>>>(aggQb, aggKb, mask, flags, attnb, D, S);
  agg_mfma<<<D, 256, 0, stream>>>(attnb, patient, subT, aggTb, D, S);
  score_head<<<(B * D + 3) / 4, 256, 0, stream>>>(aggTb, score_w1, score_b1, score_w2, score_b2,
                                                  (float*)d_out, B * D);
}

// Round 12
// 1044.517 us; speedup vs baseline: 2.7641x; 1.0701x over previous
//
#include <hip/hip_runtime.h>

// ---------------------------------------------------------------------------
// MoleRec pipeline on gfx950.
// R11: gin_fused3's Phase C wrote bf16 outputs as 2-byte scattered stores ->
//      WRITE_SIZE 144MB vs 54MB logical (2.7x partial-line inflation).
//      Phase C now overwrites the just-consumed z1s rows per-mt (barrier
//      between af loads and writes), then one coalesced us8 store loop
//      (1KB contiguous per wave, full cachelines).
// ---------------------------------------------------------------------------

typedef short short8 __attribute__((ext_vector_type(8)));
typedef unsigned short us8 __attribute__((ext_vector_type(8)));
typedef float f32x4 __attribute__((ext_vector_type(4)));
typedef unsigned short us4 __attribute__((ext_vector_type(4)));

#define BN_RSQ 0.9999950000374997f   // 1/sqrt(1+1e-5)  (BatchNorm eval, var=1)
#define LN_EPS 1e-5f
#define NEGBIG -4294967296.0f        // -(1<<32), matches reference mask fill

__device__ __forceinline__ unsigned short f2bf(float x) {
  union { float f; unsigned int u; } v; v.f = x;
  unsigned int r = v.u + 0x7fffu + ((v.u >> 16) & 1u);   // RNE
  return (unsigned short)(r >> 16);
}
__device__ __forceinline__ float bf2f(unsigned short x) {
  union { unsigned int u; float f; } v; v.u = ((unsigned int)x) << 16;
  return v.f;
}

// ---------------- weight prep: fp32 [K][N] -> bf16 [N][K] ------------------
__global__ void prep_weights(const float* __restrict__ w1, const float* __restrict__ w2,
                             unsigned short* __restrict__ w1t, unsigned short* __restrict__ w2t) {
  int i = blockIdx.x * 256 + threadIdx.x;
  if (i >= 262144) return;
  int gl = i >> 15;
  int k1 = (i >> 8) & 127, c1 = i & 255;
  w1t[(gl << 15) + c1 * 128 + k1] = f2bf(w1[i]);
  int k2 = (i >> 7) & 255, c2 = i & 127;
  w2t[(gl << 15) + c2 * 256 + k2] = f2bf(w2[i]);
}

// ---------------- bond tables fp32 -> bf16 (same layout) --------------------
__global__ void prep_bond(const float* __restrict__ in, unsigned short* __restrict__ out, int n) {
  int i = blockIdx.x * 256 + threadIdx.x;
  if (i < n) out[i] = f2bf(in[i]);
}

// ---------------- mask layout detection (block-reduced) ---------------------
__global__ __launch_bounds__(256) void mask_detect(const unsigned char* __restrict__ m,
                                                   int* __restrict__ flags, int nbytes) {
  __shared__ int lf[2];
  if (threadIdx.x == 0) { lf[0] = 0; lf[1] = 0; }
  __syncthreads();
  int f0 = 0, f1 = 0;
  for (int i = blockIdx.x * 256 + threadIdx.x; i < nbytes; i += gridDim.x * 256) {
    if (m[i]) { if ((i & 3) == 0) f0 = 1; else f1 = 1; }
  }
  if (f0) atomicOr(&lf[0], 1);
  if (f1) atomicOr(&lf[1], 1);
  __syncthreads();
  if (threadIdx.x == 0) {
    if (lf[0]) atomicOr(flags, 1);
    if (lf[1]) atomicOr(flags + 1, 1);
  }
}

// ---------------- CSR build: count (padded merged node space) ---------------
__global__ void build_count(const int* __restrict__ ei_m, int Em,
                            const int* __restrict__ ei_s, int Es,
                            const int* __restrict__ bm, int Nm,
                            const int* __restrict__ bs, int Ns,
                            int* __restrict__ deg_e, int* __restrict__ deg_n,
                            int M, int NmR) {
  int i = blockIdx.x * 256 + threadIdx.x;
  if (i < Em) { atomicAdd(&deg_e[ei_m[i]], 1); return; }
  i -= Em;
  if (i < Es) { atomicAdd(&deg_e[NmR + ei_s[i]], 1); return; }
  i -= Es;
  if (i < Nm) { atomicAdd(&deg_n[bm[i]], 1); return; }
  i -= Nm;
  if (i < Ns) { atomicAdd(&deg_n[M + bs[i]], 1); }
}

// ---------------- CSR build: block-level exclusive scan ---------------------
__global__ __launch_bounds__(256) void scan_block(const int* __restrict__ cnt, int n,
                                                  int* __restrict__ excl, int* __restrict__ bsum) {
  int gid = blockIdx.x * 256 + threadIdx.x;
  int lane = threadIdx.x & 63, w = threadIdx.x >> 6;
  int v = (gid < n) ? cnt[gid] : 0;
  int x = v;
#pragma unroll
  for (int off = 1; off < 64; off <<= 1) {
    int y = __shfl_up(x, off, 64);
    if (lane >= off) x += y;
  }
  __shared__ int wt[4];
  if (lane == 63) wt[w] = x;
  __syncthreads();
  int add = 0;
  for (int i = 0; i < w; i++) add += wt[i];
  x += add;
  if (gid < n) excl[gid] = x - v;
  if (threadIdx.x == 255) bsum[blockIdx.x] = x;
}

__global__ __launch_bounds__(1024) void scan_top(int* __restrict__ bsum, int n) {
  int t = threadIdx.x;
  int lane = t & 63, w = t >> 6;
  int v = (t < n) ? bsum[t] : 0;
  int x = v;
#pragma unroll
  for (int off = 1; off < 64; off <<= 1) {
    int y = __shfl_up(x, off, 64);
    if (lane >= off) x += y;
  }
  __shared__ int wt[16];
  if (lane == 63) wt[w] = x;
  __syncthreads();
  int add = 0;
  for (int i = 0; i < w; i++) add += wt[i];
  x += add;
  if (t < n) bsum[t] = x - v;
}

// ---------------- rowptr finalize: rowptr[i] = excl[i]+bsum[i>>8] -----------
__global__ void finalize_rowptr(const int* __restrict__ excl, const int* __restrict__ bsum,
                                int n, int total, int* __restrict__ rowptr) {
  int i = blockIdx.x * 256 + threadIdx.x;
  if (i < n) rowptr[i] = excl[i] + bsum[i >> 8];
  if (i == n) rowptr[n] = total;
}

// ---------------- CSR build: scatter ----------------------------------------
__global__ void scatter_edges(const int* __restrict__ ei_m, const int* __restrict__ ea_m, int Em,
                              const int* __restrict__ ei_s, const int* __restrict__ ea_s, int Es, int NmR,
                              const int* __restrict__ rowptr_e,
                              int* __restrict__ cur_e, int4* __restrict__ epool) {
  int i = blockIdx.x * 256 + threadIdx.x;
  int g, src, a0, a1, a2;
  if (i < Em) {
    g = ei_m[i]; src = ei_m[Em + i];
    a0 = ea_m[i * 3]; a1 = ea_m[i * 3 + 1]; a2 = ea_m[i * 3 + 2];
  } else {
    int j = i - Em; if (j >= Es) return;
    g = NmR + ei_s[j]; src = NmR + ei_s[Es + j];
    a0 = ea_s[j * 3]; a1 = ea_s[j * 3 + 1]; a2 = ea_s[j * 3 + 2];
  }
  int slot = rowptr_e[g] + atomicAdd(&cur_e[g], 1);
  int p0 = a0 * 128, p1 = (64 + a1) * 128, p2 = (128 + a2) * 128;
  epool[slot] = make_int4(src * 128, 0, p0 | (p1 << 16), p2);
}

__global__ void scatter_nodes(const int* __restrict__ bm, int Nm,
                              const int* __restrict__ bs, int Ns, int M, int NmR,
                              const int* __restrict__ rowptr_n,
                              int* __restrict__ cur_n, int* __restrict__ npool) {
  int i = blockIdx.x * 256 + threadIdx.x;
  int g, node;
  if (i < Nm) { g = bm[i]; node = i; }
  else { int j = i - Nm; if (j >= Ns) return; g = M + bs[j]; node = NmR + j; }
  int slot = rowptr_n[g] + atomicAdd(&cur_n[g], 1);
  npool[slot] = node;
}

// ---------------- node embedding (bf16 out) ---------------------------------
__global__ void embed_nodes(const int* __restrict__ x, const float* __restrict__ table,
                            unsigned short* __restrict__ h, int N) {
  int i = blockIdx.x * 256 + threadIdx.x;
  if (i >= N * 128) return;
  int n = i >> 7, c = i & 127;
  float s = 0.f;
#pragma unroll
  for (int f = 0; f < 9; f++) {
    int v = x[n * 9 + f];
    s += table[(f * 64 + v) * 128 + c];
  }
  h[i] = f2bf(s);
}

// ---------------- fused GIN layer (R11) -------------------------------------
__global__ __launch_bounds__(256, 4) void gin_fused3(
    const unsigned short* __restrict__ hin, unsigned short* __restrict__ hout,
    const float* __restrict__ eps_all, int l, int NmR,
    const unsigned short* __restrict__ bt16,
    const int4* __restrict__ epool, const int* __restrict__ rowptr_e,
    const unsigned short* __restrict__ w1t_a, const float* __restrict__ b1_a,
    const float* __restrict__ g1_a, const float* __restrict__ be1_a,
    const unsigned short* __restrict__ w2t_a, const float* __restrict__ b2_a,
    const float* __restrict__ g2_a, const float* __restrict__ be2_a) {
  __shared__ __align__(16) unsigned char smem[38144];
  unsigned short* z1s = (unsigned short*)smem;              // u16 idx: r*264 + c
  unsigned short* zs  = (unsigned short*)(smem + 20736);    // u16 idx: r*136 + c
  int t = threadIdx.x;
  int r0 = blockIdx.x * 64;
  int g = (r0 < NmR) ? 1 : 0;
  int gl = g * 4 + l;
  const unsigned short* bt = bt16 + (size_t)gl * 3 * 64 * 128;
  const unsigned short* w1t = w1t_a + (size_t)gl * 32768;
  const unsigned short* w2t = w2t_a + (size_t)gl * 32768;
  const float* b1 = b1_a + gl * 256;
  const float* g1 = g1_a + gl * 256;
  const float* be1 = be1_a + gl * 256;
  const float* b2 = b2_a + gl * 128;
  const float* g2 = g2_a + gl * 128;
  const float* be2 = be2_a + gl * 128;
  float eps1 = 1.0f + eps_all[gl];
  int do_relu = (l != 3);

  // Phase A: node-parallel gather into zs (8 thr/node x 16ch, register acc)
#pragma unroll
  for (int p = 0; p < 2; p++) {
    int lr = p * 32 + (t >> 3);
    int n = r0 + lr;
    int cb = (t & 7) * 16;
    float acc[16];
    {
      const unsigned short* hr = hin + (size_t)n * 128 + cb;
      us8 v0 = *(const us8*)hr, v1 = *(const us8*)(hr + 8);
#pragma unroll
      for (int k = 0; k < 8; k++) {
        acc[k]     = eps1 * bf2f(v0[k]);
        acc[8 + k] = eps1 * bf2f(v1[k]);
      }
    }
    int e0 = rowptr_e[n], e1 = rowptr_e[n + 1];
    for (int e = e0; e < e1; e++) {
      int4 rec = epool[e];
      const unsigned short* hs = hin + rec.x + cb;
      const unsigned short* q0 = bt + (rec.z & 0xffff) + cb;
      const unsigned short* q1 = bt + (((unsigned)rec.z) >> 16) + cb;
      const unsigned short* q2 = bt + rec.w + cb;
      us8 a0 = *(const us8*)hs, a1 = *(const us8*)(hs + 8);
      us8 b0 = *(const us8*)q0, b1v = *(const us8*)(q0 + 8);
      us8 c0 = *(const us8*)q1, c1 = *(const us8*)(q1 + 8);
      us8 d0 = *(const us8*)q2, d1 = *(const us8*)(q2 + 8);
#pragma unroll
      for (int k = 0; k < 8; k++) {
        acc[k]     += fmaxf(bf2f(a0[k]) + bf2f(b0[k]) + bf2f(c0[k]) + bf2f(d0[k]), 0.f);
        acc[8 + k] += fmaxf(bf2f(a1[k]) + bf2f(b1v[k]) + bf2f(c1[k]) + bf2f(d1[k]), 0.f);
      }
    }
    unsigned short ob[16];
#pragma unroll
    for (int k = 0; k < 16; k++) ob[k] = f2bf(acc[k]);
    unsigned short* zr = zs + lr * 136 + cb;
    *(us8*)zr = *(const us8*)&ob[0];
    *(us8*)(zr + 8) = *(const us8*)&ob[8];
  }
  __syncthreads();

  int lane = t & 63, wave = t >> 6;
  int quad = lane >> 4, l16 = lane & 15;
  // Phase B: z1[64x256] = relu(bn1(z @ w1 + b1)); per-mt barrier (overlay)
  {
    short8 bw[4][4];
    int cb = wave * 64;
#pragma unroll
    for (int nt = 0; nt < 4; nt++) {
      const unsigned short* p = w1t + (cb + nt * 16 + l16) * 128 + quad * 8;
#pragma unroll
      for (int kc = 0; kc < 4; kc++) bw[nt][kc] = *(const short8*)(p + kc * 32);
    }
    for (int mt = 0; mt < 4; mt++) {
      short8 af[4];
      const unsigned short* zrow = zs + (mt * 16 + l16) * 136 + quad * 8;
#pragma unroll
      for (int kc = 0; kc < 4; kc++)
        af[kc] = *(const short8*)(zrow + kc * 32);
#pragma unroll
      for (int nt = 0; nt < 4; nt++) {
        f32x4 acc = {0.f, 0.f, 0.f, 0.f};
#pragma unroll
        for (int kc = 0; kc < 4; kc++)
          acc = __builtin_amdgcn_mfma_f32_16x16x32_bf16(af[kc], bw[nt][kc], acc, 0, 0, 0);
        int c = cb + nt * 16 + l16;
        float sc = g1[c] * BN_RSQ, sh = be1[c], bb = b1[c];
#pragma unroll
        for (int reg = 0; reg < 4; reg++) {
          int r = mt * 16 + quad * 4 + reg;
          float y = (acc[reg] + bb) * sc + sh;
          z1s[r * 264 + c] = f2bf(fmaxf(y, 0.f));
        }
      }
      __syncthreads();
    }
  }
  // Phase C: h_out = bn2(z1 @ w2 + b2) (+relu).
  // R11: per-mt, all waves load af, barrier, then overwrite the SAME z1s
  // rows with the bf16 output (they're dead after the loads). Coalesced
  // global store afterwards.
  {
    short8 bw[2][8];
    int cb = wave * 32;
#pragma unroll
    for (int nt = 0; nt < 2; nt++) {
      const unsigned short* p = w2t + (cb + nt * 16 + l16) * 256 + quad * 8;
#pragma unroll
      for (int kc = 0; kc < 8; kc++) bw[nt][kc] = *(const short8*)(p + kc * 32);
    }
    for (int mt = 0; mt < 4; mt++) {
      short8 af[8];
      const unsigned short* zrow = z1s + (mt * 16 + l16) * 264 + quad * 8;
#pragma unroll
      for (int kc = 0; kc < 8; kc++)
        af[kc] = *(const short8*)(zrow + kc * 32);
      __syncthreads();   // all waves done reading rows [mt*16, mt*16+16)
#pragma unroll
      for (int nt = 0; nt < 2; nt++) {
        f32x4 acc = {0.f, 0.f, 0.f, 0.f};
#pragma unroll
        for (int kc = 0; kc < 8; kc++)
          acc = __builtin_amdgcn_mfma_f32_16x16x32_bf16(af[kc], bw[nt][kc], acc, 0, 0, 0);
        int c = cb + nt * 16 + l16;
        float sc = g2[c] * BN_RSQ, sh = be2[c], bb = b2[c];
#pragma unroll
        for (int reg = 0; reg < 4; reg++) {
          int r = mt * 16 + quad * 4 + reg;
          float y = (acc[reg] + bb) * sc + sh;
          if (do_relu) y = fmaxf(y, 0.f);
          z1s[r * 264 + c] = f2bf(y);     // overwrite consumed row
        }
      }
    }
  }
  __syncthreads();
  // Coalesced store: wave moves 4 full 256B rows (1KB contiguous).
  for (int i = t; i < 1024; i += 256) {
    int r = i >> 4, c8 = (i & 15) * 8;
    us8 v = *(const us8*)(z1s + r * 264 + c8);
    *(us8*)(hout + (size_t)(r0 + r) * 128 + c8) = v;
  }
}

// ---------------- CSR mean pooling (bf16 h, merged node ids) ----------------
__global__ __launch_bounds__(128) void pool_csr(const unsigned short* __restrict__ h,
                                                const int* __restrict__ npool,
                                                const int* __restrict__ rowptr_n,
                                                float* __restrict__ pooled, int nseg) {
  int m = blockIdx.x;
  if (m >= nseg) return;
  int st = rowptr_n[m];
  int e = rowptr_n[m + 1];
  int len = e - st;
  int c = threadIdx.x;
  float s = 0.f;
  int i = st;
  for (; i + 3 < e; i += 4) {
    int n0 = npool[i], n1 = npool[i + 1], n2 = npool[i + 2], n3 = npool[i + 3];
    float v0 = bf2f(h[(size_t)n0 * 128 + c]);
    float v1 = bf2f(h[(size_t)n1 * 128 + c]);
    float v2 = bf2f(h[(size_t)n2 * 128 + c]);
    float v3 = bf2f(h[(size_t)n3 * 128 + c]);
    s += (v0 + v1) + (v2 + v3);
  }
  for (; i < e; i++) s += bf2f(h[(size_t)npool[i] * 128 + c]);
  pooled[m * 128 + c] = s / ((float)len + 1e-9f);
}

// ---------------- row GEMM (N=128): C[r,:] = A[r,:] @ W + bias --------------
__global__ __launch_bounds__(256) void gemm_tile(const float* __restrict__ A, const float* __restrict__ W,
                                                 const float* __restrict__ bias, float* __restrict__ C,
                                                 int K) {
  __shared__ float As[608];
  __shared__ float red[128];
  int r = blockIdx.x;
  int t = threadIdx.x;
  for (int i = t; i < K; i += 256) As[i] = A[(size_t)r * K + i];
  __syncthreads();
  int c = t & 127, half = t >> 7;
  int Kh = K >> 1;
  int k0 = half * Kh, k1 = k0 + Kh;
  float acc = 0.f;
#pragma unroll 8
  for (int k = k0; k < k1; k++) acc = fmaf(As[k], W[(size_t)k * 128 + c], acc);
  if (half) red[c] = acc;
  __syncthreads();
  if (!half) {
    float v = acc + red[c] + (bias ? bias[c] : 0.f);
    C[(size_t)r * 128 + c] = v;
  }
}

// ---------------- fused QKV row GEMM (K=128), blockIdx.y picks W/bias/out ---
__global__ __launch_bounds__(256) void gemm_qkv(const float* __restrict__ A,
                                                const float* __restrict__ W0, const float* __restrict__ bi0, float* __restrict__ C0,
                                                const float* __restrict__ W1, const float* __restrict__ bi1, float* __restrict__ C1,
                                                const float* __restrict__ W2, const float* __restrict__ bi2, float* __restrict__ C2) {
  __shared__ float As[128];
  __shared__ float red[128];
  int r = blockIdx.x, which = blockIdx.y;
  const float* W = (which == 0) ? W0 : (which == 1) ? W1 : W2;
  const float* bias = (which == 0) ? bi0 : (which == 1) ? bi1 : bi2;
  float* C = (which == 0) ? C0 : (which == 1) ? C1 : C2;
  int t = threadIdx.x;
  if (t < 128) As[t] = A[(size_t)r * 128 + t];
  __syncthreads();
  int c = t & 127, half = t >> 7;
  int k0 = half * 64, k1 = k0 + 64;
  float acc = 0.f;
#pragma unroll 8
  for (int k = k0; k < k1; k++) acc = fmaf(As[k], W[(size_t)k * 128 + c], acc);
  if (half) red[c] = acc;
  __syncthreads();
  if (!half) C[(size_t)r * 128 + c] = acc + red[c] + bias[c];
}

// ---------------- SAB attention: O = Qs + softmax(QsKs^T/8) Vs -------------
__global__ __launch_bounds__(256) void sab_attn(const float* __restrict__ Q, const float* __restrict__ K,
                                                const float* __restrict__ V, float* __restrict__ O, int S) {
  int q = blockIdx.x, hd = blockIdx.y;
  int t = threadIdx.x;
  __shared__ float sc[512];
  __shared__ float red[8];
  __shared__ float pacc[4][64];
  const float* qrow = Q + q * 128 + hd * 64;
  for (int k = t; k < 512; k += 256) {
    float d = -1e30f;
    if (k < S) {
      const float* krow = K + k * 128 + hd * 64;
      d = 0.f;
#pragma unroll
      for (int j = 0; j < 64; j += 4) {
        float4 a = *(const float4*)(qrow + j);
        float4 b = *(const float4*)(krow + j);
        d += a.x * b.x + a.y * b.y + a.z * b.z + a.w * b.w;
      }
      d *= 0.125f;
    }
    sc[k] = d;
  }
  __syncthreads();
  float m = fmaxf(sc[t], sc[t + 256]);
  for (int off = 32; off; off >>= 1) m = fmaxf(m, __shfl_down(m, off));
  if ((t & 63) == 0) red[t >> 6] = m;
  __syncthreads();
  m = fmaxf(fmaxf(red[0], red[1]), fmaxf(red[2], red[3]));
  float p0 = __expf(sc[t] - m), p1 = __expf(sc[t + 256] - m);
  sc[t] = p0; sc[t + 256] = p1;
  float s = p0 + p1;
  for (int off = 32; off; off >>= 1) s += __shfl_down(s, off);
  if ((t & 63) == 0) red[4 + (t >> 6)] = s;
  __syncthreads();
  float inv = 1.f / (red[4] + red[5] + red[6] + red[7]);
  int d = t & 63, part = t >> 6;
  float acc = 0.f;
  for (int k = part; k < S; k += 4) acc += sc[k] * V[k * 128 + hd * 64 + d];
  pacc[part][d] = acc;
  __syncthreads();
  if (part == 0) {
    float o = (pacc[0][d] + pacc[1][d] + pacc[2][d] + pacc[3][d]) * inv;
    O[q * 128 + hd * 64 + d] = qrow[d] + o;
  }
}

// ---------------- row LayerNorm over 128 ------------------------------------
__global__ __launch_bounds__(128) void ln_rows(const float* __restrict__ in, float* __restrict__ out,
                                               const float* __restrict__ g, const float* __restrict__ b) {
  int r = blockIdx.x, t = threadIdx.x;
  __shared__ float red[4];
  float x = in[r * 128 + t];
  float s = x;
  for (int off = 32; off; off >>= 1) s += __shfl_down(s, off);
  if ((t & 63) == 0) red[t >> 6] = s;
  __syncthreads();
  float mu = (red[0] + red[1]) * (1.f / 128.f);
  float dd = x - mu;
  float v = dd * dd;
  for (int off = 32; off; off >>= 1) v += __shfl_down(v, off);
  if ((t & 63) == 0) red[2 + (t >> 6)] = v;
  __syncthreads();
  float var = (red[2] + red[3]) * (1.f / 128.f);
  out[r * 128 + t] = g[t] * dd * rsqrtf(var + LN_EPS) + b[t];
}

// ---------------- masked softmax attn: attn[d,s] ----------------------------
__global__ __launch_bounds__(256) void agg_attn(const float* __restrict__ Q, const float* __restrict__ Kt,
                                                const void* __restrict__ mask, const int* __restrict__ flags,
                                                float* __restrict__ attn, int D, int S) {
  int d = blockIdx.x, t = threadIdx.x;
  __shared__ float sc[512];
  __shared__ float red[8];
  int layout = (flags[1] == 0) ? 0 : (flags[0] ? 1 : 2);
  const float* qrow = Q + d * 128;
  for (int s = t; s < 512; s += 256) {
    float v = NEGBIG;
    if (s < S) {
      int mi = d * S + s;
      bool msk;
      if (layout == 0)      msk = ((const int*)mask)[mi] != 0;
      else if (layout == 1) msk = ((const unsigned char*)mask)[mi] != 0;
      else                  msk = ((const float*)mask)[mi] != 0.f;
      if (!msk) {
        float dd = 0.f;
        const float* krow = Kt + s * 128;
#pragma unroll
        for (int j = 0; j < 128; j += 4) {
          float4 a = *(const float4*)(qrow + j);
          float4 b = *(const float4*)(krow + j);
          dd += a.x * b.x + a.y * b.y + a.z * b.z + a.w * b.w;
        }
        v = dd * 0.08838834764831845f;
      }
    }
    sc[s] = v;
  }
  __syncthreads();
  float m = fmaxf(sc[t], sc[t + 256]);
  for (int off = 32; off; off >>= 1) m = fmaxf(m, __shfl_down(m, off));
  if ((t & 63) == 0) red[t >> 6] = m;
  __syncthreads();
  m = fmaxf(fmaxf(red[0], red[1]), fmaxf(red[2], red[3]));
  float p0 = __expf(sc[t] - m), p1 = __expf(sc[t + 256] - m);
  float s2 = p0 + p1;
  for (int off = 32; off; off >>= 1) s2 += __shfl_down(s2, off);
  if ((t & 63) == 0) red[4 + (t >> 6)] = s2;
  __syncthreads();
  float inv = 1.f / (red[4] + red[5] + red[6] + red[7]);
  attn[d * S + t] = p0 * inv;
  if (t + 256 < S) attn[d * S + t + 256] = p1 * inv;
}

// ---------------- subT prep: subf [S][128] f32 -> subT bf16 [128][512] ------
__global__ void prep_subT(const float* __restrict__ subf, unsigned short* __restrict__ subT, int S) {
  int i = blockIdx.x * 256 + threadIdx.x;
  if (i >= 128 * 512) return;
  int hh = i >> 9, k = i & 511;
  subT[i] = (k < S) ? f2bf(subf[k * 128 + hh]) : (unsigned short)0;
}

// ---------------- agg via MFMA: per d, (pat .* attn[d])[64x492] @ sub -------
__global__ __launch_bounds__(256) void agg_mfma(const float* __restrict__ attn, const float* __restrict__ pat,
                                                const unsigned short* __restrict__ subT,
                                                float* __restrict__ aggT, int D, int S) {
  int d = blockIdx.x, t = threadIdx.x;
  __shared__ unsigned short As[64][40];
  int lane = t & 63, wave = t >> 6;
  int quad = lane >> 4, l16 = lane & 15;
  f32x4 acc[8];
#pragma unroll
  for (int nt = 0; nt < 8; nt++) acc[nt] = (f32x4){0.f, 0.f, 0.f, 0.f};
  const float* arow = attn + d * S;
  int srow = t >> 2, skb = (t & 3) * 8;
  for (int c = 0; c < 16; c++) {
    int s0 = c * 32;
    __syncthreads();
    unsigned short v[8];
#pragma unroll
    for (int j = 0; j < 8; j++) {
      int s = s0 + skb + j;
      float x = (s < S) ? arow[s] * pat[srow * S + s] : 0.f;
      v[j] = f2bf(x);
    }
    *(us4*)&As[srow][skb]     = *(us4*)&v[0];
    *(us4*)&As[srow][skb + 4] = *(us4*)&v[4];
    __syncthreads();
    short8 af = *(const short8*)&As[16 * wave + l16][quad * 8];
#pragma unroll
    for (int nt = 0; nt < 8; nt++) {
      short8 bf = *(const short8*)(subT + (nt * 16 + l16) * 512 + s0 + quad * 8);
      acc[nt] = __builtin_amdgcn_mfma_f32_16x16x32_bf16(af, bf, acc[nt], 0, 0, 0);
    }
  }
#pragma unroll
  for (int nt = 0; nt < 8; nt++) {
    int hh = nt * 16 + l16;
#pragma unroll
    for (int reg = 0; reg < 4; reg++) {
      int b = 16 * wave + quad * 4 + reg;
      aggT[((size_t)(b * D + d)) * 128 + hh] = acc[nt][reg];
    }
  }
}

// ---------------- score head: sigmoid(relu(agg@w1+b1)@w2+b2), 4 rows/block --
__global__ __launch_bounds__(256) void score_head(const float* __restrict__ aggT,
                                                  const float* __restrict__ w1, const float* __restrict__ b1,
                                                  const float* __restrict__ w2, const float* __restrict__ b2,
                                                  float* __restrict__ out, int total) {
  int i = blockIdx.x * 4 + (threadIdx.x >> 6);   // one output per wave
  int j = threadIdx.x & 63;
  if (i >= total) return;
  const float* av = aggT + (size_t)i * 128;
  float acc = b1[j];
#pragma unroll 8
  for (int k = 0; k < 128; k++) acc = fmaf(av[k], w1[k * 64 + j], acc);
  acc = fmaxf(acc, 0.f) * w2[j];
  for (int off = 32; off; off >>= 1) acc += __shfl_down(acc, off);
  if (j == 0) {
    float x = acc + b2[0];
    out[i] = 1.f / (1.f + __expf(-x));
  }
}

// ---------------------------------------------------------------------------
extern "C" void kernel_launch(void* const* d_in, const int* in_sizes, int n_in,
                              void* d_out, int out_size, void* d_ws, size_t ws_size,
                              hipStream_t stream) {
  const float* atom_emb = (const float*)d_in[0];
  const float* bond_emb = (const float*)d_in[1];
  const float* gin_eps  = (const float*)d_in[2];
  const float* gin_w1   = (const float*)d_in[3];
  const float* gin_b1   = (const float*)d_in[4];
  const float* bn1g     = (const float*)d_in[5];
  const float* bn1b     = (const float*)d_in[6];
  const float* gin_w2   = (const float*)d_in[7];
  const float* gin_b2   = (const float*)d_in[8];
  const float* bn2g     = (const float*)d_in[9];
  const float* bn2b     = (const float*)d_in[10];
  const float* sab_wq = (const float*)d_in[11];
  const float* sab_wk = (const float*)d_in[12];
  const float* sab_wv = (const float*)d_in[13];
  const float* sab_wo = (const float*)d_in[14];
  const float* sab_bq = (const float*)d_in[15];
  const float* sab_bk = (const float*)d_in[16];
  const float* sab_bv = (const float*)d_in[17];
  const float* sab_bo = (const float*)d_in[18];
  const float* ln1b = (const float*)d_in[19];
  const float* ln2b = (const float*)d_in[20];
  const float* ln1g = (const float*)d_in[21];
  const float* ln2g = (const float*)d_in[22];
  const float* agg_wq = (const float*)d_in[23];
  const float* agg_bq = (const float*)d_in[24];
  const float* agg_wk = (const float*)d_in[25];
  const float* agg_bk = (const float*)d_in[26];
  const float* score_w1 = (const float*)d_in[27];
  const float* score_b1 = (const float*)d_in[28];
  const float* score_w2 = (const float*)d_in[29];
  const float* score_b2 = (const float*)d_in[30];
  const float* patient  = (const float*)d_in[31];
  const float* avgproj  = (const float*)d_in[32];
  const int* sub_x     = (const int*)d_in[33];
  const int* sub_ea    = (const int*)d_in[34];
  const int* sub_ei    = (const int*)d_in[35];
  const int* sub_batch = (const int*)d_in[36];
  const int* mol_x     = (const int*)d_in[37];
  const int* mol_ea    = (const int*)d_in[38];
  const int* mol_ei    = (const int*)d_in[39];
  const int* mol_batch = (const int*)d_in[40];
  const void* mask     = d_in[41];

  const int Ns = in_sizes[33] / 9, Es = in_sizes[34] / 3;
  const int Nm = in_sizes[37] / 9, Em = in_sizes[38] / 3;
  const int S = 492, M = 600, D = 200, B = 64;
  const int NmR = (Nm + 63) & ~63;       // mol padded (64-aligned)
  const int NsR = (Ns + 63) & ~63;       // sub padded
  const int NTOT = NmR + NsR;            // merged padded node space
  const int NSEG = M + S;                // segments (mol first)
  const int ETOT = Em + Es;
  const int BONDE = 2 * 4 * 3 * 64 * 128;

  // ---- workspace carve-up ----
  char* Wp = (char*)d_ws;
  size_t off = 0;
  auto alloc = [&](size_t bytes) -> void* {
    void* p = Wp + off;
    off = (off + bytes + 255) & ~(size_t)255;
    return p;
  };
  unsigned short* h0 = (unsigned short*)alloc((size_t)NTOT * 128 * 2);
  unsigned short* h1 = (unsigned short*)alloc((size_t)NTOT * 128 * 2);
  unsigned short* w1t = (unsigned short*)alloc(262144 * 2);
  unsigned short* w2t = (unsigned short*)alloc(262144 * 2);
  unsigned short* bt16 = (unsigned short*)alloc((size_t)BONDE * 2);
  int4* epool  = (int4*)alloc((size_t)ETOT * 16);
  int*  npool  = (int*)alloc((size_t)(Nm + Ns) * 4);
  int*  excl_e = (int*)alloc((size_t)NTOT * 4);
  int*  bsum_e = (int*)alloc(1024 * 4);
  int*  excl_n = (int*)alloc((size_t)NSEG * 4);
  int*  bsum_n = (int*)alloc(1024 * 4);
  int*  rowptr_e = (int*)alloc((size_t)(NTOT + 1) * 4);
  int*  rowptr_n = (int*)alloc((size_t)(NSEG + 1) * 4);
  char* zstart = Wp + off;                       // region zeroed below
  int*  deg_e  = (int*)alloc((size_t)NTOT * 4);
  int*  deg_n  = (int*)alloc((size_t)NSEG * 4);
  int*  cur_e  = (int*)alloc((size_t)NTOT * 4);
  int*  cur_n  = (int*)alloc((size_t)NSEG * 4);
  int*  flags  = (int*)alloc(8);
  size_t zsize = (size_t)((Wp + off) - zstart);
  float* pooled_all = (float*)alloc((size_t)NSEG * 128 * 4);
  float* pooled_mol = pooled_all;
  float* pooled_sub = pooled_all + (size_t)M * 128;
  float* Qb   = (float*)alloc((size_t)S * 128 * 4);
  float* Kb   = (float*)alloc((size_t)S * 128 * 4);
  float* Vb   = (float*)alloc((size_t)S * 128 * 4);
  float* Ob   = (float*)alloc((size_t)S * 128 * 4);
  float* O2b  = (float*)alloc((size_t)S * 128 * 4);
  float* subf = (float*)alloc((size_t)S * 128 * 4);
  unsigned short* subT = (unsigned short*)alloc((size_t)128 * 512 * 2);
  float* mol_embb = (float*)alloc((size_t)D * 128 * 4);
  float* aggQb = (float*)alloc((size_t)D * 128 * 4);
  float* aggKb = (float*)alloc((size_t)S * 128 * 4);
  float* attnb = (float*)alloc((size_t)D * S * 4);
  float* aggTb = (float*)alloc((size_t)B * D * 128 * 4);
  (void)ws_size; (void)n_in; (void)out_size;

  hipMemsetAsync(zstart, 0, zsize, stream);
  prep_weights<<<1024, 256, 0, stream>>>(gin_w1, gin_w2, w1t, w2t);
  prep_bond<<<(BONDE + 255) / 256, 256, 0, stream>>>(bond_emb, bt16, BONDE);
  mask_detect<<<64, 256, 0, stream>>>((const unsigned char*)mask, flags, D * S);

  // ---- CSR build over padded merged space ----
  int total_cnt = Em + Es + Nm + Ns;
  build_count<<<(total_cnt + 255) / 256, 256, 0, stream>>>(
      mol_ei, Em, sub_ei, Es, mol_batch, Nm, sub_batch, Ns, deg_e, deg_n, M, NmR);
  int nb_e = (NTOT + 255) / 256;
  int nb_n = (NSEG + 255) / 256;
  scan_block<<<nb_e, 256, 0, stream>>>(deg_e, NTOT, excl_e, bsum_e);
  scan_top<<<1, 1024, 0, stream>>>(bsum_e, nb_e);
  scan_block<<<nb_n, 256, 0, stream>>>(deg_n, NSEG, excl_n, bsum_n);
  scan_top<<<1, 1024, 0, stream>>>(bsum_n, nb_n);
  finalize_rowptr<<<(NTOT + 256) / 256 + 1, 256, 0, stream>>>(excl_e, bsum_e, NTOT, ETOT, rowptr_e);
  finalize_rowptr<<<(NSEG + 256) / 256 + 1, 256, 0, stream>>>(excl_n, bsum_n, NSEG, Nm + Ns, rowptr_n);
  scatter_edges<<<(ETOT + 255) / 256, 256, 0, stream>>>(
      mol_ei, mol_ea, Em, sub_ei, sub_ea, Es, NmR, rowptr_e, cur_e, epool);
  scatter_nodes<<<(Nm + Ns + 255) / 256, 256, 0, stream>>>(
      mol_batch, Nm, sub_batch, Ns, M, NmR, rowptr_n, cur_n, npool);

  // ---- merged GIN: embed both graphs, 4 fused layers, one pooling ----
  embed_nodes<<<(Nm * 128 + 255) / 256, 256, 0, stream>>>(
      mol_x, atom_emb + (size_t)1 * 9 * 64 * 128, h0, Nm);
  embed_nodes<<<(Ns * 128 + 255) / 256, 256, 0, stream>>>(
      sub_x, atom_emb + (size_t)0 * 9 * 64 * 128, h0 + (size_t)NmR * 128, Ns);
  unsigned short* hin = h0; unsigned short* hout = h1;
  for (int l = 0; l < 4; l++) {
    gin_fused3<<<NTOT / 64, 256, 0, stream>>>(
        hin, hout, gin_eps, l, NmR, bt16, epool, rowptr_e,
        w1t, gin_b1, bn1g, bn1b, w2t, gin_b2, bn2g, bn2b);
    unsigned short* tmp = hin; hin = hout; hout = tmp;
  }
  pool_csr<<<NSEG, 128, 0, stream>>>(hin, npool, rowptr_n, pooled_all, NSEG);

  // --- SAB on sub pooled ---
  gemm_qkv<<<dim3(S, 3), 256, 0, stream>>>(pooled_sub,
                                           sab_wq, sab_bq, Qb,
                                           sab_wk, sab_bk, Kb,
                                           sab_wv, sab_bv, Vb);
  sab_attn<<<dim3(S, 2), 256, 0, stream>>>(Qb, Kb, Vb, Ob, S);
  ln_rows<<<S, 128, 0, stream>>>(Ob, Ob, ln1g, ln1b);
  gemm_tile<<<S, 256, 0, stream>>>(Ob, sab_wo, sab_bo, O2b, 128);
  ln_rows<<<S, 128, 0, stream>>>(O2b, subf, ln2g, ln2b);
  prep_subT<<<(128 * 512 + 255) / 256, 256, 0, stream>>>(subf, subT, S);

  // --- molecule projection ---
  gemm_tile<<<D, 256, 0, stream>>>(avgproj, pooled_mol, (const float*)nullptr, mol_embb, 600);

  // --- attention aggregation + score ---
  gemm_tile<<<D, 256, 0, stream>>>(mol_embb, agg_wq, agg_bq, aggQb, 128);
  gemm_tile<<<S, 256, 0, stream>>>(subf, agg_wk, agg_bk, aggKb, 128);
  agg_attn<<<D, 256, 0, stream>>>(aggQb, aggKb, mask, flags, attnb, D, S);
  agg_mfma<<<D, 256, 0, stream>>>(attnb, patient, subT, aggTb, D, S);
  score_head<<<(B * D + 3) / 4, 256, 0, stream>>>(aggTb, score_w1, score_b1, score_w2, score_b2,
                                                  (float*)d_out, B * D);
}